// Round 5
// baseline (1063.752 us; speedup 1.0000x reference)
//
#include <hip/hip_runtime.h>
#include <math.h>

#define HH 256
#define WW 256
#define CC 64
#define PLANE (HH*WW)

typedef short s16x8 __attribute__((ext_vector_type(8)));
typedef float f32x16 __attribute__((ext_vector_type(16)));
typedef unsigned int uint;
typedef uint u32x4v __attribute__((ext_vector_type(4)));

__device__ inline uint bf16rne(float f) {
    uint u = __float_as_uint(f);
    return (u + 0x7FFFu + ((u >> 16) & 1u)) >> 16;
}
__device__ inline float bf16val(uint h) { return __uint_as_float(h << 16); }
__device__ inline s16x8 fragpack(uint a, uint b, uint c, uint d) {
    u32x4v t = {a, b, c, d};
    return __builtin_bit_cast(s16x8, t);
}

// ---------------- weight prep: split fp32 W into bf16 hi/lo, pack ic-pairs ----
// layout: wh/wl [tap][oc][icpair] dwords
__global__ __launch_bounds__(256) void wprep_kernel(
    const float* __restrict__ w1, const float* __restrict__ w2,
    uint* __restrict__ wh1, uint* __restrict__ wl1,
    uint* __restrict__ wh2, uint* __restrict__ wl2)
{
    const int idx = blockIdx.x * 256 + threadIdx.x;      // 0..18431
    const float* w = blockIdx.y ? w2 : w1;
    uint* wh = blockIdx.y ? wh2 : wh1;
    uint* wl = blockIdx.y ? wl2 : wl1;
    const int tap = idx >> 11;           // 9
    const int oc  = (idx >> 5) & 63;     // 64
    const int icp = idx & 31;            // 32 ic-pairs
    float w0 = w[(oc * 64 + 2 * icp) * 9 + tap];
    float w1v = w[(oc * 64 + 2 * icp + 1) * 9 + tap];
    uint h0 = bf16rne(w0); float l0 = w0 - bf16val(h0);
    uint h1 = bf16rne(w1v); float l1 = w1v - bf16val(h1);
    wh[idx] = h0 | (h1 << 16);
    wl[idx] = bf16rne(l0) | (bf16rne(l1) << 16);
}

// ---------------- x repack: fp32 NCHW -> bf16-pair NHWC packed ----------------
// xp[((b*HW + px))*32 + icp] = bf16(x[2icp]) | bf16(x[2icp+1])<<16
__global__ __launch_bounds__(256) void xrepack_kernel(
    const float* __restrict__ x, uint* __restrict__ xp)
{
    const int tid = threadIdx.x;
    const size_t px = (size_t)blockIdx.x * 256 + tid;
    const int b = blockIdx.y;
    const float* xb = x + (size_t)b * CC * PLANE + px;
    uint* o = xp + ((size_t)b * PLANE + px) * 32;
    uint d[32];
#pragma unroll
    for (int icp = 0; icp < 32; icp++) {
        float v0 = xb[(size_t)(2 * icp) * PLANE];
        float v1 = xb[(size_t)(2 * icp + 1) * PLANE];
        d[icp] = bf16rne(v0) | (bf16rne(v1) << 16);
    }
#pragma unroll
    for (int k = 0; k < 8; k++)
        *(uint4*)(o + 4 * k) = make_uint4(d[4*k], d[4*k+1], d[4*k+2], d[4*k+3]);
}

// ---------------- conv 3x3 reflect via MFMA, NHWC-direct (no staging) --------
// block: 4 waves; tile 64 oc x 8 rows x 32 cols. wave w: rows {2w, 2w+1}.
// B-frag = one global dwordx4/lane from NHWC-packed input (L1/L2-hot).
// MODE 1: PReLU + NHWC-packed out (XOR-swizzled LDS transpose).
// MODE 2: fp32 NCHW out.
template<int MODE>
__global__ __launch_bounds__(256, 3) void conv_mfma(
    const uint* __restrict__ xin,   // [B][H][W][32] bf16-pair dwords
    const uint* __restrict__ wh, const uint* __restrict__ wl,
    const float* __restrict__ bias, const float* __restrict__ prelu,
    uint* __restrict__ op, float* __restrict__ of)
{
    __shared__ uint tlds[(MODE == 1) ? 8 * 32 * 32 : 1];
    const int tid  = threadIdx.x;
    const int lane = tid & 63;
    const int wid  = tid >> 6;
    const int x0 = blockIdx.x * 32;
    const int y0 = blockIdx.y * 8;
    const int b  = blockIdx.z;
    const int colx = lane & 31;
    const int half = lane >> 5;
    const int r0 = wid * 2;

    // reflect-resolved row/col offsets (dwords), computed once
    int roff0[3], roff1[3], coff[3];
#pragma unroll
    for (int d = 0; d < 3; d++) {
        int yA = y0 + r0 + d - 1; yA = yA < 0 ? 1 : (yA > 255 ? 254 : yA);
        int yB = y0 + r0 + d;     yB = yB > 255 ? 254 : yB;     // (never <0)
        roff0[d] = yA * (256 * 32);
        roff1[d] = yB * (256 * 32);
        int cx = x0 + colx + d - 1; cx = cx < 0 ? 1 : (cx > 255 ? 254 : cx);
        coff[d] = cx * 32;
    }
    const uint* bp = xin + (size_t)b * PLANE * 32;

    f32x16 acc00 = (f32x16)0.f, acc01 = (f32x16)0.f;   // [Mtile][row]
    f32x16 acc10 = (f32x16)0.f, acc11 = (f32x16)0.f;

#pragma unroll
    for (int tap = 0; tap < 9; tap++) {
        const int dy = tap / 3, dx = tap % 3;
        const uint* b0p = bp + roff0[dy] + coff[dx] + half * 4;
        const uint* b1p = bp + roff1[dy] + coff[dx] + half * 4;
        const uint* wbh = wh + ((size_t)tap * 64 + colx) * 32 + half * 4;
        const uint* wbl = wl + ((size_t)tap * 64 + colx) * 32 + half * 4;
#pragma unroll
        for (int c = 0; c < 4; c++) {
            const uint4 bq0 = *(const uint4*)(b0p + c * 8);
            const uint4 bq1 = *(const uint4*)(b1p + c * 8);
            const s16x8 B0 = fragpack(bq0.x, bq0.y, bq0.z, bq0.w);
            const s16x8 B1 = fragpack(bq1.x, bq1.y, bq1.z, bq1.w);
            const uint4 ah0 = *(const uint4*)(wbh + c * 8);
            const uint4 al0 = *(const uint4*)(wbl + c * 8);
            const uint4 ah1 = *(const uint4*)(wbh + 1024 + c * 8);
            const uint4 al1 = *(const uint4*)(wbl + 1024 + c * 8);
            const s16x8 A0h = fragpack(ah0.x, ah0.y, ah0.z, ah0.w);
            const s16x8 A0l = fragpack(al0.x, al0.y, al0.z, al0.w);
            const s16x8 A1h = fragpack(ah1.x, ah1.y, ah1.z, ah1.w);
            const s16x8 A1l = fragpack(al1.x, al1.y, al1.z, al1.w);
            acc00 = __builtin_amdgcn_mfma_f32_32x32x16_bf16(A0h, B0, acc00, 0, 0, 0);
            acc01 = __builtin_amdgcn_mfma_f32_32x32x16_bf16(A0h, B1, acc01, 0, 0, 0);
            acc10 = __builtin_amdgcn_mfma_f32_32x32x16_bf16(A1h, B0, acc10, 0, 0, 0);
            acc11 = __builtin_amdgcn_mfma_f32_32x32x16_bf16(A1h, B1, acc11, 0, 0, 0);
            acc00 = __builtin_amdgcn_mfma_f32_32x32x16_bf16(A0l, B0, acc00, 0, 0, 0);
            acc01 = __builtin_amdgcn_mfma_f32_32x32x16_bf16(A0l, B1, acc01, 0, 0, 0);
            acc10 = __builtin_amdgcn_mfma_f32_32x32x16_bf16(A1l, B0, acc10, 0, 0, 0);
            acc11 = __builtin_amdgcn_mfma_f32_32x32x16_bf16(A1l, B1, acc11, 0, 0, 0);
        }
    }

    // ---- epilogue. C/D layout (32x32): col=lane&31 (pixel), row=(j&3)+8*(j>>2)+4*half (oc)
    if constexpr (MODE == 1) {
        // PReLU, pack oc-pairs, XOR-swizzled LDS transpose -> coalesced NHWC stores
#define ST1(ACC, MT, RR) { \
        _Pragma("unroll") \
        for (int j = 0; j < 16; j += 2) { \
            const int row = (j & 3) + 8 * (j >> 2) + 4 * half; \
            const int oc = MT * 32 + row; \
            float v0 = ACC[j]     + bias[oc]; \
            float v1 = ACC[j + 1] + bias[oc + 1]; \
            const float a0 = prelu[oc], a1 = prelu[oc + 1]; \
            v0 = fmaxf(v0, 0.f) + a0 * fminf(v0, 0.f); \
            v1 = fmaxf(v1, 0.f) + a1 * fminf(v1, 0.f); \
            const int icp = oc >> 1; \
            tlds[((RR) * 32 + icp) * 32 + (colx ^ icp)] = \
                bf16rne(v0) | (bf16rne(v1) << 16); \
        } }
        ST1(acc00, 0, r0) ST1(acc01, 0, r0 + 1) ST1(acc10, 1, r0) ST1(acc11, 1, r0 + 1)
#undef ST1
        __syncthreads();
        const int prow = tid >> 5, pcol = tid & 31;
        uint* o = op + ((size_t)b * PLANE + (size_t)(y0 + prow) * 256 + x0 + pcol) * 32;
        uint d[32];
#pragma unroll
        for (int i = 0; i < 32; i++)
            d[i] = tlds[(prow * 32 + i) * 32 + (pcol ^ i)];
#pragma unroll
        for (int k = 0; k < 8; k++)
            *(uint4*)(o + 4 * k) = make_uint4(d[4*k], d[4*k+1], d[4*k+2], d[4*k+3]);
    } else {
#define ST2(ACC, MT, RR) { \
        _Pragma("unroll") \
        for (int j = 0; j < 16; j++) { \
            const int row = (j & 3) + 8 * (j >> 2) + 4 * half; \
            const int oc = MT * 32 + row; \
            of[(((size_t)b * 64 + oc) * 256 + y0 + (RR)) * 256 + x0 + colx] = \
                ACC[j] + bias[oc]; \
        } }
        ST2(acc00, 0, r0) ST2(acc01, 0, r0 + 1) ST2(acc10, 1, r0) ST2(acc11, 1, r0 + 1)
#undef ST2
    }
}

// ---------------- fused: per-pixel channel mean/max + global avg pool ----------------
__global__ __launch_bounds__(256) void stats_kernel(
    const float* __restrict__ r, float* __restrict__ amx /*[B,2,HW]*/,
    float* __restrict__ g /*[B*C], pre-zeroed*/)
{
    const int tid = threadIdx.x;
    const int pix = blockIdx.x * 256 + tid;
    const int b = blockIdx.y;
    const int lane = tid & 63, wv = tid >> 6;
    __shared__ float gpart[4][64];

    const float* rb = r + (size_t)b * CC * PLANE + pix;
    float s = 0.f, m = -INFINITY;
    for (int c = 0; c < CC; c++) {
        float v = rb[(size_t)c * PLANE];
        s += v; m = fmaxf(m, v);
        float t = v;
        t += __shfl_xor(t, 1, 64);
        t += __shfl_xor(t, 2, 64);
        t += __shfl_xor(t, 4, 64);
        t += __shfl_xor(t, 8, 64);
        t += __shfl_xor(t, 16, 64);
        t += __shfl_xor(t, 32, 64);
        if (lane == 0) gpart[wv][c] = t;
    }
    amx[(size_t)b * 2 * PLANE + pix] = s * (1.f / CC);
    amx[(size_t)b * 2 * PLANE + PLANE + pix] = m;
    __syncthreads();
    if (tid < 64) {
        float ps = (gpart[0][tid] + gpart[1][tid] + gpart[2][tid] + gpart[3][tid])
                   * (1.f / PLANE);
        atomicAdd(&g[b * 64 + tid], ps);
    }
}

// ---------------- spatial-attention 3x3 conv (2ch -> 1ch) ----------------
__global__ __launch_bounds__(256) void saconv_kernel(
    const float* __restrict__ amx, const float* __restrict__ sa_w,
    const float* __restrict__ sa_b, float* __restrict__ smap)
{
    int pix = blockIdx.x * 256 + threadIdx.x;
    int b = blockIdx.y;
    int x = pix & 255, y = pix >> 8;
    float acc = sa_b[0];
    const float* ab = amx + (size_t)b * 2 * PLANE;
#pragma unroll
    for (int c = 0; c < 2; c++)
#pragma unroll
        for (int dy = -1; dy <= 1; dy++)
#pragma unroll
            for (int dx = -1; dx <= 1; dx++) {
                int gx = x + dx; gx = gx < 0 ? 1 : (gx >= WW ? 2 * WW - 2 - gx : gx);
                int gy = y + dy; gy = gy < 0 ? 1 : (gy >= HH ? 2 * HH - 2 - gy : gy);
                acc += sa_w[c * 9 + (dy + 1) * 3 + (dx + 1)] * ab[(size_t)c * PLANE + gy * WW + gx];
            }
    smap[(size_t)b * PLANE + pix] = acc;
}

// ---------------- tiny MLPs: channel attention + hyper kernels ----------------
__global__ __launch_bounds__(256) void mlp_kernel(
    const float* __restrict__ h, const float* __restrict__ g,
    const float* __restrict__ ca_w1, const float* __restrict__ ca_b1,
    const float* __restrict__ ca_a,
    const float* __restrict__ ca_w2, const float* __restrict__ ca_b2,
    const float* __restrict__ fc_w, const float* __restrict__ fc_b,
    const float* __restrict__ k1_w, const float* __restrict__ k1_b,
    const float* __restrict__ k2_w, const float* __restrict__ k2_b,
    const float* __restrict__ k3_w, const float* __restrict__ k3_b,
    float* __restrict__ kernA, float* __restrict__ kernB /*[B,64,64]*/)
{
    int b = blockIdx.x, tid = threadIdx.x;
    __shared__ float gb[64], t16[16], u32[32], v32[32], cg1[32], casig[64];

    if (tid < 64) gb[tid] = g[b * 64 + tid];
    __syncthreads();

    if (tid < 16) {
        float s = fc_b[tid];
        for (int j = 0; j < 16; j++) s += fc_w[tid * 16 + j] * h[b * 16 + j];
        t16[tid] = s >= 0.f ? s : 0.01f * s;
    }
    if (tid < 32) {
        float c1 = ca_b1[tid];
        for (int j = 0; j < 64; j++) c1 += ca_w1[tid * 64 + j] * gb[j];
        cg1[tid] = fmaxf(c1, 0.f) + ca_a[tid] * fminf(c1, 0.f);
    }
    __syncthreads();
    if (tid < 32) {
        float s = k1_b[tid];
        for (int j = 0; j < 16; j++) s += k1_w[tid * 16 + j] * t16[j];
        u32[tid] = s >= 0.f ? s : 0.01f * s;
    }
    if (tid < 64) {
        float c2 = ca_b2[tid];
        for (int j = 0; j < 32; j++) c2 += ca_w2[tid * 32 + j] * cg1[j];
        casig[tid] = 1.f / (1.f + expf(-c2));
    }
    __syncthreads();
    if (tid < 32) {
        float s = k2_b[tid];
        for (int j = 0; j < 32; j++) s += k2_w[tid * 32 + j] * u32[j];
        v32[tid] = s >= 0.f ? s : 0.01f * s;
    }
    __syncthreads();
    for (int o = tid; o < 8192; o += 256) {
        float s = k3_b[o];
        for (int j = 0; j < 32; j++) s += k3_w[(size_t)o * 32 + j] * v32[j];
        int oc = o >> 7;
        int i = o & 127;
        if (i < 64) kernA[((size_t)b * 64 + oc) * 64 + i] = s;
        else        kernB[((size_t)b * 64 + oc) * 64 + (i - 64)] = s * casig[i - 64];
    }
}

// ---------------- final: out = x + hc_bias + sig(s)*(A.r) + (B.r) ----------------
__global__ __launch_bounds__(256) void final_kernel(
    const float* __restrict__ x, const float* __restrict__ r,
    const float* __restrict__ smap,
    const float* __restrict__ kernA, const float* __restrict__ kernB,
    const float* __restrict__ hc_bias,
    float* __restrict__ out)
{
    const int tid = threadIdx.x;
    const int pix = blockIdx.x * 256 + tid;
    const int og = blockIdx.y * 32;
    const int b = blockIdx.z;

    __shared__ float kA[64][32], kB[64][32];
    for (int idx = tid; idx < 64 * 32; idx += 256) {
        int oc = idx & 31, c = idx >> 5;
        kA[c][oc] = kernA[((size_t)b * 64 + og + oc) * 64 + c];
        kB[c][oc] = kernB[((size_t)b * 64 + og + oc) * 64 + c];
    }
    __syncthreads();

    float accA[32], accB[32];
#pragma unroll
    for (int i = 0; i < 32; i++) { accA[i] = 0.f; accB[i] = 0.f; }

    const float* rb = r + (size_t)b * CC * PLANE + pix;
    for (int c = 0; c < CC; c++) {
        float rv = rb[(size_t)c * PLANE];
#pragma unroll
        for (int oc = 0; oc < 32; oc++) {
            accA[oc] += kA[c][oc] * rv;
            accB[oc] += kB[c][oc] * rv;
        }
    }

    float sv = smap[(size_t)b * PLANE + pix];
    float sig = 1.f / (1.f + expf(-sv));
    const float* xb = x + ((size_t)b * CC + og) * PLANE + pix;
    float* ob = out + ((size_t)b * CC + og) * PLANE + pix;
#pragma unroll
    for (int oc = 0; oc < 32; oc++) {
        ob[(size_t)oc * PLANE] = xb[(size_t)oc * PLANE] + hc_bias[og + oc]
                               + sig * accA[oc] + accB[oc];
    }
}

extern "C" void kernel_launch(void* const* d_in, const int* in_sizes, int n_in,
                              void* d_out, int out_size, void* d_ws, size_t ws_size,
                              hipStream_t stream) {
    const float* x   = (const float*)d_in[0];
    const float* h   = (const float*)d_in[1];
    const float* c1w = (const float*)d_in[2];
    const float* c1b = (const float*)d_in[3];
    const float* pa  = (const float*)d_in[4];
    const float* c2w = (const float*)d_in[5];
    const float* c2b = (const float*)d_in[6];
    const float* saw = (const float*)d_in[7];
    const float* sab = (const float*)d_in[8];
    const float* cw1 = (const float*)d_in[9];
    const float* cb1 = (const float*)d_in[10];
    const float* caa = (const float*)d_in[11];
    const float* cw2 = (const float*)d_in[12];
    const float* cb2 = (const float*)d_in[13];
    const float* fcw = (const float*)d_in[14];
    const float* fcb = (const float*)d_in[15];
    const float* k1w = (const float*)d_in[16];
    const float* k1b = (const float*)d_in[17];
    const float* k2w = (const float*)d_in[18];
    const float* k2b = (const float*)d_in[19];
    const float* k3w = (const float*)d_in[20];
    const float* k3b = (const float*)d_in[21];
    const float* hcb = (const float*)d_in[22];
    float* out = (float*)d_out;

    char* ws = (char*)d_ws;
    const size_t SZ_Q = (size_t)8 * PLANE * 32 * 4;   // 67,108,864 (NHWC packed)
    uint*  xp  = (uint*)ws;                           // x repacked
    uint*  r1p = (uint*)(ws + SZ_Q);                  // conv1 out, NHWC packed
    float* r   = (float*)(ws + 2 * SZ_Q);             // conv2 out, fp32 NCHW
    // small buffers reuse [0, 2*SZ_Q) AFTER convs complete (xp, r1p dead)
    float* amx   = (float*)ws;
    float* smap  = (float*)(ws + (size_t)8 * 2 * PLANE * 4);
    float* g     = (float*)(ws + (size_t)8 * 3 * PLANE * 4);
    float* kernA = (float*)(ws + (size_t)8 * 3 * PLANE * 4 + 4096);
    float* kernB = kernA + (size_t)8 * 64 * 64;

    // weight packs live in d_out (dead until final_kernel overwrites it)
    uint* wsp = (uint*)d_out;
    uint* wh1 = wsp;          uint* wl1 = wsp + 18432;
    uint* wh2 = wsp + 36864;  uint* wl2 = wsp + 55296;

    wprep_kernel<<<dim3(72, 2), 256, 0, stream>>>(c1w, c2w, wh1, wl1, wh2, wl2);
    xrepack_kernel<<<dim3(PLANE / 256, 8), 256, 0, stream>>>(x, xp);

    dim3 cgrid(WW / 32, HH / 8, 8);  // (8, 32, 8)
    conv_mfma<1><<<cgrid, 256, 0, stream>>>(xp, wh1, wl1, c1b, pa, r1p, nullptr);
    conv_mfma<2><<<cgrid, 256, 0, stream>>>(r1p, wh2, wl2, c2b, nullptr, nullptr, r);

    hipMemsetAsync(g, 0, 512 * sizeof(float), stream);
    stats_kernel<<<dim3(PLANE / 256, 8), 256, 0, stream>>>(r, amx, g);
    saconv_kernel<<<dim3(PLANE / 256, 8), 256, 0, stream>>>(amx, saw, sab, smap);
    mlp_kernel<<<8, 256, 0, stream>>>(h, g, cw1, cb1, caa, cw2, cb2,
                                      fcw, fcb, k1w, k1b, k2w, k2b, k3w, k3b,
                                      kernA, kernB);
    final_kernel<<<dim3(PLANE / 256, 2, 8), 256, 0, stream>>>(
        x, r, smap, kernA, kernB, hcb, out);
}

// Round 6
// 978.983 us; speedup vs baseline: 1.0866x; 1.0866x over previous
//
#include <hip/hip_runtime.h>
#include <math.h>

#define HH 256
#define WW 256
#define CC 64
#define PLANE (HH*WW)

typedef short s16x8 __attribute__((ext_vector_type(8)));
typedef float f32x16 __attribute__((ext_vector_type(16)));
typedef unsigned int uint;
typedef uint u32x4v __attribute__((ext_vector_type(4)));

__device__ inline uint bf16rne(float f) {
    uint u = __float_as_uint(f);
    return (u + 0x7FFFu + ((u >> 16) & 1u)) >> 16;
}
__device__ inline float bf16val(uint h) { return __uint_as_float(h << 16); }
__device__ inline s16x8 fragpack(uint a, uint b, uint c, uint d) {
    u32x4v t = {a, b, c, d};
    return __builtin_bit_cast(s16x8, t);
}
__device__ inline void gload_lds16(const uint* g, uint* l) {
    __builtin_amdgcn_global_load_lds(
        (const __attribute__((address_space(1))) uint*)g,
        (__attribute__((address_space(3))) uint*)l, 16, 0, 0);
}

// ---------------- weight prep: split fp32 W into bf16 hi/lo, pack ic-pairs ----
__global__ __launch_bounds__(256) void wprep_kernel(
    const float* __restrict__ w1, const float* __restrict__ w2,
    uint* __restrict__ wh1, uint* __restrict__ wl1,
    uint* __restrict__ wh2, uint* __restrict__ wl2)
{
    const int idx = blockIdx.x * 256 + threadIdx.x;      // 0..18431
    const float* w = blockIdx.y ? w2 : w1;
    uint* wh = blockIdx.y ? wh2 : wh1;
    uint* wl = blockIdx.y ? wl2 : wl1;
    const int tap = idx >> 11;           // 9
    const int oc  = (idx >> 5) & 63;     // 64
    const int icp = idx & 31;            // 32 ic-pairs
    float w0 = w[(oc * 64 + 2 * icp) * 9 + tap];
    float w1v = w[(oc * 64 + 2 * icp + 1) * 9 + tap];
    uint h0 = bf16rne(w0); float l0 = w0 - bf16val(h0);
    uint h1 = bf16rne(w1v); float l1 = w1v - bf16val(h1);
    wh[idx] = h0 | (h1 << 16);
    wl[idx] = bf16rne(l0) | (bf16rne(l1) << 16);
}

// ---------------- x repack: fp32 NCHW -> bf16-pair NHWC packed ----------------
__global__ __launch_bounds__(256) void xrepack_kernel(
    const float* __restrict__ x, uint* __restrict__ xp)
{
    const int tid = threadIdx.x;
    const size_t px = (size_t)blockIdx.x * 256 + tid;
    const int b = blockIdx.y;
    const float* xb = x + (size_t)b * CC * PLANE + px;
    uint* o = xp + ((size_t)b * PLANE + px) * 32;
    uint d[32];
#pragma unroll
    for (int icp = 0; icp < 32; icp++) {
        float v0 = xb[(size_t)(2 * icp) * PLANE];
        float v1 = xb[(size_t)(2 * icp + 1) * PLANE];
        d[icp] = bf16rne(v0) | (bf16rne(v1) << 16);
    }
#pragma unroll
    for (int k = 0; k < 8; k++)
        *(uint4*)(o + 4 * k) = make_uint4(d[4*k], d[4*k+1], d[4*k+2], d[4*k+3]);
}

// ---------------- conv 3x3 reflect via MFMA, LDS-staged halo ----------------
// block: 4 waves; tile 64 oc x 8 rows x 32 cols. wave w: rows {2w, 2w+1}.
// Halo: 10 rows x 34 cols x 32 dw NHWC-packed, staged via global_load_lds(16B)
// with XOR chunk swizzle (slot = c2 ^ (pix&7)) applied on the GLOBAL source
// (LDS dest linear, rule 21) -> conflict-free ds_read_b128 in the K-loop.
// Weights from global (16 KB/tap, L1-hot). No barriers in K-loop.
// MODE 1: PReLU + NHWC-packed out (LDS transpose, buffer reused).
// MODE 2: fp32 NCHW out.
#define HPIX 340                 // 10*34 halo pixels
#define HCHUNK (HPIX*8)          // 16B chunks = 2720
template<int MODE>
__global__ __launch_bounds__(256, 3) void conv_mfma(
    const uint* __restrict__ xin,   // [B][H][W][32] bf16-pair dwords
    const uint* __restrict__ wh, const uint* __restrict__ wl,
    const float* __restrict__ bias, const float* __restrict__ prelu,
    uint* __restrict__ op, float* __restrict__ of)
{
    __shared__ uint lds[HPIX * 32];          // 43,520 B
    const int tid  = threadIdx.x;
    const int lane = tid & 63;
    const int wid  = tid >> 6;
    const int x0 = blockIdx.x * 32;
    const int y0 = blockIdx.y * 8;
    const int b  = blockIdx.z;
    const int colx = lane & 31;
    const int half = lane >> 5;
    const int r0 = wid * 2;

    // ---- stage halo: chunk k -> LDS byte k*16 (linear), source pre-swizzled
    {
        const uint* gb = xin + (size_t)b * PLANE * 32;
#pragma unroll
        for (int iter = 0; iter < 11; iter++) {
            const int k = iter * 256 + tid;
            if (iter < 10 || k < HCHUNK) {
                const int pix = k >> 3;
                const int slot = k & 7;
                const int hrow = pix / 34;
                const int hcol = pix - hrow * 34;
                int gy = y0 - 1 + hrow; gy = gy < 0 ? 1 : (gy > 255 ? 254 : gy);
                int gx = x0 - 1 + hcol; gx = gx < 0 ? 1 : (gx > 255 ? 254 : gx);
                const int c2 = slot ^ (pix & 7);    // involution
                gload_lds16(gb + ((size_t)(gy * 256 + gx)) * 32 + c2 * 4,
                            &lds[(iter * 256 + wid * 64) * 4]);
            }
        }
    }
    __syncthreads();

    f32x16 acc00 = (f32x16)0.f, acc01 = (f32x16)0.f;   // [Mtile][row]
    f32x16 acc10 = (f32x16)0.f, acc11 = (f32x16)0.f;

#pragma unroll
    for (int tap = 0; tap < 9; tap++) {
        const int dy = tap / 3, dx = tap % 3;
        const int pix0 = (r0 + dy) * 34 + dx + colx;   // output row r0
        const int pix1 = pix0 + 34;                    // output row r0+1
        const uint* wbh = wh + ((size_t)tap * 64 + colx) * 32 + half * 4;
        const uint* wbl = wl + ((size_t)tap * 64 + colx) * 32 + half * 4;
#pragma unroll
        for (int c = 0; c < 4; c++) {
            const int c2 = c * 2 + half;
            const uint4 bq0 = *(const uint4*)&lds[(pix0 * 8 + (c2 ^ (pix0 & 7))) * 4];
            const uint4 bq1 = *(const uint4*)&lds[(pix1 * 8 + (c2 ^ (pix1 & 7))) * 4];
            const s16x8 B0 = fragpack(bq0.x, bq0.y, bq0.z, bq0.w);
            const s16x8 B1 = fragpack(bq1.x, bq1.y, bq1.z, bq1.w);
            const uint4 ah0 = *(const uint4*)(wbh + c * 8);
            const uint4 al0 = *(const uint4*)(wbl + c * 8);
            const uint4 ah1 = *(const uint4*)(wbh + 1024 + c * 8);
            const uint4 al1 = *(const uint4*)(wbl + 1024 + c * 8);
            const s16x8 A0h = fragpack(ah0.x, ah0.y, ah0.z, ah0.w);
            const s16x8 A0l = fragpack(al0.x, al0.y, al0.z, al0.w);
            const s16x8 A1h = fragpack(ah1.x, ah1.y, ah1.z, ah1.w);
            const s16x8 A1l = fragpack(al1.x, al1.y, al1.z, al1.w);
            acc00 = __builtin_amdgcn_mfma_f32_32x32x16_bf16(A0h, B0, acc00, 0, 0, 0);
            acc01 = __builtin_amdgcn_mfma_f32_32x32x16_bf16(A0h, B1, acc01, 0, 0, 0);
            acc10 = __builtin_amdgcn_mfma_f32_32x32x16_bf16(A1h, B0, acc10, 0, 0, 0);
            acc11 = __builtin_amdgcn_mfma_f32_32x32x16_bf16(A1h, B1, acc11, 0, 0, 0);
            acc00 = __builtin_amdgcn_mfma_f32_32x32x16_bf16(A0l, B0, acc00, 0, 0, 0);
            acc01 = __builtin_amdgcn_mfma_f32_32x32x16_bf16(A0l, B1, acc01, 0, 0, 0);
            acc10 = __builtin_amdgcn_mfma_f32_32x32x16_bf16(A1l, B0, acc10, 0, 0, 0);
            acc11 = __builtin_amdgcn_mfma_f32_32x32x16_bf16(A1l, B1, acc11, 0, 0, 0);
        }
    }

    // ---- epilogue. C/D layout (32x32): col=lane&31 (pixel), row=(j&3)+8*(j>>2)+4*half (oc)
    if constexpr (MODE == 1) {
        __syncthreads();                    // halo reads done; reuse lds for transpose
#define ST1(ACC, MT, RR) { \
        _Pragma("unroll") \
        for (int j = 0; j < 16; j += 2) { \
            const int row = (j & 3) + 8 * (j >> 2) + 4 * half; \
            const int oc = MT * 32 + row; \
            float v0 = ACC[j]     + bias[oc]; \
            float v1 = ACC[j + 1] + bias[oc + 1]; \
            const float a0 = prelu[oc], a1 = prelu[oc + 1]; \
            v0 = fmaxf(v0, 0.f) + a0 * fminf(v0, 0.f); \
            v1 = fmaxf(v1, 0.f) + a1 * fminf(v1, 0.f); \
            const int icp = oc >> 1; \
            lds[((RR) * 32 + icp) * 32 + (colx ^ icp)] = \
                bf16rne(v0) | (bf16rne(v1) << 16); \
        } }
        ST1(acc00, 0, r0) ST1(acc01, 0, r0 + 1) ST1(acc10, 1, r0) ST1(acc11, 1, r0 + 1)
#undef ST1
        __syncthreads();
        const int prow = tid >> 5, pcol = tid & 31;
        uint* o = op + ((size_t)b * PLANE + (size_t)(y0 + prow) * 256 + x0 + pcol) * 32;
        uint d[32];
#pragma unroll
        for (int i = 0; i < 32; i++)
            d[i] = lds[(prow * 32 + i) * 32 + (pcol ^ i)];
#pragma unroll
        for (int k = 0; k < 8; k++)
            *(uint4*)(o + 4 * k) = make_uint4(d[4*k], d[4*k+1], d[4*k+2], d[4*k+3]);
    } else {
#define ST2(ACC, MT, RR) { \
        _Pragma("unroll") \
        for (int j = 0; j < 16; j++) { \
            const int row = (j & 3) + 8 * (j >> 2) + 4 * half; \
            const int oc = MT * 32 + row; \
            of[(((size_t)b * 64 + oc) * 256 + y0 + (RR)) * 256 + x0 + colx] = \
                ACC[j] + bias[oc]; \
        } }
        ST2(acc00, 0, r0) ST2(acc01, 0, r0 + 1) ST2(acc10, 1, r0) ST2(acc11, 1, r0 + 1)
#undef ST2
    }
}

// ---------------- per-pixel channel mean/max ----------------
__global__ __launch_bounds__(256) void chanstats_kernel(
    const float* __restrict__ r, float* __restrict__ amx /*[B,2,HW]*/)
{
    int pix = blockIdx.x * 256 + threadIdx.x;
    int b = blockIdx.y;
    const float* rb = r + (size_t)b * CC * PLANE + pix;
    float s = 0.f, m = -INFINITY;
    for (int c = 0; c < CC; c++) {
        float v = rb[(size_t)c * PLANE];
        s += v; m = fmaxf(m, v);
    }
    amx[(size_t)b * 2 * PLANE + pix] = s * (1.f / CC);
    amx[(size_t)b * 2 * PLANE + PLANE + pix] = m;
}

// ---------------- global average pool: g[b,c] ----------------
__global__ __launch_bounds__(256) void gpool_kernel(
    const float* __restrict__ r, float* __restrict__ g /*[B*C]*/)
{
    int bc = blockIdx.x; // 0..511
    const float* p = r + (size_t)bc * PLANE;
    float s = 0.f;
    for (int i = threadIdx.x; i < PLANE; i += 256) s += p[i];
    for (int off = 32; off > 0; off >>= 1) s += __shfl_down(s, off, 64);
    __shared__ float ls[4];
    int lane = threadIdx.x & 63, wv = threadIdx.x >> 6;
    if (lane == 0) ls[wv] = s;
    __syncthreads();
    if (threadIdx.x == 0)
        g[bc] = (ls[0] + ls[1] + ls[2] + ls[3]) * (1.f / PLANE);
}

// ---------------- spatial-attention 3x3 conv (2ch -> 1ch) ----------------
__global__ __launch_bounds__(256) void saconv_kernel(
    const float* __restrict__ amx, const float* __restrict__ sa_w,
    const float* __restrict__ sa_b, float* __restrict__ smap)
{
    int pix = blockIdx.x * 256 + threadIdx.x;
    int b = blockIdx.y;
    int x = pix & 255, y = pix >> 8;
    float acc = sa_b[0];
    const float* ab = amx + (size_t)b * 2 * PLANE;
#pragma unroll
    for (int c = 0; c < 2; c++)
#pragma unroll
        for (int dy = -1; dy <= 1; dy++)
#pragma unroll
            for (int dx = -1; dx <= 1; dx++) {
                int gx = x + dx; gx = gx < 0 ? 1 : (gx >= WW ? 2 * WW - 2 - gx : gx);
                int gy = y + dy; gy = gy < 0 ? 1 : (gy >= HH ? 2 * HH - 2 - gy : gy);
                acc += sa_w[c * 9 + (dy + 1) * 3 + (dx + 1)] * ab[(size_t)c * PLANE + gy * WW + gx];
            }
    smap[(size_t)b * PLANE + pix] = acc;
}

// ---------------- tiny MLPs: channel attention + hyper kernels ----------------
__global__ __launch_bounds__(256) void mlp_kernel(
    const float* __restrict__ h, const float* __restrict__ g,
    const float* __restrict__ ca_w1, const float* __restrict__ ca_b1,
    const float* __restrict__ ca_a,
    const float* __restrict__ ca_w2, const float* __restrict__ ca_b2,
    const float* __restrict__ fc_w, const float* __restrict__ fc_b,
    const float* __restrict__ k1_w, const float* __restrict__ k1_b,
    const float* __restrict__ k2_w, const float* __restrict__ k2_b,
    const float* __restrict__ k3_w, const float* __restrict__ k3_b,
    float* __restrict__ kernA, float* __restrict__ kernB /*[B,64,64]*/)
{
    int b = blockIdx.x, tid = threadIdx.x;
    __shared__ float gb[64], t16[16], u32[32], v32[32], cg1[32], casig[64];

    if (tid < 64) gb[tid] = g[b * 64 + tid];
    __syncthreads();

    if (tid < 16) {
        float s = fc_b[tid];
        for (int j = 0; j < 16; j++) s += fc_w[tid * 16 + j] * h[b * 16 + j];
        t16[tid] = s >= 0.f ? s : 0.01f * s;
    }
    if (tid < 32) {
        float c1 = ca_b1[tid];
        for (int j = 0; j < 64; j++) c1 += ca_w1[tid * 64 + j] * gb[j];
        cg1[tid] = fmaxf(c1, 0.f) + ca_a[tid] * fminf(c1, 0.f);
    }
    __syncthreads();
    if (tid < 32) {
        float s = k1_b[tid];
        for (int j = 0; j < 16; j++) s += k1_w[tid * 16 + j] * t16[j];
        u32[tid] = s >= 0.f ? s : 0.01f * s;
    }
    if (tid < 64) {
        float c2 = ca_b2[tid];
        for (int j = 0; j < 32; j++) c2 += ca_w2[tid * 32 + j] * cg1[j];
        casig[tid] = 1.f / (1.f + expf(-c2));
    }
    __syncthreads();
    if (tid < 32) {
        float s = k2_b[tid];
        for (int j = 0; j < 32; j++) s += k2_w[tid * 32 + j] * u32[j];
        v32[tid] = s >= 0.f ? s : 0.01f * s;
    }
    __syncthreads();
    for (int o = tid; o < 8192; o += 256) {
        float s = k3_b[o];
        for (int j = 0; j < 32; j++) s += k3_w[(size_t)o * 32 + j] * v32[j];
        int oc = o >> 7;
        int i = o & 127;
        if (i < 64) kernA[((size_t)b * 64 + oc) * 64 + i] = s;
        else        kernB[((size_t)b * 64 + oc) * 64 + (i - 64)] = s * casig[i - 64];
    }
}

// ---------------- final: out = x + hc_bias + sig(s)*(A.r) + (B.r) ----------------
__global__ __launch_bounds__(256) void final_kernel(
    const float* __restrict__ x, const float* __restrict__ r,
    const float* __restrict__ smap,
    const float* __restrict__ kernA, const float* __restrict__ kernB,
    const float* __restrict__ hc_bias,
    float* __restrict__ out)
{
    const int tid = threadIdx.x;
    const int pix = blockIdx.x * 256 + tid;
    const int og = blockIdx.y * 32;
    const int b = blockIdx.z;

    __shared__ float kA[64][32], kB[64][32];
    for (int idx = tid; idx < 64 * 32; idx += 256) {
        int oc = idx & 31, c = idx >> 5;
        kA[c][oc] = kernA[((size_t)b * 64 + og + oc) * 64 + c];
        kB[c][oc] = kernB[((size_t)b * 64 + og + oc) * 64 + c];
    }
    __syncthreads();

    float accA[32], accB[32];
#pragma unroll
    for (int i = 0; i < 32; i++) { accA[i] = 0.f; accB[i] = 0.f; }

    const float* rb = r + (size_t)b * CC * PLANE + pix;
    for (int c = 0; c < CC; c++) {
        float rv = rb[(size_t)c * PLANE];
#pragma unroll
        for (int oc = 0; oc < 32; oc++) {
            accA[oc] += kA[c][oc] * rv;
            accB[oc] += kB[c][oc] * rv;
        }
    }

    float sv = smap[(size_t)b * PLANE + pix];
    float sig = 1.f / (1.f + expf(-sv));
    const float* xb = x + ((size_t)b * CC + og) * PLANE + pix;
    float* ob = out + ((size_t)b * CC + og) * PLANE + pix;
#pragma unroll
    for (int oc = 0; oc < 32; oc++) {
        ob[(size_t)oc * PLANE] = xb[(size_t)oc * PLANE] + hc_bias[og + oc]
                               + sig * accA[oc] + accB[oc];
    }
}

extern "C" void kernel_launch(void* const* d_in, const int* in_sizes, int n_in,
                              void* d_out, int out_size, void* d_ws, size_t ws_size,
                              hipStream_t stream) {
    const float* x   = (const float*)d_in[0];
    const float* h   = (const float*)d_in[1];
    const float* c1w = (const float*)d_in[2];
    const float* c1b = (const float*)d_in[3];
    const float* pa  = (const float*)d_in[4];
    const float* c2w = (const float*)d_in[5];
    const float* c2b = (const float*)d_in[6];
    const float* saw = (const float*)d_in[7];
    const float* sab = (const float*)d_in[8];
    const float* cw1 = (const float*)d_in[9];
    const float* cb1 = (const float*)d_in[10];
    const float* caa = (const float*)d_in[11];
    const float* cw2 = (const float*)d_in[12];
    const float* cb2 = (const float*)d_in[13];
    const float* fcw = (const float*)d_in[14];
    const float* fcb = (const float*)d_in[15];
    const float* k1w = (const float*)d_in[16];
    const float* k1b = (const float*)d_in[17];
    const float* k2w = (const float*)d_in[18];
    const float* k2b = (const float*)d_in[19];
    const float* k3w = (const float*)d_in[20];
    const float* k3b = (const float*)d_in[21];
    const float* hcb = (const float*)d_in[22];
    float* out = (float*)d_out;

    char* ws = (char*)d_ws;
    const size_t SZ_Q = (size_t)8 * PLANE * 32 * 4;   // 67,108,864 (NHWC packed)
    uint*  xp  = (uint*)ws;                           // x repacked
    uint*  r1p = (uint*)(ws + SZ_Q);                  // conv1 out, NHWC packed
    float* r   = (float*)(ws + 2 * SZ_Q);             // conv2 out, fp32 NCHW
    // small buffers reuse [0, 2*SZ_Q) AFTER convs complete (xp, r1p dead)
    float* amx   = (float*)ws;
    float* smap  = (float*)(ws + (size_t)8 * 2 * PLANE * 4);
    float* g     = (float*)(ws + (size_t)8 * 3 * PLANE * 4);
    float* kernA = (float*)(ws + (size_t)8 * 3 * PLANE * 4 + 4096);
    float* kernB = kernA + (size_t)8 * 64 * 64;

    // weight packs live in d_out (dead until final_kernel overwrites it)
    uint* wsp = (uint*)d_out;
    uint* wh1 = wsp;          uint* wl1 = wsp + 18432;
    uint* wh2 = wsp + 36864;  uint* wl2 = wsp + 55296;

    wprep_kernel<<<dim3(72, 2), 256, 0, stream>>>(c1w, c2w, wh1, wl1, wh2, wl2);
    xrepack_kernel<<<dim3(PLANE / 256, 8), 256, 0, stream>>>(x, xp);

    dim3 cgrid(WW / 32, HH / 8, 8);  // (8, 32, 8)
    conv_mfma<1><<<cgrid, 256, 0, stream>>>(xp, wh1, wl1, c1b, pa, r1p, nullptr);
    conv_mfma<2><<<cgrid, 256, 0, stream>>>(r1p, wh2, wl2, c2b, nullptr, nullptr, r);

    chanstats_kernel<<<dim3(PLANE / 256, 8), 256, 0, stream>>>(r, amx);
    gpool_kernel<<<512, 256, 0, stream>>>(r, g);
    saconv_kernel<<<dim3(PLANE / 256, 8), 256, 0, stream>>>(amx, saw, sab, smap);
    mlp_kernel<<<8, 256, 0, stream>>>(h, g, cw1, cb1, caa, cw2, cb2,
                                      fcw, fcb, k1w, k1b, k2w, k2b, k3w, k3b,
                                      kernA, kernB);
    final_kernel<<<dim3(PLANE / 256, 2, 8), 256, 0, stream>>>(
        x, r, smap, kernA, kernB, hcb, out);
}

// Round 7
// 949.395 us; speedup vs baseline: 1.1205x; 1.0312x over previous
//
#include <hip/hip_runtime.h>
#include <math.h>

#define HH 256
#define WW 256
#define CC 64
#define PLANE (HH*WW)

typedef short s16x8 __attribute__((ext_vector_type(8)));
typedef float f32x16 __attribute__((ext_vector_type(16)));
typedef unsigned int uint;
typedef uint u32x4v __attribute__((ext_vector_type(4)));

__device__ inline uint bf16rne(float f) {
    uint u = __float_as_uint(f);
    return (u + 0x7FFFu + ((u >> 16) & 1u)) >> 16;
}
__device__ inline float bf16val(uint h) { return __uint_as_float(h << 16); }
__device__ inline s16x8 fragpack(uint4 q) {
    u32x4v t = {q.x, q.y, q.z, q.w};
    return __builtin_bit_cast(s16x8, t);
}
__device__ inline void gload_lds16(const uint* g, uint* l) {
    __builtin_amdgcn_global_load_lds(
        (const __attribute__((address_space(1))) uint*)g,
        (__attribute__((address_space(3))) uint*)l, 16, 0, 0);
}

// ---------------- weight prep: split fp32 W into bf16 hi/lo, pack ic-pairs ----
__global__ __launch_bounds__(256) void wprep_kernel(
    const float* __restrict__ w1, const float* __restrict__ w2,
    uint* __restrict__ wh1, uint* __restrict__ wl1,
    uint* __restrict__ wh2, uint* __restrict__ wl2)
{
    const int idx = blockIdx.x * 256 + threadIdx.x;      // 0..18431
    const float* w = blockIdx.y ? w2 : w1;
    uint* wh = blockIdx.y ? wh2 : wh1;
    uint* wl = blockIdx.y ? wl2 : wl1;
    const int tap = idx >> 11;           // 9
    const int oc  = (idx >> 5) & 63;     // 64
    const int icp = idx & 31;            // 32 ic-pairs
    float w0 = w[(oc * 64 + 2 * icp) * 9 + tap];
    float w1v = w[(oc * 64 + 2 * icp + 1) * 9 + tap];
    uint h0 = bf16rne(w0); float l0 = w0 - bf16val(h0);
    uint h1 = bf16rne(w1v); float l1 = w1v - bf16val(h1);
    wh[idx] = h0 | (h1 << 16);
    wl[idx] = bf16rne(l0) | (bf16rne(l1) << 16);
}

// ---------------- x repack: fp32 NCHW -> bf16-pair NHWC packed ----------------
__global__ __launch_bounds__(256) void xrepack_kernel(
    const float* __restrict__ x, uint* __restrict__ xp)
{
    const int tid = threadIdx.x;
    const size_t px = (size_t)blockIdx.x * 256 + tid;
    const int b = blockIdx.y;
    const float* xb = x + (size_t)b * CC * PLANE + px;
    uint* o = xp + ((size_t)b * PLANE + px) * 32;
    uint d[32];
#pragma unroll
    for (int icp = 0; icp < 32; icp++) {
        float v0 = xb[(size_t)(2 * icp) * PLANE];
        float v1 = xb[(size_t)(2 * icp + 1) * PLANE];
        d[icp] = bf16rne(v0) | (bf16rne(v1) << 16);
    }
#pragma unroll
    for (int k = 0; k < 8; k++)
        *(uint4*)(o + 4 * k) = make_uint4(d[4*k], d[4*k+1], d[4*k+2], d[4*k+3]);
}

// ---------------- conv 3x3 reflect via MFMA, LDS halo, per-tap batched loads --
// block: 4 waves; tile 64 oc x 8 rows x 32 cols. wave w: rows {2w, 2w+1}.
// Per tap: batch-load 8 B-frags (ds_read_b128) + 16 W-frags (global dwordx4)
// into static register arrays, THEN 32 MFMAs -> one latency exposure per tap.
// MODE 1: PReLU + NHWC-packed out. MODE 2: fp32 NCHW out + fused chan mean/max.
#define HPIX 340                 // 10*34 halo pixels
#define HCHUNK (HPIX*8)          // 16B chunks = 2720
template<int MODE>
__global__ __launch_bounds__(256, 2) void conv_mfma(
    const uint* __restrict__ xin,   // [B][H][W][32] bf16-pair dwords
    const uint* __restrict__ wh, const uint* __restrict__ wl,
    const float* __restrict__ bias, const float* __restrict__ prelu,
    uint* __restrict__ op, float* __restrict__ of, float* __restrict__ amx)
{
    __shared__ uint lds[HPIX * 32];          // 43,520 B
    const int tid  = threadIdx.x;
    const int lane = tid & 63;
    const int wid  = tid >> 6;
    const int x0 = blockIdx.x * 32;
    const int y0 = blockIdx.y * 8;
    const int b  = blockIdx.z;
    const int colx = lane & 31;
    const int half = lane >> 5;
    const int r0 = wid * 2;

    // ---- stage halo: chunk k -> LDS byte k*16 (linear), source pre-swizzled
    {
        const uint* gb = xin + (size_t)b * PLANE * 32;
#pragma unroll
        for (int iter = 0; iter < 11; iter++) {
            const int k = iter * 256 + tid;
            if (iter < 10 || k < HCHUNK) {
                const int pix = k >> 3;
                const int slot = k & 7;
                const int hrow = pix / 34;
                const int hcol = pix - hrow * 34;
                int gy = y0 - 1 + hrow; gy = gy < 0 ? 1 : (gy > 255 ? 254 : gy);
                int gx = x0 - 1 + hcol; gx = gx < 0 ? 1 : (gx > 255 ? 254 : gx);
                const int c2 = slot ^ (pix & 7);    // involution
                gload_lds16(gb + ((size_t)(gy * 256 + gx)) * 32 + c2 * 4,
                            &lds[(iter * 256 + wid * 64) * 4]);
            }
        }
    }
    __syncthreads();

    f32x16 acc00 = (f32x16)0.f, acc01 = (f32x16)0.f;   // [Mtile][row]
    f32x16 acc10 = (f32x16)0.f, acc11 = (f32x16)0.f;

    const uint* wth = wh + colx * 32 + half * 4;
    const uint* wtl = wl + colx * 32 + half * 4;

#pragma unroll
    for (int tap = 0; tap < 9; tap++) {
        const int dy = tap / 3, dx = tap % 3;
        const int pix0 = (r0 + dy) * 34 + dx + colx;   // output row r0
        const int pix1 = pix0 + 34;                    // output row r0+1

        uint4 B0[4], B1[4], H0[4], H1[4], L0[4], L1[4];
#pragma unroll
        for (int c = 0; c < 4; c++) {
            const int c2 = c * 2 + half;
            B0[c] = *(const uint4*)&lds[(pix0 * 8 + (c2 ^ (pix0 & 7))) * 4];
            B1[c] = *(const uint4*)&lds[(pix1 * 8 + (c2 ^ (pix1 & 7))) * 4];
        }
#pragma unroll
        for (int c = 0; c < 4; c++) {
            H0[c] = *(const uint4*)(wth + tap * 2048 + c * 8);
            H1[c] = *(const uint4*)(wth + tap * 2048 + 1024 + c * 8);
        }
#pragma unroll
        for (int c = 0; c < 4; c++) {
            L0[c] = *(const uint4*)(wtl + tap * 2048 + c * 8);
            L1[c] = *(const uint4*)(wtl + tap * 2048 + 1024 + c * 8);
        }
#pragma unroll
        for (int c = 0; c < 4; c++) {
            const s16x8 b0 = fragpack(B0[c]), b1 = fragpack(B1[c]);
            acc00 = __builtin_amdgcn_mfma_f32_32x32x16_bf16(fragpack(H0[c]), b0, acc00, 0, 0, 0);
            acc01 = __builtin_amdgcn_mfma_f32_32x32x16_bf16(fragpack(H0[c]), b1, acc01, 0, 0, 0);
            acc10 = __builtin_amdgcn_mfma_f32_32x32x16_bf16(fragpack(H1[c]), b0, acc10, 0, 0, 0);
            acc11 = __builtin_amdgcn_mfma_f32_32x32x16_bf16(fragpack(H1[c]), b1, acc11, 0, 0, 0);
        }
#pragma unroll
        for (int c = 0; c < 4; c++) {
            const s16x8 b0 = fragpack(B0[c]), b1 = fragpack(B1[c]);
            acc00 = __builtin_amdgcn_mfma_f32_32x32x16_bf16(fragpack(L0[c]), b0, acc00, 0, 0, 0);
            acc01 = __builtin_amdgcn_mfma_f32_32x32x16_bf16(fragpack(L0[c]), b1, acc01, 0, 0, 0);
            acc10 = __builtin_amdgcn_mfma_f32_32x32x16_bf16(fragpack(L1[c]), b0, acc10, 0, 0, 0);
            acc11 = __builtin_amdgcn_mfma_f32_32x32x16_bf16(fragpack(L1[c]), b1, acc11, 0, 0, 0);
        }
    }

    // ---- epilogue. C/D layout (32x32): col=lane&31 (pixel), row=(j&3)+8*(j>>2)+4*half (oc)
    if constexpr (MODE == 1) {
        __syncthreads();                    // halo reads done; reuse lds for transpose
#define ST1(ACC, MT, RR) { \
        _Pragma("unroll") \
        for (int j = 0; j < 16; j += 2) { \
            const int row = (j & 3) + 8 * (j >> 2) + 4 * half; \
            const int oc = MT * 32 + row; \
            float v0 = ACC[j]     + bias[oc]; \
            float v1 = ACC[j + 1] + bias[oc + 1]; \
            const float a0 = prelu[oc], a1 = prelu[oc + 1]; \
            v0 = fmaxf(v0, 0.f) + a0 * fminf(v0, 0.f); \
            v1 = fmaxf(v1, 0.f) + a1 * fminf(v1, 0.f); \
            const int icp = oc >> 1; \
            lds[((RR) * 32 + icp) * 32 + (colx ^ icp)] = \
                bf16rne(v0) | (bf16rne(v1) << 16); \
        } }
        ST1(acc00, 0, r0) ST1(acc01, 0, r0 + 1) ST1(acc10, 1, r0) ST1(acc11, 1, r0 + 1)
#undef ST1
        __syncthreads();
        const int prow = tid >> 5, pcol = tid & 31;
        uint* o = op + ((size_t)b * PLANE + (size_t)(y0 + prow) * 256 + x0 + pcol) * 32;
        uint d[32];
#pragma unroll
        for (int i = 0; i < 32; i++)
            d[i] = lds[(prow * 32 + i) * 32 + (pcol ^ i)];
#pragma unroll
        for (int k = 0; k < 8; k++)
            *(uint4*)(o + 4 * k) = make_uint4(d[4*k], d[4*k+1], d[4*k+2], d[4*k+3]);
    } else {
        // fp32 NCHW out + fused per-pixel channel mean/max (lane + xor-32 partner
        // together hold all 64 channels of one pixel)
#define ST2(ACCa, ACCb, RR) { \
        float s_ = 0.f, m_ = -INFINITY; \
        _Pragma("unroll") \
        for (int j = 0; j < 16; j++) { \
            const int row = (j & 3) + 8 * (j >> 2) + 4 * half; \
            float v = ACCa[j] + bias[row]; \
            of[(((size_t)b * 64 + row) * 256 + y0 + (RR)) * 256 + x0 + colx] = v; \
            s_ += v; m_ = fmaxf(m_, v); \
        } \
        _Pragma("unroll") \
        for (int j = 0; j < 16; j++) { \
            const int row = (j & 3) + 8 * (j >> 2) + 4 * half; \
            float v = ACCb[j] + bias[32 + row]; \
            of[(((size_t)b * 64 + 32 + row) * 256 + y0 + (RR)) * 256 + x0 + colx] = v; \
            s_ += v; m_ = fmaxf(m_, v); \
        } \
        s_ += __shfl_xor(s_, 32, 64); \
        m_ = fmaxf(m_, __shfl_xor(m_, 32, 64)); \
        if (half == 0) { \
            amx[(size_t)b * 2 * PLANE + (size_t)(y0 + (RR)) * 256 + x0 + colx] = s_ * (1.f / 64.f); \
            amx[(size_t)b * 2 * PLANE + PLANE + (size_t)(y0 + (RR)) * 256 + x0 + colx] = m_; \
        } }
        ST2(acc00, acc10, r0) ST2(acc01, acc11, r0 + 1)
#undef ST2
    }
}

// ---------------- global average pool: g[b,c] ----------------
__global__ __launch_bounds__(256) void gpool_kernel(
    const float* __restrict__ r, float* __restrict__ g /*[B*C]*/)
{
    int bc = blockIdx.x; // 0..511
    const float* p = r + (size_t)bc * PLANE;
    float s = 0.f;
    for (int i = threadIdx.x; i < PLANE; i += 256) s += p[i];
    for (int off = 32; off > 0; off >>= 1) s += __shfl_down(s, off, 64);
    __shared__ float ls[4];
    int lane = threadIdx.x & 63, wv = threadIdx.x >> 6;
    if (lane == 0) ls[wv] = s;
    __syncthreads();
    if (threadIdx.x == 0)
        g[bc] = (ls[0] + ls[1] + ls[2] + ls[3]) * (1.f / PLANE);
}

// ---------------- spatial-attention 3x3 conv (2ch -> 1ch) ----------------
__global__ __launch_bounds__(256) void saconv_kernel(
    const float* __restrict__ amx, const float* __restrict__ sa_w,
    const float* __restrict__ sa_b, float* __restrict__ smap)
{
    int pix = blockIdx.x * 256 + threadIdx.x;
    int b = blockIdx.y;
    int x = pix & 255, y = pix >> 8;
    float acc = sa_b[0];
    const float* ab = amx + (size_t)b * 2 * PLANE;
#pragma unroll
    for (int c = 0; c < 2; c++)
#pragma unroll
        for (int dy = -1; dy <= 1; dy++)
#pragma unroll
            for (int dx = -1; dx <= 1; dx++) {
                int gx = x + dx; gx = gx < 0 ? 1 : (gx >= WW ? 2 * WW - 2 - gx : gx);
                int gy = y + dy; gy = gy < 0 ? 1 : (gy >= HH ? 2 * HH - 2 - gy : gy);
                acc += sa_w[c * 9 + (dy + 1) * 3 + (dx + 1)] * ab[(size_t)c * PLANE + gy * WW + gx];
            }
    smap[(size_t)b * PLANE + pix] = acc;
}

// ---------------- tiny MLPs: channel attention + hyper kernels ----------------
__global__ __launch_bounds__(256) void mlp_kernel(
    const float* __restrict__ h, const float* __restrict__ g,
    const float* __restrict__ ca_w1, const float* __restrict__ ca_b1,
    const float* __restrict__ ca_a,
    const float* __restrict__ ca_w2, const float* __restrict__ ca_b2,
    const float* __restrict__ fc_w, const float* __restrict__ fc_b,
    const float* __restrict__ k1_w, const float* __restrict__ k1_b,
    const float* __restrict__ k2_w, const float* __restrict__ k2_b,
    const float* __restrict__ k3_w, const float* __restrict__ k3_b,
    float* __restrict__ kernA, float* __restrict__ kernB /*[B,64,64]*/)
{
    int b = blockIdx.x, tid = threadIdx.x;
    __shared__ float gb[64], t16[16], u32[32], v32[32], cg1[32], casig[64];

    if (tid < 64) gb[tid] = g[b * 64 + tid];
    __syncthreads();

    if (tid < 16) {
        float s = fc_b[tid];
        for (int j = 0; j < 16; j++) s += fc_w[tid * 16 + j] * h[b * 16 + j];
        t16[tid] = s >= 0.f ? s : 0.01f * s;
    }
    if (tid < 32) {
        float c1 = ca_b1[tid];
        for (int j = 0; j < 64; j++) c1 += ca_w1[tid * 64 + j] * gb[j];
        cg1[tid] = fmaxf(c1, 0.f) + ca_a[tid] * fminf(c1, 0.f);
    }
    __syncthreads();
    if (tid < 32) {
        float s = k1_b[tid];
        for (int j = 0; j < 16; j++) s += k1_w[tid * 16 + j] * t16[j];
        u32[tid] = s >= 0.f ? s : 0.01f * s;
    }
    if (tid < 64) {
        float c2 = ca_b2[tid];
        for (int j = 0; j < 32; j++) c2 += ca_w2[tid * 32 + j] * cg1[j];
        casig[tid] = 1.f / (1.f + expf(-c2));
    }
    __syncthreads();
    if (tid < 32) {
        float s = k2_b[tid];
        for (int j = 0; j < 32; j++) s += k2_w[tid * 32 + j] * u32[j];
        v32[tid] = s >= 0.f ? s : 0.01f * s;
    }
    __syncthreads();
    for (int o = tid; o < 8192; o += 256) {
        float s = k3_b[o];
        for (int j = 0; j < 32; j++) s += k3_w[(size_t)o * 32 + j] * v32[j];
        int oc = o >> 7;
        int i = o & 127;
        if (i < 64) kernA[((size_t)b * 64 + oc) * 64 + i] = s;
        else        kernB[((size_t)b * 64 + oc) * 64 + (i - 64)] = s * casig[i - 64];
    }
}

// ---------------- final: out = x + hc_bias + sig(s)*(A.r) + (B.r) ----------------
__global__ __launch_bounds__(256) void final_kernel(
    const float* __restrict__ x, const float* __restrict__ r,
    const float* __restrict__ smap,
    const float* __restrict__ kernA, const float* __restrict__ kernB,
    const float* __restrict__ hc_bias,
    float* __restrict__ out)
{
    const int tid = threadIdx.x;
    const int pix = blockIdx.x * 256 + tid;
    const int og = blockIdx.y * 32;
    const int b = blockIdx.z;

    __shared__ float kA[64][32], kB[64][32];
    for (int idx = tid; idx < 64 * 32; idx += 256) {
        int oc = idx & 31, c = idx >> 5;
        kA[c][oc] = kernA[((size_t)b * 64 + og + oc) * 64 + c];
        kB[c][oc] = kernB[((size_t)b * 64 + og + oc) * 64 + c];
    }
    __syncthreads();

    float accA[32], accB[32];
#pragma unroll
    for (int i = 0; i < 32; i++) { accA[i] = 0.f; accB[i] = 0.f; }

    const float* rb = r + (size_t)b * CC * PLANE + pix;
    for (int c = 0; c < CC; c++) {
        float rv = rb[(size_t)c * PLANE];
#pragma unroll
        for (int oc = 0; oc < 32; oc++) {
            accA[oc] += kA[c][oc] * rv;
            accB[oc] += kB[c][oc] * rv;
        }
    }

    float sv = smap[(size_t)b * PLANE + pix];
    float sig = 1.f / (1.f + expf(-sv));
    const float* xb = x + ((size_t)b * CC + og) * PLANE + pix;
    float* ob = out + ((size_t)b * CC + og) * PLANE + pix;
#pragma unroll
    for (int oc = 0; oc < 32; oc++) {
        ob[(size_t)oc * PLANE] = xb[(size_t)oc * PLANE] + hc_bias[og + oc]
                               + sig * accA[oc] + accB[oc];
    }
}

extern "C" void kernel_launch(void* const* d_in, const int* in_sizes, int n_in,
                              void* d_out, int out_size, void* d_ws, size_t ws_size,
                              hipStream_t stream) {
    const float* x   = (const float*)d_in[0];
    const float* h   = (const float*)d_in[1];
    const float* c1w = (const float*)d_in[2];
    const float* c1b = (const float*)d_in[3];
    const float* pa  = (const float*)d_in[4];
    const float* c2w = (const float*)d_in[5];
    const float* c2b = (const float*)d_in[6];
    const float* saw = (const float*)d_in[7];
    const float* sab = (const float*)d_in[8];
    const float* cw1 = (const float*)d_in[9];
    const float* cb1 = (const float*)d_in[10];
    const float* caa = (const float*)d_in[11];
    const float* cw2 = (const float*)d_in[12];
    const float* cb2 = (const float*)d_in[13];
    const float* fcw = (const float*)d_in[14];
    const float* fcb = (const float*)d_in[15];
    const float* k1w = (const float*)d_in[16];
    const float* k1b = (const float*)d_in[17];
    const float* k2w = (const float*)d_in[18];
    const float* k2b = (const float*)d_in[19];
    const float* k3w = (const float*)d_in[20];
    const float* k3b = (const float*)d_in[21];
    const float* hcb = (const float*)d_in[22];
    float* out = (float*)d_out;

    char* ws = (char*)d_ws;
    const size_t SZ_Q = (size_t)8 * PLANE * 32 * 4;   // 67,108,864 (NHWC packed)
    uint*  xp  = (uint*)ws;                           // x repacked
    uint*  r1p = (uint*)(ws + SZ_Q);                  // conv1 out, NHWC packed
    float* r   = (float*)(ws + 2 * SZ_Q);             // conv2 out, fp32 NCHW
    // small buffers reuse [0, 2*SZ_Q) AFTER their producers' inputs are dead
    float* amx   = (float*)ws;                        // written by conv2 (xp dead then)
    float* smap  = (float*)(ws + (size_t)8 * 2 * PLANE * 4);
    float* g     = (float*)(ws + (size_t)8 * 3 * PLANE * 4);
    float* kernA = (float*)(ws + (size_t)8 * 3 * PLANE * 4 + 4096);
    float* kernB = kernA + (size_t)8 * 64 * 64;

    // weight packs live in d_out (dead until final_kernel overwrites it)
    uint* wsp = (uint*)d_out;
    uint* wh1 = wsp;          uint* wl1 = wsp + 18432;
    uint* wh2 = wsp + 36864;  uint* wl2 = wsp + 55296;

    wprep_kernel<<<dim3(72, 2), 256, 0, stream>>>(c1w, c2w, wh1, wl1, wh2, wl2);
    xrepack_kernel<<<dim3(PLANE / 256, 8), 256, 0, stream>>>(x, xp);

    dim3 cgrid(WW / 32, HH / 8, 8);  // (8, 32, 8)
    conv_mfma<1><<<cgrid, 256, 0, stream>>>(xp, wh1, wl1, c1b, pa, r1p, nullptr, nullptr);
    conv_mfma<2><<<cgrid, 256, 0, stream>>>(r1p, wh2, wl2, c2b, nullptr, nullptr, r, amx);

    gpool_kernel<<<512, 256, 0, stream>>>(r, g);
    saconv_kernel<<<dim3(PLANE / 256, 8), 256, 0, stream>>>(amx, saw, sab, smap);
    mlp_kernel<<<8, 256, 0, stream>>>(h, g, cw1, cb1, caa, cw2, cb2,
                                      fcw, fcb, k1w, k1b, k2w, k2b, k3w, k3b,
                                      kernA, kernB);
    final_kernel<<<dim3(PLANE / 256, 2, 8), 256, 0, stream>>>(
        x, r, smap, kernA, kernB, hcb, out);
}

// Round 8
// 913.518 us; speedup vs baseline: 1.1645x; 1.0393x over previous
//
#include <hip/hip_runtime.h>
#include <math.h>

#define HH 256
#define WW 256
#define CC 64
#define PLANE (HH*WW)

typedef short s16x8 __attribute__((ext_vector_type(8)));
typedef float f32x16 __attribute__((ext_vector_type(16)));
typedef unsigned int uint;
typedef uint u32x4v __attribute__((ext_vector_type(4)));

__device__ inline uint bf16rne(float f) {
    uint u = __float_as_uint(f);
    return (u + 0x7FFFu + ((u >> 16) & 1u)) >> 16;
}
__device__ inline float bf16val(uint h) { return __uint_as_float(h << 16); }
__device__ inline s16x8 fragpack(uint4 q) {
    u32x4v t = {q.x, q.y, q.z, q.w};
    return __builtin_bit_cast(s16x8, t);
}
__device__ inline void gload_lds16(const uint* g, uint* l) {
    __builtin_amdgcn_global_load_lds(
        (const __attribute__((address_space(1))) uint*)g,
        (__attribute__((address_space(3))) uint*)l, 16, 0, 0);
}

// ---------------- weight prep: split fp32 W into bf16 hi/lo, pack ic-pairs ----
__global__ __launch_bounds__(256) void wprep_kernel(
    const float* __restrict__ w1, const float* __restrict__ w2,
    uint* __restrict__ wh1, uint* __restrict__ wl1,
    uint* __restrict__ wh2, uint* __restrict__ wl2)
{
    const int idx = blockIdx.x * 256 + threadIdx.x;      // 0..18431
    const float* w = blockIdx.y ? w2 : w1;
    uint* wh = blockIdx.y ? wh2 : wh1;
    uint* wl = blockIdx.y ? wl2 : wl1;
    const int tap = idx >> 11;           // 9
    const int oc  = (idx >> 5) & 63;     // 64
    const int icp = idx & 31;            // 32 ic-pairs
    float w0 = w[(oc * 64 + 2 * icp) * 9 + tap];
    float w1v = w[(oc * 64 + 2 * icp + 1) * 9 + tap];
    uint h0 = bf16rne(w0); float l0 = w0 - bf16val(h0);
    uint h1 = bf16rne(w1v); float l1 = w1v - bf16val(h1);
    wh[idx] = h0 | (h1 << 16);
    wl[idx] = bf16rne(l0) | (bf16rne(l1) << 16);
}

// ---------------- x repack: fp32 NCHW -> bf16-pair NHWC packed ----------------
__global__ __launch_bounds__(256) void xrepack_kernel(
    const float* __restrict__ x, uint* __restrict__ xp)
{
    const int tid = threadIdx.x;
    const size_t px = (size_t)blockIdx.x * 256 + tid;
    const int b = blockIdx.y;
    const float* xb = x + (size_t)b * CC * PLANE + px;
    uint* o = xp + ((size_t)b * PLANE + px) * 32;
    uint d[32];
#pragma unroll
    for (int icp = 0; icp < 32; icp++) {
        float v0 = xb[(size_t)(2 * icp) * PLANE];
        float v1 = xb[(size_t)(2 * icp + 1) * PLANE];
        d[icp] = bf16rne(v0) | (bf16rne(v1) << 16);
    }
#pragma unroll
    for (int k = 0; k < 8; k++)
        *(uint4*)(o + 4 * k) = make_uint4(d[4*k], d[4*k+1], d[4*k+2], d[4*k+3]);
}

// ---------------- conv 3x3 reflect via MFMA, LDS halo, per-tap batched loads --
// MODE 1: PReLU + NHWC-packed (hi only) out.
// MODE 2: NHWC-packed hi/lo out + fused per-pixel channel mean/max (amx).
#define HPIX 340                 // 10*34 halo pixels
#define HCHUNK (HPIX*8)          // 16B chunks = 2720
template<int MODE>
__global__ __launch_bounds__(256, 2) void conv_mfma(
    const uint* __restrict__ xin,   // [B][H][W][32] bf16-pair dwords
    const uint* __restrict__ wh, const uint* __restrict__ wl,
    const float* __restrict__ bias, const float* __restrict__ prelu,
    uint* __restrict__ op, uint* __restrict__ op2, float* __restrict__ amx)
{
    __shared__ uint lds[(MODE == 2) ? 16384 : HPIX * 32];
    const int tid  = threadIdx.x;
    const int lane = tid & 63;
    const int wid  = tid >> 6;
    const int x0 = blockIdx.x * 32;
    const int y0 = blockIdx.y * 8;
    const int b  = blockIdx.z;
    const int colx = lane & 31;
    const int half = lane >> 5;
    const int r0 = wid * 2;

    // ---- stage halo: chunk k -> LDS byte k*16 (linear), source pre-swizzled
    {
        const uint* gb = xin + (size_t)b * PLANE * 32;
#pragma unroll
        for (int iter = 0; iter < 11; iter++) {
            const int k = iter * 256 + tid;
            if (iter < 10 || k < HCHUNK) {
                const int pix = k >> 3;
                const int slot = k & 7;
                const int hrow = pix / 34;
                const int hcol = pix - hrow * 34;
                int gy = y0 - 1 + hrow; gy = gy < 0 ? 1 : (gy > 255 ? 254 : gy);
                int gx = x0 - 1 + hcol; gx = gx < 0 ? 1 : (gx > 255 ? 254 : gx);
                const int c2 = slot ^ (pix & 7);    // involution
                gload_lds16(gb + ((size_t)(gy * 256 + gx)) * 32 + c2 * 4,
                            &lds[(iter * 256 + wid * 64) * 4]);
            }
        }
    }
    __syncthreads();

    f32x16 acc00 = (f32x16)0.f, acc01 = (f32x16)0.f;   // [Mtile][row]
    f32x16 acc10 = (f32x16)0.f, acc11 = (f32x16)0.f;

    const uint* wth = wh + colx * 32 + half * 4;
    const uint* wtl = wl + colx * 32 + half * 4;

#pragma unroll
    for (int tap = 0; tap < 9; tap++) {
        const int dy = tap / 3, dx = tap % 3;
        const int pix0 = (r0 + dy) * 34 + dx + colx;   // output row r0
        const int pix1 = pix0 + 34;                    // output row r0+1

        uint4 B0[4], B1[4], H0[4], H1[4], L0[4], L1[4];
#pragma unroll
        for (int c = 0; c < 4; c++) {
            const int c2 = c * 2 + half;
            B0[c] = *(const uint4*)&lds[(pix0 * 8 + (c2 ^ (pix0 & 7))) * 4];
            B1[c] = *(const uint4*)&lds[(pix1 * 8 + (c2 ^ (pix1 & 7))) * 4];
        }
#pragma unroll
        for (int c = 0; c < 4; c++) {
            H0[c] = *(const uint4*)(wth + tap * 2048 + c * 8);
            H1[c] = *(const uint4*)(wth + tap * 2048 + 1024 + c * 8);
        }
#pragma unroll
        for (int c = 0; c < 4; c++) {
            L0[c] = *(const uint4*)(wtl + tap * 2048 + c * 8);
            L1[c] = *(const uint4*)(wtl + tap * 2048 + 1024 + c * 8);
        }
#pragma unroll
        for (int c = 0; c < 4; c++) {
            const s16x8 b0 = fragpack(B0[c]), b1 = fragpack(B1[c]);
            acc00 = __builtin_amdgcn_mfma_f32_32x32x16_bf16(fragpack(H0[c]), b0, acc00, 0, 0, 0);
            acc01 = __builtin_amdgcn_mfma_f32_32x32x16_bf16(fragpack(H0[c]), b1, acc01, 0, 0, 0);
            acc10 = __builtin_amdgcn_mfma_f32_32x32x16_bf16(fragpack(H1[c]), b0, acc10, 0, 0, 0);
            acc11 = __builtin_amdgcn_mfma_f32_32x32x16_bf16(fragpack(H1[c]), b1, acc11, 0, 0, 0);
        }
#pragma unroll
        for (int c = 0; c < 4; c++) {
            const s16x8 b0 = fragpack(B0[c]), b1 = fragpack(B1[c]);
            acc00 = __builtin_amdgcn_mfma_f32_32x32x16_bf16(fragpack(L0[c]), b0, acc00, 0, 0, 0);
            acc01 = __builtin_amdgcn_mfma_f32_32x32x16_bf16(fragpack(L0[c]), b1, acc01, 0, 0, 0);
            acc10 = __builtin_amdgcn_mfma_f32_32x32x16_bf16(fragpack(L1[c]), b0, acc10, 0, 0, 0);
            acc11 = __builtin_amdgcn_mfma_f32_32x32x16_bf16(fragpack(L1[c]), b1, acc11, 0, 0, 0);
        }
    }

    // ---- epilogue. C/D layout (32x32): col=lane&31 (pixel), row=(j&3)+8*(j>>2)+4*half (oc)
    if constexpr (MODE == 1) {
        __syncthreads();                    // halo reads done; reuse lds for transpose
#define ST1(ACC, MT, RR) { \
        _Pragma("unroll") \
        for (int j = 0; j < 16; j += 2) { \
            const int row = (j & 3) + 8 * (j >> 2) + 4 * half; \
            const int oc = MT * 32 + row; \
            float v0 = ACC[j]     + bias[oc]; \
            float v1 = ACC[j + 1] + bias[oc + 1]; \
            const float a0 = prelu[oc], a1 = prelu[oc + 1]; \
            v0 = fmaxf(v0, 0.f) + a0 * fminf(v0, 0.f); \
            v1 = fmaxf(v1, 0.f) + a1 * fminf(v1, 0.f); \
            const int icp = oc >> 1; \
            lds[((RR) * 32 + icp) * 32 + (colx ^ icp)] = \
                bf16rne(v0) | (bf16rne(v1) << 16); \
        } }
        ST1(acc00, 0, r0) ST1(acc01, 0, r0 + 1) ST1(acc10, 1, r0) ST1(acc11, 1, r0 + 1)
#undef ST1
        __syncthreads();
        const int prow = tid >> 5, pcol = tid & 31;
        uint* o = op + ((size_t)b * PLANE + (size_t)(y0 + prow) * 256 + x0 + pcol) * 32;
        uint d[32];
#pragma unroll
        for (int i = 0; i < 32; i++)
            d[i] = lds[(prow * 32 + i) * 32 + (pcol ^ i)];
#pragma unroll
        for (int k = 0; k < 8; k++)
            *(uint4*)(o + 4 * k) = make_uint4(d[4*k], d[4*k+1], d[4*k+2], d[4*k+3]);
    } else {
        // hi/lo bf16 NHWC out + fused per-pixel channel mean/max
        __syncthreads();
#define ST2(ACC, MT, RR) { \
        _Pragma("unroll") \
        for (int j = 0; j < 16; j += 2) { \
            const int row = (j & 3) + 8 * (j >> 2) + 4 * half; \
            const int oc = MT * 32 + row; \
            float v0 = ACC[j]     + bias[oc]; \
            float v1 = ACC[j + 1] + bias[oc + 1]; \
            uint h0 = bf16rne(v0); float l0 = v0 - bf16val(h0); \
            uint h1 = bf16rne(v1); float l1 = v1 - bf16val(h1); \
            const int icp = oc >> 1; \
            lds[((RR) * 32 + icp) * 32 + (colx ^ icp)] = h0 | (h1 << 16); \
            lds[8192 + ((RR) * 32 + icp) * 32 + (colx ^ icp)] = \
                bf16rne(l0) | (bf16rne(l1) << 16); \
        } }
        ST2(acc00, 0, r0) ST2(acc01, 0, r0 + 1) ST2(acc10, 1, r0) ST2(acc11, 1, r0 + 1)
#undef ST2
        __syncthreads();
        const int prow = tid >> 5, pcol = tid & 31;
        const size_t pixg = (size_t)(y0 + prow) * 256 + x0 + pcol;
        uint* oh = op  + ((size_t)b * PLANE + pixg) * 32;
        uint* ol = op2 + ((size_t)b * PLANE + pixg) * 32;
        uint d[32], dl[32];
        float s_ = 0.f, m_ = -INFINITY;
#pragma unroll
        for (int i = 0; i < 32; i++) {
            d[i]  = lds[(prow * 32 + i) * 32 + (pcol ^ i)];
            dl[i] = lds[8192 + (prow * 32 + i) * 32 + (pcol ^ i)];
            float ve = bf16val(d[i] & 0xffffu) + bf16val(dl[i] & 0xffffu);
            float vo = bf16val(d[i] >> 16)     + bf16val(dl[i] >> 16);
            s_ += ve + vo;
            m_ = fmaxf(m_, fmaxf(ve, vo));
        }
#pragma unroll
        for (int k = 0; k < 8; k++) {
            *(uint4*)(oh + 4 * k) = make_uint4(d[4*k], d[4*k+1], d[4*k+2], d[4*k+3]);
            *(uint4*)(ol + 4 * k) = make_uint4(dl[4*k], dl[4*k+1], dl[4*k+2], dl[4*k+3]);
        }
        amx[(size_t)b * 2 * PLANE + pixg] = s_ * (1.f / 64.f);
        amx[(size_t)b * 2 * PLANE + PLANE + pixg] = m_;
    }
}

// ---------------- global average pool from packed hi: g[b,c] ----------------
__global__ __launch_bounds__(256) void gpool_kernel(
    const uint* __restrict__ rph, float* __restrict__ g /*[B*C], pre-zeroed*/)
{
    const int tid = threadIdx.x;
    const int icp = tid & 31, grp = tid >> 5;
    const int b = blockIdx.y;
    const uint* base = rph + (size_t)b * PLANE * 32;
    float s0 = 0.f, s1 = 0.f;
    for (int it = 0; it < 128; it++) {
        const int pix = blockIdx.x * 1024 + it * 8 + grp;
        const uint d = base[(size_t)pix * 32 + icp];
        s0 += bf16val(d & 0xffffu);
        s1 += bf16val(d >> 16);
    }
    __shared__ float red[8][64];
    red[grp][2 * icp] = s0;
    red[grp][2 * icp + 1] = s1;
    __syncthreads();
    if (tid < 64) {
        float t = 0.f;
#pragma unroll
        for (int g8 = 0; g8 < 8; g8++) t += red[g8][tid];
        atomicAdd(&g[b * 64 + tid], t * (1.f / PLANE));
    }
}

// ---------------- spatial-attention 3x3 conv (2ch -> 1ch) ----------------
__global__ __launch_bounds__(256) void saconv_kernel(
    const float* __restrict__ amx, const float* __restrict__ sa_w,
    const float* __restrict__ sa_b, float* __restrict__ smap)
{
    int pix = blockIdx.x * 256 + threadIdx.x;
    int b = blockIdx.y;
    int x = pix & 255, y = pix >> 8;
    float acc = sa_b[0];
    const float* ab = amx + (size_t)b * 2 * PLANE;
#pragma unroll
    for (int c = 0; c < 2; c++)
#pragma unroll
        for (int dy = -1; dy <= 1; dy++)
#pragma unroll
            for (int dx = -1; dx <= 1; dx++) {
                int gx = x + dx; gx = gx < 0 ? 1 : (gx >= WW ? 2 * WW - 2 - gx : gx);
                int gy = y + dy; gy = gy < 0 ? 1 : (gy >= HH ? 2 * HH - 2 - gy : gy);
                acc += sa_w[c * 9 + (dy + 1) * 3 + (dx + 1)] * ab[(size_t)c * PLANE + gy * WW + gx];
            }
    smap[(size_t)b * PLANE + pix] = acc;
}

// ---------------- tiny MLPs -> hyper kernels packed bf16 hi/lo A-frag layout --
__global__ __launch_bounds__(256) void mlp_kernel(
    const float* __restrict__ h, const float* __restrict__ g,
    const float* __restrict__ ca_w1, const float* __restrict__ ca_b1,
    const float* __restrict__ ca_a,
    const float* __restrict__ ca_w2, const float* __restrict__ ca_b2,
    const float* __restrict__ fc_w, const float* __restrict__ fc_b,
    const float* __restrict__ k1_w, const float* __restrict__ k1_b,
    const float* __restrict__ k2_w, const float* __restrict__ k2_b,
    const float* __restrict__ k3_w, const float* __restrict__ k3_b,
    uint* __restrict__ kAhi, uint* __restrict__ kAlo,
    uint* __restrict__ kBhi, uint* __restrict__ kBlo)
{
    int b = blockIdx.x, tid = threadIdx.x;
    __shared__ float gb[64], t16[16], u32[32], v32[32], cg1[32], casig[64];

    if (tid < 64) gb[tid] = g[b * 64 + tid];
    __syncthreads();

    if (tid < 16) {
        float s = fc_b[tid];
        for (int j = 0; j < 16; j++) s += fc_w[tid * 16 + j] * h[b * 16 + j];
        t16[tid] = s >= 0.f ? s : 0.01f * s;
    }
    if (tid < 32) {
        float c1 = ca_b1[tid];
        for (int j = 0; j < 64; j++) c1 += ca_w1[tid * 64 + j] * gb[j];
        cg1[tid] = fmaxf(c1, 0.f) + ca_a[tid] * fminf(c1, 0.f);
    }
    __syncthreads();
    if (tid < 32) {
        float s = k1_b[tid];
        for (int j = 0; j < 16; j++) s += k1_w[tid * 16 + j] * t16[j];
        u32[tid] = s >= 0.f ? s : 0.01f * s;
    }
    if (tid < 64) {
        float c2 = ca_b2[tid];
        for (int j = 0; j < 32; j++) c2 += ca_w2[tid * 32 + j] * cg1[j];
        casig[tid] = 1.f / (1.f + expf(-c2));
    }
    __syncthreads();
    if (tid < 32) {
        float s = k2_b[tid];
        for (int j = 0; j < 32; j++) s += k2_w[tid * 32 + j] * u32[j];
        v32[tid] = s >= 0.f ? s : 0.01f * s;
    }
    __syncthreads();
    // k3: 8192 outputs, adjacent pairs -> one packed dword (hi + lo)
    for (int o2 = tid; o2 < 4096; o2 += 256) {
        const int o = o2 * 2;
        const int oc = o >> 7;        // /128
        const int i = o & 127;        // even
        float s0 = k3_b[o], s1 = k3_b[o + 1];
        for (int j = 0; j < 32; j++) {
            s0 += k3_w[(size_t)o * 32 + j] * v32[j];
            s1 += k3_w[(size_t)(o + 1) * 32 + j] * v32[j];
        }
        uint *hi, *lo;
        if (i < 64) { hi = kAhi; lo = kAlo; }
        else { s0 *= casig[i - 64]; s1 *= casig[i - 63]; hi = kBhi; lo = kBlo; }
        const int cp = (i & 63) >> 1;
        uint h0 = bf16rne(s0); float l0 = s0 - bf16val(h0);
        uint h1 = bf16rne(s1); float l1 = s1 - bf16val(h1);
        hi[(size_t)b * 2048 + oc * 32 + cp] = h0 | (h1 << 16);
        lo[(size_t)b * 2048 + oc * 32 + cp] = bf16rne(l0) | (bf16rne(l1) << 16);
    }
}

// ---------------- final via MFMA: out = x + hcb + sig(s)*(A.r) + (B.r) --------
// wave = one 32-oc Mtile x 32 pixels; K=64 channels; hi/lo 3-term products.
__global__ __launch_bounds__(256, 2) void final_mfma(
    const float* __restrict__ x, const uint* __restrict__ rph,
    const uint* __restrict__ rpl, const float* __restrict__ smap,
    const uint* __restrict__ kAhi, const uint* __restrict__ kAlo,
    const uint* __restrict__ kBhi, const uint* __restrict__ kBlo,
    const float* __restrict__ hcb, float* __restrict__ out)
{
    const int tid = threadIdx.x;
    const int lane = tid & 63;
    const int wid = tid >> 6;
    const int mt = wid & 1;          // oc Mtile
    const int gq = wid >> 1;         // pixel group
    const int b = blockIdx.y;
    const int colx = lane & 31;
    const int half = lane >> 5;
    const int pix = blockIdx.x * 64 + gq * 32 + colx;

    const size_t kb = (size_t)b * 2048 + (size_t)(mt * 32 + colx) * 32 + half * 4;
    uint4 KAh[4], KAl[4], KBh[4], KBl[4];
#pragma unroll
    for (int c = 0; c < 4; c++) {
        KAh[c] = *(const uint4*)(kAhi + kb + c * 8);
        KAl[c] = *(const uint4*)(kAlo + kb + c * 8);
        KBh[c] = *(const uint4*)(kBhi + kb + c * 8);
        KBl[c] = *(const uint4*)(kBlo + kb + c * 8);
    }
    const size_t rb = ((size_t)b * PLANE + pix) * 32 + half * 4;
    uint4 Bh[4], Bl[4];
#pragma unroll
    for (int c = 0; c < 4; c++) {
        Bh[c] = *(const uint4*)(rph + rb + c * 8);
        Bl[c] = *(const uint4*)(rpl + rb + c * 8);
    }
    f32x16 accA = (f32x16)0.f, accB = (f32x16)0.f;
#pragma unroll
    for (int c = 0; c < 4; c++) {
        const s16x8 bh = fragpack(Bh[c]), bl = fragpack(Bl[c]);
        const s16x8 ah = fragpack(KAh[c]), al = fragpack(KAl[c]);
        const s16x8 ch = fragpack(KBh[c]), cl = fragpack(KBl[c]);
        accA = __builtin_amdgcn_mfma_f32_32x32x16_bf16(ah, bh, accA, 0, 0, 0);
        accA = __builtin_amdgcn_mfma_f32_32x32x16_bf16(ah, bl, accA, 0, 0, 0);
        accA = __builtin_amdgcn_mfma_f32_32x32x16_bf16(al, bh, accA, 0, 0, 0);
        accB = __builtin_amdgcn_mfma_f32_32x32x16_bf16(ch, bh, accB, 0, 0, 0);
        accB = __builtin_amdgcn_mfma_f32_32x32x16_bf16(ch, bl, accB, 0, 0, 0);
        accB = __builtin_amdgcn_mfma_f32_32x32x16_bf16(cl, bh, accB, 0, 0, 0);
    }
    const float sv = smap[(size_t)b * PLANE + pix];
    const float sig = 1.f / (1.f + expf(-sv));
#pragma unroll
    for (int j = 0; j < 16; j++) {
        const int row = (j & 3) + 8 * (j >> 2) + 4 * half;
        const int oc = mt * 32 + row;
        const size_t idx = ((size_t)b * 64 + oc) * PLANE + pix;
        out[idx] = x[idx] + hcb[oc] + sig * accA[j] + accB[j];
    }
}

extern "C" void kernel_launch(void* const* d_in, const int* in_sizes, int n_in,
                              void* d_out, int out_size, void* d_ws, size_t ws_size,
                              hipStream_t stream) {
    const float* x   = (const float*)d_in[0];
    const float* h   = (const float*)d_in[1];
    const float* c1w = (const float*)d_in[2];
    const float* c1b = (const float*)d_in[3];
    const float* pa  = (const float*)d_in[4];
    const float* c2w = (const float*)d_in[5];
    const float* c2b = (const float*)d_in[6];
    const float* saw = (const float*)d_in[7];
    const float* sab = (const float*)d_in[8];
    const float* cw1 = (const float*)d_in[9];
    const float* cb1 = (const float*)d_in[10];
    const float* caa = (const float*)d_in[11];
    const float* cw2 = (const float*)d_in[12];
    const float* cb2 = (const float*)d_in[13];
    const float* fcw = (const float*)d_in[14];
    const float* fcb = (const float*)d_in[15];
    const float* k1w = (const float*)d_in[16];
    const float* k1b = (const float*)d_in[17];
    const float* k2w = (const float*)d_in[18];
    const float* k2b = (const float*)d_in[19];
    const float* k3w = (const float*)d_in[20];
    const float* k3b = (const float*)d_in[21];
    const float* hcb = (const float*)d_in[22];
    float* out = (float*)d_out;

    char* ws = (char*)d_ws;
    const size_t SZ_Q = (size_t)8 * PLANE * 32 * 4;   // 67,108,864 (NHWC packed)
    uint*  xp  = (uint*)ws;                           // x repacked
    uint*  r1p = (uint*)(ws + SZ_Q);                  // conv1 out (hi)
    uint*  rph = (uint*)(ws + 2 * SZ_Q);              // conv2 out hi
    uint*  rpl = (uint*)(ws + 3 * SZ_Q);              // conv2 out lo
    // small buffers reuse [0, 2*SZ_Q) once their aliased producers are dead:
    // amx/smap/g/kern* live in the xp region (xp dead after conv1; conv2 writes amx)
    float* amx   = (float*)ws;
    float* smap  = (float*)(ws + (size_t)8 * 2 * PLANE * 4);
    float* g     = (float*)(ws + (size_t)8 * 3 * PLANE * 4);
    uint*  kAhi  = (uint*)(ws + (size_t)8 * 3 * PLANE * 4 + 4096);
    uint*  kAlo  = kAhi + 8 * 2048;
    uint*  kBhi  = kAlo + 8 * 2048;
    uint*  kBlo  = kBhi + 8 * 2048;

    // weight packs live in d_out (dead until final_mfma overwrites it)
    uint* wsp = (uint*)d_out;
    uint* wh1 = wsp;          uint* wl1 = wsp + 18432;
    uint* wh2 = wsp + 36864;  uint* wl2 = wsp + 55296;

    wprep_kernel<<<dim3(72, 2), 256, 0, stream>>>(c1w, c2w, wh1, wl1, wh2, wl2);
    xrepack_kernel<<<dim3(PLANE / 256, 8), 256, 0, stream>>>(x, xp);

    dim3 cgrid(WW / 32, HH / 8, 8);  // (8, 32, 8)
    conv_mfma<1><<<cgrid, 256, 0, stream>>>(xp, wh1, wl1, c1b, pa, r1p, nullptr, nullptr);
    conv_mfma<2><<<cgrid, 256, 0, stream>>>(r1p, wh2, wl2, c2b, nullptr, rph, rpl, amx);

    hipMemsetAsync(g, 0, 512 * sizeof(float), stream);
    gpool_kernel<<<dim3(64, 8), 256, 0, stream>>>(rph, g);
    saconv_kernel<<<dim3(PLANE / 256, 8), 256, 0, stream>>>(amx, saw, sab, smap);
    mlp_kernel<<<8, 256, 0, stream>>>(h, g, cw1, cb1, caa, cw2, cb2,
                                      fcw, fcb, k1w, k1b, k2w, k2b, k3w, k3b,
                                      kAhi, kAlo, kBhi, kBlo);
    final_mfma<<<dim3(PLANE / 64, 8), 256, 0, stream>>>(
        x, rph, rpl, smap, kAhi, kAlo, kBhi, kBlo, hcb, out);
}

// Round 9
// 844.846 us; speedup vs baseline: 1.2591x; 1.0813x over previous
//
#include <hip/hip_runtime.h>
#include <math.h>

#define HH 256
#define WW 256
#define CC 64
#define PLANE (HH*WW)

typedef short s16x8 __attribute__((ext_vector_type(8)));
typedef float f32x16 __attribute__((ext_vector_type(16)));
typedef unsigned int uint;
typedef uint u32x4v __attribute__((ext_vector_type(4)));

__device__ inline uint bf16rne(float f) {
    uint u = __float_as_uint(f);
    return (u + 0x7FFFu + ((u >> 16) & 1u)) >> 16;
}
__device__ inline float bf16val(uint h) { return __uint_as_float(h << 16); }
__device__ inline s16x8 fragpack(uint4 q) {
    u32x4v t = {q.x, q.y, q.z, q.w};
    return __builtin_bit_cast(s16x8, t);
}
__device__ inline void gload_lds16(const uint* g, uint* l) {
    __builtin_amdgcn_global_load_lds(
        (const __attribute__((address_space(1))) uint*)g,
        (__attribute__((address_space(3))) uint*)l, 16, 0, 0);
}
// fragment-slot layout: dword (pix, dwi) at (pix>>5)*1024 + (dwi>>2)*128 + (pix&31)*4 + (dwi&3)
__device__ inline size_t chunk_addr(int pix, int c2) {
    return (size_t)(pix >> 5) * 1024 + c2 * 128 + (pix & 31) * 4;
}

// ---------------- weight prep: split fp32 W into bf16 hi/lo, pack ic-pairs ----
__global__ __launch_bounds__(256) void wprep_kernel(
    const float* __restrict__ w1, const float* __restrict__ w2,
    uint* __restrict__ wh1, uint* __restrict__ wl1,
    uint* __restrict__ wh2, uint* __restrict__ wl2)
{
    const int idx = blockIdx.x * 256 + threadIdx.x;      // 0..18431
    const float* w = blockIdx.y ? w2 : w1;
    uint* wh = blockIdx.y ? wh2 : wh1;
    uint* wl = blockIdx.y ? wl2 : wl1;
    const int tap = idx >> 11;           // 9
    const int oc  = (idx >> 5) & 63;     // 64
    const int icp = idx & 31;            // 32 ic-pairs
    float w0 = w[(oc * 64 + 2 * icp) * 9 + tap];
    float w1v = w[(oc * 64 + 2 * icp + 1) * 9 + tap];
    uint h0 = bf16rne(w0); float l0 = w0 - bf16val(h0);
    uint h1 = bf16rne(w1v); float l1 = w1v - bf16val(h1);
    wh[idx] = h0 | (h1 << 16);
    wl[idx] = bf16rne(l0) | (bf16rne(l1) << 16);
}

// ---------------- x repack: fp32 NCHW -> bf16-pair fragment-slot ----------------
__global__ __launch_bounds__(256) void xrepack_kernel(
    const float* __restrict__ x, uint* __restrict__ xp)
{
    const int tid = threadIdx.x;
    const int px = blockIdx.x * 256 + tid;
    const int b = blockIdx.y;
    const float* xb = x + (size_t)b * CC * PLANE + px;
    uint d[32];
#pragma unroll
    for (int icp = 0; icp < 32; icp++) {
        float v0 = xb[(size_t)(2 * icp) * PLANE];
        float v1 = xb[(size_t)(2 * icp + 1) * PLANE];
        d[icp] = bf16rne(v0) | (bf16rne(v1) << 16);
    }
    uint* o = xp + (size_t)b * PLANE * 32 + chunk_addr(px, 0);
#pragma unroll
    for (int k = 0; k < 8; k++)
        *(uint4*)(o + k * 128) = make_uint4(d[4*k], d[4*k+1], d[4*k+2], d[4*k+3]);
}

// ---------------- conv 3x3 reflect via MFMA, LDS halo, per-tap batched loads --
// MODE 1: PReLU + fragment-slot (hi only) out.
// MODE 2: fragment-slot hi/lo out + fused per-pixel channel mean/max (amx).
#define HPIX 340                 // 10*34 halo pixels
#define HCHUNK (HPIX*8)          // 16B chunks = 2720
template<int MODE>
__global__ __launch_bounds__(256, 2) void conv_mfma(
    const uint* __restrict__ xin,   // fragment-slot packed
    const uint* __restrict__ wh, const uint* __restrict__ wl,
    const float* __restrict__ bias, const float* __restrict__ prelu,
    uint* __restrict__ op, uint* __restrict__ op2, float* __restrict__ amx)
{
    __shared__ uint lds[(MODE == 2) ? 16384 : HPIX * 32];
    const int tid  = threadIdx.x;
    const int lane = tid & 63;
    const int wid  = tid >> 6;
    const int x0 = blockIdx.x * 32;
    const int y0 = blockIdx.y * 8;
    const int b  = blockIdx.z;
    const int colx = lane & 31;
    const int half = lane >> 5;
    const int r0 = wid * 2;

    // ---- stage halo: chunk k -> LDS byte k*16 (linear), source pre-swizzled
    {
        const uint* gb = xin + (size_t)b * PLANE * 32;
#pragma unroll
        for (int iter = 0; iter < 11; iter++) {
            const int k = iter * 256 + tid;
            if (iter < 10 || k < HCHUNK) {
                const int pix = k >> 3;
                const int slot = k & 7;
                const int hrow = pix / 34;
                const int hcol = pix - hrow * 34;
                int gy = y0 - 1 + hrow; gy = gy < 0 ? 1 : (gy > 255 ? 254 : gy);
                int gx = x0 - 1 + hcol; gx = gx < 0 ? 1 : (gx > 255 ? 254 : gx);
                const int c2 = slot ^ (pix & 7);    // involution
                gload_lds16(gb + chunk_addr(gy * 256 + gx, c2),
                            &lds[(iter * 256 + wid * 64) * 4]);
            }
        }
    }
    __syncthreads();

    f32x16 acc00 = (f32x16)0.f, acc01 = (f32x16)0.f;   // [Mtile][row]
    f32x16 acc10 = (f32x16)0.f, acc11 = (f32x16)0.f;

    const uint* wth = wh + colx * 32 + half * 4;
    const uint* wtl = wl + colx * 32 + half * 4;

#pragma unroll
    for (int tap = 0; tap < 9; tap++) {
        const int dy = tap / 3, dx = tap % 3;
        const int pix0 = (r0 + dy) * 34 + dx + colx;   // output row r0
        const int pix1 = pix0 + 34;                    // output row r0+1

        uint4 B0[4], B1[4], H0[4], H1[4], L0[4], L1[4];
#pragma unroll
        for (int c = 0; c < 4; c++) {
            const int c2 = c * 2 + half;
            B0[c] = *(const uint4*)&lds[(pix0 * 8 + (c2 ^ (pix0 & 7))) * 4];
            B1[c] = *(const uint4*)&lds[(pix1 * 8 + (c2 ^ (pix1 & 7))) * 4];
        }
#pragma unroll
        for (int c = 0; c < 4; c++) {
            H0[c] = *(const uint4*)(wth + tap * 2048 + c * 8);
            H1[c] = *(const uint4*)(wth + tap * 2048 + 1024 + c * 8);
        }
#pragma unroll
        for (int c = 0; c < 4; c++) {
            L0[c] = *(const uint4*)(wtl + tap * 2048 + c * 8);
            L1[c] = *(const uint4*)(wtl + tap * 2048 + 1024 + c * 8);
        }
#pragma unroll
        for (int c = 0; c < 4; c++) {
            const s16x8 b0 = fragpack(B0[c]), b1 = fragpack(B1[c]);
            acc00 = __builtin_amdgcn_mfma_f32_32x32x16_bf16(fragpack(H0[c]), b0, acc00, 0, 0, 0);
            acc01 = __builtin_amdgcn_mfma_f32_32x32x16_bf16(fragpack(H0[c]), b1, acc01, 0, 0, 0);
            acc10 = __builtin_amdgcn_mfma_f32_32x32x16_bf16(fragpack(H1[c]), b0, acc10, 0, 0, 0);
            acc11 = __builtin_amdgcn_mfma_f32_32x32x16_bf16(fragpack(H1[c]), b1, acc11, 0, 0, 0);
        }
#pragma unroll
        for (int c = 0; c < 4; c++) {
            const s16x8 b0 = fragpack(B0[c]), b1 = fragpack(B1[c]);
            acc00 = __builtin_amdgcn_mfma_f32_32x32x16_bf16(fragpack(L0[c]), b0, acc00, 0, 0, 0);
            acc01 = __builtin_amdgcn_mfma_f32_32x32x16_bf16(fragpack(L0[c]), b1, acc01, 0, 0, 0);
            acc10 = __builtin_amdgcn_mfma_f32_32x32x16_bf16(fragpack(L1[c]), b0, acc10, 0, 0, 0);
            acc11 = __builtin_amdgcn_mfma_f32_32x32x16_bf16(fragpack(L1[c]), b1, acc11, 0, 0, 0);
        }
    }

    // ---- epilogue. C/D layout (32x32): col=lane&31 (pixel), row=(j&3)+8*(j>>2)+4*half (oc)
    if constexpr (MODE == 1) {
        __syncthreads();                    // halo reads done; reuse lds for transpose
#define ST1(ACC, MT, RR) { \
        _Pragma("unroll") \
        for (int j = 0; j < 16; j += 2) { \
            const int row = (j & 3) + 8 * (j >> 2) + 4 * half; \
            const int oc = MT * 32 + row; \
            float v0 = ACC[j]     + bias[oc]; \
            float v1 = ACC[j + 1] + bias[oc + 1]; \
            const float a0 = prelu[oc], a1 = prelu[oc + 1]; \
            v0 = fmaxf(v0, 0.f) + a0 * fminf(v0, 0.f); \
            v1 = fmaxf(v1, 0.f) + a1 * fminf(v1, 0.f); \
            const int icp = oc >> 1; \
            lds[((RR) * 32 + icp) * 32 + (colx ^ icp)] = \
                bf16rne(v0) | (bf16rne(v1) << 16); \
        } }
        ST1(acc00, 0, r0) ST1(acc01, 0, r0 + 1) ST1(acc10, 1, r0) ST1(acc11, 1, r0 + 1)
#undef ST1
        __syncthreads();
        const int prow = tid >> 5, pcol = tid & 31;
        uint d[32];
#pragma unroll
        for (int i = 0; i < 32; i++)
            d[i] = lds[(prow * 32 + i) * 32 + (pcol ^ i)];
        uint* o = op + (size_t)b * PLANE * 32
                     + chunk_addr((y0 + prow) * 256 + x0 + pcol, 0);
#pragma unroll
        for (int k = 0; k < 8; k++)
            *(uint4*)(o + k * 128) = make_uint4(d[4*k], d[4*k+1], d[4*k+2], d[4*k+3]);
    } else {
        // hi/lo bf16 fragment-slot out + fused per-pixel channel mean/max
        __syncthreads();
#define ST2(ACC, MT, RR) { \
        _Pragma("unroll") \
        for (int j = 0; j < 16; j += 2) { \
            const int row = (j & 3) + 8 * (j >> 2) + 4 * half; \
            const int oc = MT * 32 + row; \
            float v0 = ACC[j]     + bias[oc]; \
            float v1 = ACC[j + 1] + bias[oc + 1]; \
            uint h0 = bf16rne(v0); float l0 = v0 - bf16val(h0); \
            uint h1 = bf16rne(v1); float l1 = v1 - bf16val(h1); \
            const int icp = oc >> 1; \
            lds[((RR) * 32 + icp) * 32 + (colx ^ icp)] = h0 | (h1 << 16); \
            lds[8192 + ((RR) * 32 + icp) * 32 + (colx ^ icp)] = \
                bf16rne(l0) | (bf16rne(l1) << 16); \
        } }
        ST2(acc00, 0, r0) ST2(acc01, 0, r0 + 1) ST2(acc10, 1, r0) ST2(acc11, 1, r0 + 1)
#undef ST2
        __syncthreads();
        const int prow = tid >> 5, pcol = tid & 31;
        const size_t pixg = (size_t)(y0 + prow) * 256 + x0 + pcol;
        uint d[32], dl[32];
        float s_ = 0.f, m_ = -INFINITY;
#pragma unroll
        for (int i = 0; i < 32; i++) {
            d[i]  = lds[(prow * 32 + i) * 32 + (pcol ^ i)];
            dl[i] = lds[8192 + (prow * 32 + i) * 32 + (pcol ^ i)];
            float ve = bf16val(d[i] & 0xffffu) + bf16val(dl[i] & 0xffffu);
            float vo = bf16val(d[i] >> 16)     + bf16val(dl[i] >> 16);
            s_ += ve + vo;
            m_ = fmaxf(m_, fmaxf(ve, vo));
        }
        const size_t cb = (size_t)b * PLANE * 32 + chunk_addr((int)pixg, 0);
        uint* oh = op  + cb;
        uint* ol = op2 + cb;
#pragma unroll
        for (int k = 0; k < 8; k++) {
            *(uint4*)(oh + k * 128) = make_uint4(d[4*k], d[4*k+1], d[4*k+2], d[4*k+3]);
            *(uint4*)(ol + k * 128) = make_uint4(dl[4*k], dl[4*k+1], dl[4*k+2], dl[4*k+3]);
        }
        amx[(size_t)b * 2 * PLANE + pixg] = s_ * (1.f / 64.f);
        amx[(size_t)b * 2 * PLANE + PLANE + pixg] = m_;
    }
}

// ---------------- global average pool from fragment-slot hi: g[b,c] ----------
// thread tid: fixed dwords (tid*4..tid*4+3) of each 1024-dw group
// -> channels (tid>>5)*8 + 0..7; fully dense uint4 loads.
__global__ __launch_bounds__(256) void gpool_kernel(
    const uint* __restrict__ rph, float* __restrict__ g /*[B*C], pre-zeroed*/)
{
    const int tid = threadIdx.x;
    const int b = blockIdx.y;
    const uint* base = rph + (size_t)b * PLANE * 32;
    float s[8];
#pragma unroll
    for (int i = 0; i < 8; i++) s[i] = 0.f;
    for (int it = 0; it < 32; it++) {
        const size_t a = ((size_t)blockIdx.x * 32 + it) * 1024 + tid * 4;
        const uint4 q = *(const uint4*)(base + a);
        s[0] += bf16val(q.x & 0xffffu); s[1] += bf16val(q.x >> 16);
        s[2] += bf16val(q.y & 0xffffu); s[3] += bf16val(q.y >> 16);
        s[4] += bf16val(q.z & 0xffffu); s[5] += bf16val(q.z >> 16);
        s[6] += bf16val(q.w & 0xffffu); s[7] += bf16val(q.w >> 16);
    }
#pragma unroll
    for (int off = 16; off >= 1; off >>= 1)
#pragma unroll
        for (int i = 0; i < 8; i++) s[i] += __shfl_xor(s[i], off, 64);
    if ((tid & 31) == 0) {
        const int grp = tid >> 5;   // 0..7
#pragma unroll
        for (int i = 0; i < 8; i++)
            atomicAdd(&g[b * 64 + grp * 8 + i], s[i] * (1.f / PLANE));
    }
}

// ---------------- spatial-attention 3x3 conv (2ch -> 1ch) ----------------
__global__ __launch_bounds__(256) void saconv_kernel(
    const float* __restrict__ amx, const float* __restrict__ sa_w,
    const float* __restrict__ sa_b, float* __restrict__ smap)
{
    int pix = blockIdx.x * 256 + threadIdx.x;
    int b = blockIdx.y;
    int x = pix & 255, y = pix >> 8;
    float acc = sa_b[0];
    const float* ab = amx + (size_t)b * 2 * PLANE;
#pragma unroll
    for (int c = 0; c < 2; c++)
#pragma unroll
        for (int dy = -1; dy <= 1; dy++)
#pragma unroll
            for (int dx = -1; dx <= 1; dx++) {
                int gx = x + dx; gx = gx < 0 ? 1 : (gx >= WW ? 2 * WW - 2 - gx : gx);
                int gy = y + dy; gy = gy < 0 ? 1 : (gy >= HH ? 2 * HH - 2 - gy : gy);
                acc += sa_w[c * 9 + (dy + 1) * 3 + (dx + 1)] * ab[(size_t)c * PLANE + gy * WW + gx];
            }
    smap[(size_t)b * PLANE + pix] = acc;
}

// ---------------- tiny MLPs -> hyper kernels packed bf16 hi/lo A-frag layout --
__global__ __launch_bounds__(256) void mlp_kernel(
    const float* __restrict__ h, const float* __restrict__ g,
    const float* __restrict__ ca_w1, const float* __restrict__ ca_b1,
    const float* __restrict__ ca_a,
    const float* __restrict__ ca_w2, const float* __restrict__ ca_b2,
    const float* __restrict__ fc_w, const float* __restrict__ fc_b,
    const float* __restrict__ k1_w, const float* __restrict__ k1_b,
    const float* __restrict__ k2_w, const float* __restrict__ k2_b,
    const float* __restrict__ k3_w, const float* __restrict__ k3_b,
    uint* __restrict__ kAhi, uint* __restrict__ kAlo,
    uint* __restrict__ kBhi, uint* __restrict__ kBlo)
{
    int b = blockIdx.x, tid = threadIdx.x;
    __shared__ float gb[64], t16[16], u32[32], v32[32], cg1[32], casig[64];

    if (tid < 64) gb[tid] = g[b * 64 + tid];
    __syncthreads();

    if (tid < 16) {
        float s = fc_b[tid];
        for (int j = 0; j < 16; j++) s += fc_w[tid * 16 + j] * h[b * 16 + j];
        t16[tid] = s >= 0.f ? s : 0.01f * s;
    }
    if (tid < 32) {
        float c1 = ca_b1[tid];
        for (int j = 0; j < 64; j++) c1 += ca_w1[tid * 64 + j] * gb[j];
        cg1[tid] = fmaxf(c1, 0.f) + ca_a[tid] * fminf(c1, 0.f);
    }
    __syncthreads();
    if (tid < 32) {
        float s = k1_b[tid];
        for (int j = 0; j < 16; j++) s += k1_w[tid * 16 + j] * t16[j];
        u32[tid] = s >= 0.f ? s : 0.01f * s;
    }
    if (tid < 64) {
        float c2 = ca_b2[tid];
        for (int j = 0; j < 32; j++) c2 += ca_w2[tid * 32 + j] * cg1[j];
        casig[tid] = 1.f / (1.f + expf(-c2));
    }
    __syncthreads();
    if (tid < 32) {
        float s = k2_b[tid];
        for (int j = 0; j < 32; j++) s += k2_w[tid * 32 + j] * u32[j];
        v32[tid] = s >= 0.f ? s : 0.01f * s;
    }
    __syncthreads();
    // k3: 8192 outputs, adjacent pairs -> one packed dword (hi + lo)
    for (int o2 = tid; o2 < 4096; o2 += 256) {
        const int o = o2 * 2;
        const int oc = o >> 7;        // /128
        const int i = o & 127;        // even
        float s0 = k3_b[o], s1 = k3_b[o + 1];
        for (int j = 0; j < 32; j++) {
            s0 += k3_w[(size_t)o * 32 + j] * v32[j];
            s1 += k3_w[(size_t)(o + 1) * 32 + j] * v32[j];
        }
        uint *hi, *lo;
        if (i < 64) { hi = kAhi; lo = kAlo; }
        else { s0 *= casig[i - 64]; s1 *= casig[i - 63]; hi = kBhi; lo = kBlo; }
        const int cp = (i & 63) >> 1;
        uint h0 = bf16rne(s0); float l0 = s0 - bf16val(h0);
        uint h1 = bf16rne(s1); float l1 = s1 - bf16val(h1);
        hi[(size_t)b * 2048 + oc * 32 + cp] = h0 | (h1 << 16);
        lo[(size_t)b * 2048 + oc * 32 + cp] = bf16rne(l0) | (bf16rne(l1) << 16);
    }
}

// ---------------- final via MFMA: out = x + hcb + sig(s)*(A.r) + (B.r) --------
__global__ __launch_bounds__(256, 2) void final_mfma(
    const float* __restrict__ x, const uint* __restrict__ rph,
    const uint* __restrict__ rpl, const float* __restrict__ smap,
    const uint* __restrict__ kAhi, const uint* __restrict__ kAlo,
    const uint* __restrict__ kBhi, const uint* __restrict__ kBlo,
    const float* __restrict__ hcb, float* __restrict__ out)
{
    const int tid = threadIdx.x;
    const int lane = tid & 63;
    const int wid = tid >> 6;
    const int mt = wid & 1;          // oc Mtile
    const int gq = wid >> 1;         // pixel group
    const int b = blockIdx.y;
    const int colx = lane & 31;
    const int half = lane >> 5;
    const int pix = blockIdx.x * 64 + gq * 32 + colx;
    const int pgroup = blockIdx.x * 2 + gq;   // pix >> 5

    const size_t kb = (size_t)b * 2048 + (size_t)(mt * 32 + colx) * 32 + half * 4;
    uint4 KAh[4], KAl[4], KBh[4], KBl[4];
#pragma unroll
    for (int c = 0; c < 4; c++) {
        KAh[c] = *(const uint4*)(kAhi + kb + c * 8);
        KAl[c] = *(const uint4*)(kAlo + kb + c * 8);
        KBh[c] = *(const uint4*)(kBhi + kb + c * 8);
        KBl[c] = *(const uint4*)(kBlo + kb + c * 8);
    }
    // fragment-slot reads: chunk c2 = 2c+half -> offset c*256 + half*128
    const size_t rb = (size_t)b * PLANE * 32 + (size_t)pgroup * 1024
                    + half * 128 + colx * 4;
    uint4 Bh[4], Bl[4];
#pragma unroll
    for (int c = 0; c < 4; c++) {
        Bh[c] = *(const uint4*)(rph + rb + c * 256);
        Bl[c] = *(const uint4*)(rpl + rb + c * 256);
    }
    f32x16 accA = (f32x16)0.f, accB = (f32x16)0.f;
#pragma unroll
    for (int c = 0; c < 4; c++) {
        const s16x8 bh = fragpack(Bh[c]), bl = fragpack(Bl[c]);
        const s16x8 ah = fragpack(KAh[c]), al = fragpack(KAl[c]);
        const s16x8 ch = fragpack(KBh[c]), cl = fragpack(KBl[c]);
        accA = __builtin_amdgcn_mfma_f32_32x32x16_bf16(ah, bh, accA, 0, 0, 0);
        accA = __builtin_amdgcn_mfma_f32_32x32x16_bf16(ah, bl, accA, 0, 0, 0);
        accA = __builtin_amdgcn_mfma_f32_32x32x16_bf16(al, bh, accA, 0, 0, 0);
        accB = __builtin_amdgcn_mfma_f32_32x32x16_bf16(ch, bh, accB, 0, 0, 0);
        accB = __builtin_amdgcn_mfma_f32_32x32x16_bf16(ch, bl, accB, 0, 0, 0);
        accB = __builtin_amdgcn_mfma_f32_32x32x16_bf16(cl, bh, accB, 0, 0, 0);
    }
    const float sv = smap[(size_t)b * PLANE + pix];
    const float sig = 1.f / (1.f + expf(-sv));
#pragma unroll
    for (int j = 0; j < 16; j++) {
        const int row = (j & 3) + 8 * (j >> 2) + 4 * half;
        const int oc = mt * 32 + row;
        const size_t idx = ((size_t)b * 64 + oc) * PLANE + pix;
        out[idx] = x[idx] + hcb[oc] + sig * accA[j] + accB[j];
    }
}

extern "C" void kernel_launch(void* const* d_in, const int* in_sizes, int n_in,
                              void* d_out, int out_size, void* d_ws, size_t ws_size,
                              hipStream_t stream) {
    const float* x   = (const float*)d_in[0];
    const float* h   = (const float*)d_in[1];
    const float* c1w = (const float*)d_in[2];
    const float* c1b = (const float*)d_in[3];
    const float* pa  = (const float*)d_in[4];
    const float* c2w = (const float*)d_in[5];
    const float* c2b = (const float*)d_in[6];
    const float* saw = (const float*)d_in[7];
    const float* sab = (const float*)d_in[8];
    const float* cw1 = (const float*)d_in[9];
    const float* cb1 = (const float*)d_in[10];
    const float* caa = (const float*)d_in[11];
    const float* cw2 = (const float*)d_in[12];
    const float* cb2 = (const float*)d_in[13];
    const float* fcw = (const float*)d_in[14];
    const float* fcb = (const float*)d_in[15];
    const float* k1w = (const float*)d_in[16];
    const float* k1b = (const float*)d_in[17];
    const float* k2w = (const float*)d_in[18];
    const float* k2b = (const float*)d_in[19];
    const float* k3w = (const float*)d_in[20];
    const float* k3b = (const float*)d_in[21];
    const float* hcb = (const float*)d_in[22];
    float* out = (float*)d_out;

    char* ws = (char*)d_ws;
    const size_t SZ_Q = (size_t)8 * PLANE * 32 * 4;   // 67,108,864 (packed)
    uint*  xp  = (uint*)ws;                           // x repacked
    uint*  r1p = (uint*)(ws + SZ_Q);                  // conv1 out (hi)
    uint*  rph = (uint*)(ws + 2 * SZ_Q);              // conv2 out hi
    uint*  rpl = (uint*)(ws + 3 * SZ_Q);              // conv2 out lo
    float* amx   = (float*)ws;                        // aliases xp (dead after conv1)
    float* smap  = (float*)(ws + (size_t)8 * 2 * PLANE * 4);
    float* g     = (float*)(ws + (size_t)8 * 3 * PLANE * 4);
    uint*  kAhi  = (uint*)(ws + (size_t)8 * 3 * PLANE * 4 + 4096);
    uint*  kAlo  = kAhi + 8 * 2048;
    uint*  kBhi  = kAlo + 8 * 2048;
    uint*  kBlo  = kBhi + 8 * 2048;

    // weight packs live in d_out (dead until final_mfma overwrites it)
    uint* wsp = (uint*)d_out;
    uint* wh1 = wsp;          uint* wl1 = wsp + 18432;
    uint* wh2 = wsp + 36864;  uint* wl2 = wsp + 55296;

    wprep_kernel<<<dim3(72, 2), 256, 0, stream>>>(c1w, c2w, wh1, wl1, wh2, wl2);
    xrepack_kernel<<<dim3(PLANE / 256, 8), 256, 0, stream>>>(x, xp);

    dim3 cgrid(WW / 32, HH / 8, 8);  // (8, 32, 8)
    conv_mfma<1><<<cgrid, 256, 0, stream>>>(xp, wh1, wl1, c1b, pa, r1p, nullptr, nullptr);
    conv_mfma<2><<<cgrid, 256, 0, stream>>>(r1p, wh2, wl2, c2b, nullptr, rph, rpl, amx);

    hipMemsetAsync(g, 0, 512 * sizeof(float), stream);
    gpool_kernel<<<dim3(64, 8), 256, 0, stream>>>(rph, g);
    saconv_kernel<<<dim3(PLANE / 256, 8), 256, 0, stream>>>(amx, saw, sab, smap);
    mlp_kernel<<<8, 256, 0, stream>>>(h, g, cw1, cb1, caa, cw2, cb2,
                                      fcw, fcb, k1w, k1b, k2w, k2b, k3w, k3b,
                                      kAhi, kAlo, kBhi, kBlo);
    final_mfma<<<dim3(PLANE / 64, 8), 256, 0, stream>>>(
        x, rph, rpl, smap, kAhi, kAlo, kBhi, kBlo, hcb, out);
}

// Round 10
// 706.329 us; speedup vs baseline: 1.5060x; 1.1961x over previous
//
#include <hip/hip_runtime.h>
#include <math.h>

#define HH 256
#define WW 256
#define CC 64
#define PLANE (HH*WW)

typedef short s16x8 __attribute__((ext_vector_type(8)));
typedef float f32x16 __attribute__((ext_vector_type(16)));
typedef unsigned int uint;
typedef uint u32x4v __attribute__((ext_vector_type(4)));

__device__ inline uint bf16rne(float f) {
    uint u = __float_as_uint(f);
    return (u + 0x7FFFu + ((u >> 16) & 1u)) >> 16;
}
__device__ inline float bf16val(uint h) { return __uint_as_float(h << 16); }
__device__ inline s16x8 fragpack(uint4 q) {
    u32x4v t = {q.x, q.y, q.z, q.w};
    return __builtin_bit_cast(s16x8, t);
}
__device__ inline void gload_lds16(const uint* g, uint* l) {
    __builtin_amdgcn_global_load_lds(
        (const __attribute__((address_space(1))) uint*)g,
        (__attribute__((address_space(3))) uint*)l, 16, 0, 0);
}
// activation fragment-slot layout: dword (pix, dwi) at
//   (pix>>5)*1024 + (dwi>>2)*128 + (pix&31)*4 + (dwi&3)
__device__ inline size_t chunk_addr(int pix, int c2) {
    return (size_t)(pix >> 5) * 1024 + c2 * 128 + (pix & 31) * 4;
}
// weight fragment-slot layout: dword (tap, oc, dwi) at
//   tap*2048 + (dwi>>2)*256 + oc*4 + (dwi&3)   -> lane-dense dwordx4 loads

// ---------------- weight prep: split fp32 W into bf16 hi/lo ----------------
__global__ __launch_bounds__(256) void wprep_kernel(
    const float* __restrict__ w1, const float* __restrict__ w2,
    uint* __restrict__ wh1, uint* __restrict__ wl1,
    uint* __restrict__ wh2, uint* __restrict__ wl2)
{
    const int idx = blockIdx.x * 256 + threadIdx.x;      // 0..18431
    const float* w = blockIdx.y ? w2 : w1;
    uint* wh = blockIdx.y ? wh2 : wh1;
    uint* wl = blockIdx.y ? wl2 : wl1;
    const int tap = idx >> 11;           // 9
    const int oc  = (idx >> 5) & 63;     // 64
    const int icp = idx & 31;            // 32 ic-pairs (dword index)
    float w0 = w[(oc * 64 + 2 * icp) * 9 + tap];
    float w1v = w[(oc * 64 + 2 * icp + 1) * 9 + tap];
    uint h0 = bf16rne(w0); float l0 = w0 - bf16val(h0);
    uint h1 = bf16rne(w1v); float l1 = w1v - bf16val(h1);
    const int a = tap * 2048 + (icp >> 2) * 256 + oc * 4 + (icp & 3);
    wh[a] = h0 | (h1 << 16);
    wl[a] = bf16rne(l0) | (bf16rne(l1) << 16);
}

// ---------------- x repack: fp32 NCHW -> bf16-pair fragment-slot ----------------
__global__ __launch_bounds__(256) void xrepack_kernel(
    const float* __restrict__ x, uint* __restrict__ xp)
{
    const int tid = threadIdx.x;
    const int px = blockIdx.x * 256 + tid;
    const int b = blockIdx.y;
    const float* xb = x + (size_t)b * CC * PLANE + px;
    uint d[32];
#pragma unroll
    for (int icp = 0; icp < 32; icp++) {
        float v0 = xb[(size_t)(2 * icp) * PLANE];
        float v1 = xb[(size_t)(2 * icp + 1) * PLANE];
        d[icp] = bf16rne(v0) | (bf16rne(v1) << 16);
    }
    uint* o = xp + (size_t)b * PLANE * 32 + chunk_addr(px, 0);
#pragma unroll
    for (int k = 0; k < 8; k++)
        *(uint4*)(o + k * 128) = make_uint4(d[4*k], d[4*k+1], d[4*k+2], d[4*k+3]);
}

// ---------------- conv 3x3 reflect via MFMA, LDS halo, per-tap batched loads --
// MODE 1: PReLU + fragment-slot (hi only) out.
// MODE 2: fragment-slot hi/lo out (sequential transposes) + fused chan mean/max.
#define HPIX 340                 // 10*34 halo pixels
#define HCHUNK (HPIX*8)          // 16B chunks = 2720
template<int MODE>
__global__ __launch_bounds__(256, 2) void conv_mfma(
    const uint* __restrict__ xin,   // fragment-slot packed
    const uint* __restrict__ wh, const uint* __restrict__ wl,
    const float* __restrict__ bias, const float* __restrict__ prelu,
    uint* __restrict__ op, uint* __restrict__ op2, float* __restrict__ amx)
{
    __shared__ uint lds[HPIX * 32];          // 43,520 B (transposes reuse it)
    const int tid  = threadIdx.x;
    const int lane = tid & 63;
    const int wid  = tid >> 6;
    const int x0 = blockIdx.x * 32;
    const int y0 = blockIdx.y * 8;
    const int b  = blockIdx.z;
    const int colx = lane & 31;
    const int half = lane >> 5;
    const int r0 = wid * 2;

    // ---- stage halo: chunk k -> LDS byte k*16 (linear), source pre-swizzled
    {
        const uint* gb = xin + (size_t)b * PLANE * 32;
#pragma unroll
        for (int iter = 0; iter < 11; iter++) {
            const int k = iter * 256 + tid;
            if (iter < 10 || k < HCHUNK) {
                const int pix = k >> 3;
                const int slot = k & 7;
                const int hrow = pix / 34;
                const int hcol = pix - hrow * 34;
                int gy = y0 - 1 + hrow; gy = gy < 0 ? 1 : (gy > 255 ? 254 : gy);
                int gx = x0 - 1 + hcol; gx = gx < 0 ? 1 : (gx > 255 ? 254 : gx);
                const int c2 = slot ^ (pix & 7);    // involution
                gload_lds16(gb + chunk_addr(gy * 256 + gx, c2),
                            &lds[(iter * 256 + wid * 64) * 4]);
            }
        }
    }
    __syncthreads();

    f32x16 acc00 = (f32x16)0.f, acc01 = (f32x16)0.f;   // [Mtile][row]
    f32x16 acc10 = (f32x16)0.f, acc11 = (f32x16)0.f;

    // lane-dense weight base: dword (tap,oc,dwi) at tap*2048+(dwi>>2)*256+oc*4+(dwi&3)
    const uint* wlh = wh + half * 256 + colx * 4;
    const uint* wll = wl + half * 256 + colx * 4;

#pragma unroll
    for (int tap = 0; tap < 9; tap++) {
        const int dy = tap / 3, dx = tap % 3;
        const int pix0 = (r0 + dy) * 34 + dx + colx;   // output row r0
        const int pix1 = pix0 + 34;                    // output row r0+1

        uint4 B0[4], B1[4], H0[4], H1[4], L0[4], L1[4];
#pragma unroll
        for (int c = 0; c < 4; c++) {
            const int c2 = c * 2 + half;
            B0[c] = *(const uint4*)&lds[(pix0 * 8 + (c2 ^ (pix0 & 7))) * 4];
            B1[c] = *(const uint4*)&lds[(pix1 * 8 + (c2 ^ (pix1 & 7))) * 4];
        }
#pragma unroll
        for (int c = 0; c < 4; c++) {
            H0[c] = *(const uint4*)(wlh + tap * 2048 + c * 512);
            H1[c] = *(const uint4*)(wlh + tap * 2048 + c * 512 + 128);
        }
#pragma unroll
        for (int c = 0; c < 4; c++) {
            L0[c] = *(const uint4*)(wll + tap * 2048 + c * 512);
            L1[c] = *(const uint4*)(wll + tap * 2048 + c * 512 + 128);
        }
#pragma unroll
        for (int c = 0; c < 4; c++) {
            const s16x8 b0 = fragpack(B0[c]), b1 = fragpack(B1[c]);
            acc00 = __builtin_amdgcn_mfma_f32_32x32x16_bf16(fragpack(H0[c]), b0, acc00, 0, 0, 0);
            acc01 = __builtin_amdgcn_mfma_f32_32x32x16_bf16(fragpack(H0[c]), b1, acc01, 0, 0, 0);
            acc10 = __builtin_amdgcn_mfma_f32_32x32x16_bf16(fragpack(H1[c]), b0, acc10, 0, 0, 0);
            acc11 = __builtin_amdgcn_mfma_f32_32x32x16_bf16(fragpack(H1[c]), b1, acc11, 0, 0, 0);
        }
#pragma unroll
        for (int c = 0; c < 4; c++) {
            const s16x8 b0 = fragpack(B0[c]), b1 = fragpack(B1[c]);
            acc00 = __builtin_amdgcn_mfma_f32_32x32x16_bf16(fragpack(L0[c]), b0, acc00, 0, 0, 0);
            acc01 = __builtin_amdgcn_mfma_f32_32x32x16_bf16(fragpack(L0[c]), b1, acc01, 0, 0, 0);
            acc10 = __builtin_amdgcn_mfma_f32_32x32x16_bf16(fragpack(L1[c]), b0, acc10, 0, 0, 0);
            acc11 = __builtin_amdgcn_mfma_f32_32x32x16_bf16(fragpack(L1[c]), b1, acc11, 0, 0, 0);
        }
    }

    // ---- epilogue. C/D layout (32x32): col=lane&31 (pixel), row=(j&3)+8*(j>>2)+4*half (oc)
    const int prow = tid >> 5, pcol = tid & 31;
    if constexpr (MODE == 1) {
        __syncthreads();                    // halo reads done; reuse lds for transpose
#define ST1(ACC, MT, RR) { \
        _Pragma("unroll") \
        for (int j = 0; j < 16; j += 2) { \
            const int row = (j & 3) + 8 * (j >> 2) + 4 * half; \
            const int oc = MT * 32 + row; \
            float v0 = ACC[j]     + bias[oc]; \
            float v1 = ACC[j + 1] + bias[oc + 1]; \
            const float a0 = prelu[oc], a1 = prelu[oc + 1]; \
            v0 = fmaxf(v0, 0.f) + a0 * fminf(v0, 0.f); \
            v1 = fmaxf(v1, 0.f) + a1 * fminf(v1, 0.f); \
            const int icp = oc >> 1; \
            lds[((RR) * 32 + icp) * 32 + (colx ^ icp)] = \
                bf16rne(v0) | (bf16rne(v1) << 16); \
        } }
        ST1(acc00, 0, r0) ST1(acc01, 0, r0 + 1) ST1(acc10, 1, r0) ST1(acc11, 1, r0 + 1)
#undef ST1
        __syncthreads();
        uint d[32];
#pragma unroll
        for (int i = 0; i < 32; i++)
            d[i] = lds[(prow * 32 + i) * 32 + (pcol ^ i)];
        uint* o = op + (size_t)b * PLANE * 32
                     + chunk_addr((y0 + prow) * 256 + x0 + pcol, 0);
#pragma unroll
        for (int k = 0; k < 8; k++)
            *(uint4*)(o + k * 128) = make_uint4(d[4*k], d[4*k+1], d[4*k+2], d[4*k+3]);
    } else {
        // hi pass, then lo pass, reusing the halo LDS (8192 dwords needed)
        const size_t pixg = (size_t)(y0 + prow) * 256 + x0 + pcol;
        const size_t cb = (size_t)b * PLANE * 32 + chunk_addr((int)pixg, 0);
        uint d[32], dl[32];
        __syncthreads();
#define STH(ACC, MT, RR) { \
        _Pragma("unroll") \
        for (int j = 0; j < 16; j += 2) { \
            const int row = (j & 3) + 8 * (j >> 2) + 4 * half; \
            const int oc = MT * 32 + row; \
            float v0 = ACC[j]     + bias[oc]; \
            float v1 = ACC[j + 1] + bias[oc + 1]; \
            const int icp = oc >> 1; \
            lds[((RR) * 32 + icp) * 32 + (colx ^ icp)] = \
                bf16rne(v0) | (bf16rne(v1) << 16); \
        } }
        STH(acc00, 0, r0) STH(acc01, 0, r0 + 1) STH(acc10, 1, r0) STH(acc11, 1, r0 + 1)
#undef STH
        __syncthreads();
#pragma unroll
        for (int i = 0; i < 32; i++)
            d[i] = lds[(prow * 32 + i) * 32 + (pcol ^ i)];
        uint* oh = op + cb;
#pragma unroll
        for (int k = 0; k < 8; k++)
            *(uint4*)(oh + k * 128) = make_uint4(d[4*k], d[4*k+1], d[4*k+2], d[4*k+3]);
        __syncthreads();
#define STL(ACC, MT, RR) { \
        _Pragma("unroll") \
        for (int j = 0; j < 16; j += 2) { \
            const int row = (j & 3) + 8 * (j >> 2) + 4 * half; \
            const int oc = MT * 32 + row; \
            float v0 = ACC[j]     + bias[oc]; \
            float v1 = ACC[j + 1] + bias[oc + 1]; \
            float l0 = v0 - bf16val(bf16rne(v0)); \
            float l1 = v1 - bf16val(bf16rne(v1)); \
            const int icp = oc >> 1; \
            lds[((RR) * 32 + icp) * 32 + (colx ^ icp)] = \
                bf16rne(l0) | (bf16rne(l1) << 16); \
        } }
        STL(acc00, 0, r0) STL(acc01, 0, r0 + 1) STL(acc10, 1, r0) STL(acc11, 1, r0 + 1)
#undef STL
        __syncthreads();
        float s_ = 0.f, m_ = -INFINITY;
#pragma unroll
        for (int i = 0; i < 32; i++) {
            dl[i] = lds[(prow * 32 + i) * 32 + (pcol ^ i)];
            float ve = bf16val(d[i] & 0xffffu) + bf16val(dl[i] & 0xffffu);
            float vo = bf16val(d[i] >> 16)     + bf16val(dl[i] >> 16);
            s_ += ve + vo;
            m_ = fmaxf(m_, fmaxf(ve, vo));
        }
        uint* ol = op2 + cb;
#pragma unroll
        for (int k = 0; k < 8; k++)
            *(uint4*)(ol + k * 128) = make_uint4(dl[4*k], dl[4*k+1], dl[4*k+2], dl[4*k+3]);
        amx[(size_t)b * 2 * PLANE + pixg] = s_ * (1.f / 64.f);
        amx[(size_t)b * 2 * PLANE + PLANE + pixg] = m_;
    }
}

// ---------------- global average pool from fragment-slot hi: g[b,c] ----------
__global__ __launch_bounds__(256) void gpool_kernel(
    const uint* __restrict__ rph, float* __restrict__ g /*[B*C], pre-zeroed*/)
{
    const int tid = threadIdx.x;
    const int b = blockIdx.y;
    const uint* base = rph + (size_t)b * PLANE * 32;
    float s[8];
#pragma unroll
    for (int i = 0; i < 8; i++) s[i] = 0.f;
    for (int it = 0; it < 32; it++) {
        const size_t a = ((size_t)blockIdx.x * 32 + it) * 1024 + tid * 4;
        const uint4 q = *(const uint4*)(base + a);
        s[0] += bf16val(q.x & 0xffffu); s[1] += bf16val(q.x >> 16);
        s[2] += bf16val(q.y & 0xffffu); s[3] += bf16val(q.y >> 16);
        s[4] += bf16val(q.z & 0xffffu); s[5] += bf16val(q.z >> 16);
        s[6] += bf16val(q.w & 0xffffu); s[7] += bf16val(q.w >> 16);
    }
#pragma unroll
    for (int off = 16; off >= 1; off >>= 1)
#pragma unroll
        for (int i = 0; i < 8; i++) s[i] += __shfl_xor(s[i], off, 64);
    if ((tid & 31) == 0) {
        const int grp = tid >> 5;   // 0..7
#pragma unroll
        for (int i = 0; i < 8; i++)
            atomicAdd(&g[b * 64 + grp * 8 + i], s[i] * (1.f / PLANE));
    }
}

// ---------------- spatial-attention 3x3 conv (2ch -> 1ch) ----------------
__global__ __launch_bounds__(256) void saconv_kernel(
    const float* __restrict__ amx, const float* __restrict__ sa_w,
    const float* __restrict__ sa_b, float* __restrict__ smap)
{
    int pix = blockIdx.x * 256 + threadIdx.x;
    int b = blockIdx.y;
    int x = pix & 255, y = pix >> 8;
    float acc = sa_b[0];
    const float* ab = amx + (size_t)b * 2 * PLANE;
#pragma unroll
    for (int c = 0; c < 2; c++)
#pragma unroll
        for (int dy = -1; dy <= 1; dy++)
#pragma unroll
            for (int dx = -1; dx <= 1; dx++) {
                int gx = x + dx; gx = gx < 0 ? 1 : (gx >= WW ? 2 * WW - 2 - gx : gx);
                int gy = y + dy; gy = gy < 0 ? 1 : (gy >= HH ? 2 * HH - 2 - gy : gy);
                acc += sa_w[c * 9 + (dy + 1) * 3 + (dx + 1)] * ab[(size_t)c * PLANE + gy * WW + gx];
            }
    smap[(size_t)b * PLANE + pix] = acc;
}

// ---------------- tiny MLPs -> hyper kernels, fragment-slot hi/lo --------
__global__ __launch_bounds__(256) void mlp_kernel(
    const float* __restrict__ h, const float* __restrict__ g,
    const float* __restrict__ ca_w1, const float* __restrict__ ca_b1,
    const float* __restrict__ ca_a,
    const float* __restrict__ ca_w2, const float* __restrict__ ca_b2,
    const float* __restrict__ fc_w, const float* __restrict__ fc_b,
    const float* __restrict__ k1_w, const float* __restrict__ k1_b,
    const float* __restrict__ k2_w, const float* __restrict__ k2_b,
    const float* __restrict__ k3_w, const float* __restrict__ k3_b,
    uint* __restrict__ kAhi, uint* __restrict__ kAlo,
    uint* __restrict__ kBhi, uint* __restrict__ kBlo)
{
    int b = blockIdx.x, tid = threadIdx.x;
    __shared__ float gb[64], t16[16], u32[32], v32[32], cg1[32], casig[64];

    if (tid < 64) gb[tid] = g[b * 64 + tid];
    __syncthreads();

    if (tid < 16) {
        float s = fc_b[tid];
        for (int j = 0; j < 16; j++) s += fc_w[tid * 16 + j] * h[b * 16 + j];
        t16[tid] = s >= 0.f ? s : 0.01f * s;
    }
    if (tid < 32) {
        float c1 = ca_b1[tid];
        for (int j = 0; j < 64; j++) c1 += ca_w1[tid * 64 + j] * gb[j];
        cg1[tid] = fmaxf(c1, 0.f) + ca_a[tid] * fminf(c1, 0.f);
    }
    __syncthreads();
    if (tid < 32) {
        float s = k1_b[tid];
        for (int j = 0; j < 16; j++) s += k1_w[tid * 16 + j] * t16[j];
        u32[tid] = s >= 0.f ? s : 0.01f * s;
    }
    if (tid < 64) {
        float c2 = ca_b2[tid];
        for (int j = 0; j < 32; j++) c2 += ca_w2[tid * 32 + j] * cg1[j];
        casig[tid] = 1.f / (1.f + expf(-c2));
    }
    __syncthreads();
    if (tid < 32) {
        float s = k2_b[tid];
        for (int j = 0; j < 32; j++) s += k2_w[tid * 32 + j] * u32[j];
        v32[tid] = s >= 0.f ? s : 0.01f * s;
    }
    __syncthreads();
    // k3: 8192 outputs, adjacent pairs -> one packed dword, fragment-slot store
    for (int o2 = tid; o2 < 4096; o2 += 256) {
        const int o = o2 * 2;
        const int oc = o >> 7;        // /128
        const int i = o & 127;        // even
        float s0 = k3_b[o], s1 = k3_b[o + 1];
        for (int j = 0; j < 32; j++) {
            s0 += k3_w[(size_t)o * 32 + j] * v32[j];
            s1 += k3_w[(size_t)(o + 1) * 32 + j] * v32[j];
        }
        uint *hi, *lo;
        if (i < 64) { hi = kAhi; lo = kAlo; }
        else { s0 *= casig[i - 64]; s1 *= casig[i - 63]; hi = kBhi; lo = kBlo; }
        const int cp = (i & 63) >> 1;
        uint h0 = bf16rne(s0); float l0 = s0 - bf16val(h0);
        uint h1 = bf16rne(s1); float l1 = s1 - bf16val(h1);
        const size_t a = (size_t)b * 2048 + (cp >> 2) * 256 + oc * 4 + (cp & 3);
        hi[a] = h0 | (h1 << 16);
        lo[a] = bf16rne(l0) | (bf16rne(l1) << 16);
    }
}

// ---------------- final via MFMA: out = x + hcb + sig(s)*(A.r) + (B.r) --------
__global__ __launch_bounds__(256, 2) void final_mfma(
    const float* __restrict__ x, const uint* __restrict__ rph,
    const uint* __restrict__ rpl, const float* __restrict__ smap,
    const uint* __restrict__ kAhi, const uint* __restrict__ kAlo,
    const uint* __restrict__ kBhi, const uint* __restrict__ kBlo,
    const float* __restrict__ hcb, float* __restrict__ out)
{
    const int tid = threadIdx.x;
    const int lane = tid & 63;
    const int wid = tid >> 6;
    const int mt = wid & 1;          // oc Mtile
    const int gq = wid >> 1;         // pixel group
    const int b = blockIdx.y;
    const int colx = lane & 31;
    const int half = lane >> 5;
    const int pix = blockIdx.x * 64 + gq * 32 + colx;
    const int pgroup = blockIdx.x * 2 + gq;   // pix >> 5

    // fragment-slot kernel loads (lane-dense)
    const size_t kb = (size_t)b * 2048 + half * 256 + (size_t)(mt * 32 + colx) * 4;
    uint4 KAh[4], KAl[4], KBh[4], KBl[4];
#pragma unroll
    for (int c = 0; c < 4; c++) {
        KAh[c] = *(const uint4*)(kAhi + kb + c * 512);
        KAl[c] = *(const uint4*)(kAlo + kb + c * 512);
        KBh[c] = *(const uint4*)(kBhi + kb + c * 512);
        KBl[c] = *(const uint4*)(kBlo + kb + c * 512);
    }
    // fragment-slot activation loads
    const size_t rb = (size_t)b * PLANE * 32 + (size_t)pgroup * 1024
                    + half * 128 + colx * 4;
    uint4 Bh[4], Bl[4];
#pragma unroll
    for (int c = 0; c < 4; c++) {
        Bh[c] = *(const uint4*)(rph + rb + c * 256);
        Bl[c] = *(const uint4*)(rpl + rb + c * 256);
    }
    f32x16 accA = (f32x16)0.f, accB = (f32x16)0.f;
#pragma unroll
    for (int c = 0; c < 4; c++) {
        const s16x8 bh = fragpack(Bh[c]), bl = fragpack(Bl[c]);
        const s16x8 ah = fragpack(KAh[c]), al = fragpack(KAl[c]);
        const s16x8 ch = fragpack(KBh[c]), cl = fragpack(KBl[c]);
        accA = __builtin_amdgcn_mfma_f32_32x32x16_bf16(ah, bh, accA, 0, 0, 0);
        accA = __builtin_amdgcn_mfma_f32_32x32x16_bf16(ah, bl, accA, 0, 0, 0);
        accA = __builtin_amdgcn_mfma_f32_32x32x16_bf16(al, bh, accA, 0, 0, 0);
        accB = __builtin_amdgcn_mfma_f32_32x32x16_bf16(ch, bh, accB, 0, 0, 0);
        accB = __builtin_amdgcn_mfma_f32_32x32x16_bf16(ch, bl, accB, 0, 0, 0);
        accB = __builtin_amdgcn_mfma_f32_32x32x16_bf16(cl, bh, accB, 0, 0, 0);
    }
    const float sv = smap[(size_t)b * PLANE + pix];
    const float sig = 1.f / (1.f + expf(-sv));
#pragma unroll
    for (int j = 0; j < 16; j++) {
        const int row = (j & 3) + 8 * (j >> 2) + 4 * half;
        const int oc = mt * 32 + row;
        const size_t idx = ((size_t)b * 64 + oc) * PLANE + pix;
        out[idx] = x[idx] + hcb[oc] + sig * accA[j] + accB[j];
    }
}

extern "C" void kernel_launch(void* const* d_in, const int* in_sizes, int n_in,
                              void* d_out, int out_size, void* d_ws, size_t ws_size,
                              hipStream_t stream) {
    const float* x   = (const float*)d_in[0];
    const float* h   = (const float*)d_in[1];
    const float* c1w = (const float*)d_in[2];
    const float* c1b = (const float*)d_in[3];
    const float* pa  = (const float*)d_in[4];
    const float* c2w = (const float*)d_in[5];
    const float* c2b = (const float*)d_in[6];
    const float* saw = (const float*)d_in[7];
    const float* sab = (const float*)d_in[8];
    const float* cw1 = (const float*)d_in[9];
    const float* cb1 = (const float*)d_in[10];
    const float* caa = (const float*)d_in[11];
    const float* cw2 = (const float*)d_in[12];
    const float* cb2 = (const float*)d_in[13];
    const float* fcw = (const float*)d_in[14];
    const float* fcb = (const float*)d_in[15];
    const float* k1w = (const float*)d_in[16];
    const float* k1b = (const float*)d_in[17];
    const float* k2w = (const float*)d_in[18];
    const float* k2b = (const float*)d_in[19];
    const float* k3w = (const float*)d_in[20];
    const float* k3b = (const float*)d_in[21];
    const float* hcb = (const float*)d_in[22];
    float* out = (float*)d_out;

    char* ws = (char*)d_ws;
    const size_t SZ_Q = (size_t)8 * PLANE * 32 * 4;   // 67,108,864 (packed)
    uint*  xp  = (uint*)ws;                           // x repacked
    uint*  r1p = (uint*)(ws + SZ_Q);                  // conv1 out (hi)
    uint*  rph = (uint*)(ws + 2 * SZ_Q);              // conv2 out hi
    uint*  rpl = (uint*)(ws + 3 * SZ_Q);              // conv2 out lo
    float* amx   = (float*)ws;                        // aliases xp (dead after conv1)
    float* smap  = (float*)(ws + (size_t)8 * 2 * PLANE * 4);
    float* g     = (float*)(ws + (size_t)8 * 3 * PLANE * 4);
    uint*  kAhi  = (uint*)(ws + (size_t)8 * 3 * PLANE * 4 + 4096);
    uint*  kAlo  = kAhi + 8 * 2048;
    uint*  kBhi  = kAlo + 8 * 2048;
    uint*  kBlo  = kBhi + 8 * 2048;

    // weight packs live in d_out (dead until final_mfma overwrites it)
    uint* wsp = (uint*)d_out;
    uint* wh1 = wsp;          uint* wl1 = wsp + 18432;
    uint* wh2 = wsp + 36864;  uint* wl2 = wsp + 55296;

    wprep_kernel<<<dim3(72, 2), 256, 0, stream>>>(c1w, c2w, wh1, wl1, wh2, wl2);
    xrepack_kernel<<<dim3(PLANE / 256, 8), 256, 0, stream>>>(x, xp);

    dim3 cgrid(WW / 32, HH / 8, 8);  // (8, 32, 8)
    conv_mfma<1><<<cgrid, 256, 0, stream>>>(xp, wh1, wl1, c1b, pa, r1p, nullptr, nullptr);
    conv_mfma<2><<<cgrid, 256, 0, stream>>>(r1p, wh2, wl2, c2b, nullptr, rph, rpl, amx);

    hipMemsetAsync(g, 0, 512 * sizeof(float), stream);
    gpool_kernel<<<dim3(64, 8), 256, 0, stream>>>(rph, g);
    saconv_kernel<<<dim3(PLANE / 256, 8), 256, 0, stream>>>(amx, saw, sab, smap);
    mlp_kernel<<<8, 256, 0, stream>>>(h, g, cw1, cb1, caa, cw2, cb2,
                                      fcw, fcb, k1w, k1b, k2w, k2b, k3w, k3b,
                                      kAhi, kAlo, kBhi, kBlo);
    final_mfma<<<dim3(PLANE / 64, 8), 256, 0, stream>>>(
        x, rph, rpl, smap, kAhi, kAlo, kBhi, kBlo, hcb, out);
}

// Round 11
// 662.338 us; speedup vs baseline: 1.6061x; 1.0664x over previous
//
#include <hip/hip_runtime.h>
#include <math.h>

#define HH 256
#define WW 256
#define CC 64
#define PLANE (HH*WW)

typedef short s16x8 __attribute__((ext_vector_type(8)));
typedef float f32x16 __attribute__((ext_vector_type(16)));
typedef unsigned int uint;
typedef uint u32x4v __attribute__((ext_vector_type(4)));

__device__ inline uint bf16rne(float f) {
    uint u = __float_as_uint(f);
    return (u + 0x7FFFu + ((u >> 16) & 1u)) >> 16;
}
__device__ inline float bf16val(uint h) { return __uint_as_float(h << 16); }
__device__ inline s16x8 fragpack(uint4 q) {
    u32x4v t = {q.x, q.y, q.z, q.w};
    return __builtin_bit_cast(s16x8, t);
}
__device__ inline void gload_lds16(const uint* g, uint* l) {
    __builtin_amdgcn_global_load_lds(
        (const __attribute__((address_space(1))) uint*)g,
        (__attribute__((address_space(3))) uint*)l, 16, 0, 0);
}
// activation fragment-slot layout: dword (pix, dwi) at
//   (pix>>5)*1024 + (dwi>>2)*128 + (pix&31)*4 + (dwi&3)
__device__ inline size_t chunk_addr(int pix, int c2) {
    return (size_t)(pix >> 5) * 1024 + c2 * 128 + (pix & 31) * 4;
}
// weight fragment-slot layout: dword (tap, oc, dwi) at
//   tap*2048 + (dwi>>2)*256 + oc*4 + (dwi&3)   -> lane-dense dwordx4 loads

// ---------------- weight prep: split fp32 W into bf16 hi/lo ----------------
__global__ __launch_bounds__(256) void wprep_kernel(
    const float* __restrict__ w1, const float* __restrict__ w2,
    uint* __restrict__ wh1, uint* __restrict__ wl1,
    uint* __restrict__ wh2, uint* __restrict__ wl2)
{
    const int idx = blockIdx.x * 256 + threadIdx.x;      // 0..18431
    const float* w = blockIdx.y ? w2 : w1;
    uint* wh = blockIdx.y ? wh2 : wh1;
    uint* wl = blockIdx.y ? wl2 : wl1;
    const int tap = idx >> 11;           // 9
    const int oc  = (idx >> 5) & 63;     // 64
    const int icp = idx & 31;            // 32 ic-pairs (dword index)
    float w0 = w[(oc * 64 + 2 * icp) * 9 + tap];
    float w1v = w[(oc * 64 + 2 * icp + 1) * 9 + tap];
    uint h0 = bf16rne(w0); float l0 = w0 - bf16val(h0);
    uint h1 = bf16rne(w1v); float l1 = w1v - bf16val(h1);
    const int a = tap * 2048 + (icp >> 2) * 256 + oc * 4 + (icp & 3);
    wh[a] = h0 | (h1 << 16);
    wl[a] = bf16rne(l0) | (bf16rne(l1) << 16);
}

// ---------------- x repack: fp32 NCHW -> bf16-pair fragment-slot ----------------
__global__ __launch_bounds__(256) void xrepack_kernel(
    const float* __restrict__ x, uint* __restrict__ xp)
{
    const int tid = threadIdx.x;
    const int px = blockIdx.x * 256 + tid;
    const int b = blockIdx.y;
    const float* xb = x + (size_t)b * CC * PLANE + px;
    uint d[32];
#pragma unroll
    for (int icp = 0; icp < 32; icp++) {
        float v0 = xb[(size_t)(2 * icp) * PLANE];
        float v1 = xb[(size_t)(2 * icp + 1) * PLANE];
        d[icp] = bf16rne(v0) | (bf16rne(v1) << 16);
    }
    uint* o = xp + (size_t)b * PLANE * 32 + chunk_addr(px, 0);
#pragma unroll
    for (int k = 0; k < 8; k++)
        *(uint4*)(o + k * 128) = make_uint4(d[4*k], d[4*k+1], d[4*k+2], d[4*k+3]);
}

// ---------------- conv 3x3 reflect via MFMA, LDS halo ----------------
// wave w: Mtile mt = w&1 (32 oc), row-quad rq = w>>1 (rows rq*4..rq*4+3).
// Per tap: 8 weight dwordx4 (ONE Mtile, hi+lo) + 16 ds_read_b128, processed in
// two row-pair halves -> peak live ~130 VGPR, RA can batch -> one latency
// exposure per half instead of ~6 per tap.
// MODE 1: PReLU + fragment-slot (hi only) out.
// MODE 2: fragment-slot hi/lo out (sequential transposes) + fused chan mean/max.
#define HPIX 340                 // 10*34 halo pixels
#define HCHUNK (HPIX*8)          // 16B chunks = 2720
template<int MODE>
__global__ __launch_bounds__(256) void conv_mfma(
    const uint* __restrict__ xin,   // fragment-slot packed
    const uint* __restrict__ wh, const uint* __restrict__ wl,
    const float* __restrict__ bias, const float* __restrict__ prelu,
    uint* __restrict__ op, uint* __restrict__ op2, float* __restrict__ amx)
{
    __shared__ uint lds[HPIX * 32];          // 43,520 B (transposes reuse it)
    const int tid  = threadIdx.x;
    const int lane = tid & 63;
    const int wid  = tid >> 6;
    const int x0 = blockIdx.x * 32;
    const int y0 = blockIdx.y * 8;
    const int b  = blockIdx.z;
    const int colx = lane & 31;
    const int half = lane >> 5;
    const int mt = wid & 1;          // Mtile (oc group of 32)
    const int rq = wid >> 1;         // row quad: rows rq*4 .. rq*4+3

    // ---- stage halo: chunk k -> LDS byte k*16 (linear), source pre-swizzled
    {
        const uint* gb = xin + (size_t)b * PLANE * 32;
#pragma unroll
        for (int iter = 0; iter < 11; iter++) {
            const int k = iter * 256 + tid;
            if (iter < 10 || k < HCHUNK) {
                const int pix = k >> 3;
                const int slot = k & 7;
                const int hrow = pix / 34;
                const int hcol = pix - hrow * 34;
                int gy = y0 - 1 + hrow; gy = gy < 0 ? 1 : (gy > 255 ? 254 : gy);
                int gx = x0 - 1 + hcol; gx = gx < 0 ? 1 : (gx > 255 ? 254 : gx);
                const int c2 = slot ^ (pix & 7);    // involution
                gload_lds16(gb + chunk_addr(gy * 256 + gx, c2),
                            &lds[(iter * 256 + wid * 64) * 4]);
            }
        }
    }
    __syncthreads();

    f32x16 acc0 = (f32x16)0.f, acc1 = (f32x16)0.f;   // rows rq*4+0..3
    f32x16 acc2 = (f32x16)0.f, acc3 = (f32x16)0.f;

    // lane-dense weight base for this wave's Mtile
    const uint* wbh = wh + half * 256 + (mt * 32 + colx) * 4;
    const uint* wbl = wl + half * 256 + (mt * 32 + colx) * 4;

#pragma unroll
    for (int tap = 0; tap < 9; tap++) {
        const int dy = tap / 3, dx = tap % 3;
        const int pixb = (rq * 4 + dy) * 34 + dx + colx;   // row rq*4

        uint4 Hc[4], Lc[4];
#pragma unroll
        for (int c = 0; c < 4; c++) {
            Hc[c] = *(const uint4*)(wbh + tap * 2048 + c * 512);
            Lc[c] = *(const uint4*)(wbl + tap * 2048 + c * 512);
        }
        {   // rows 0,1 of the quad
            uint4 Ba[4], Bb[4];
#pragma unroll
            for (int c = 0; c < 4; c++) {
                const int c2 = c * 2 + half;
                const int p0 = pixb, p1 = pixb + 34;
                Ba[c] = *(const uint4*)&lds[(p0 * 8 + (c2 ^ (p0 & 7))) * 4];
                Bb[c] = *(const uint4*)&lds[(p1 * 8 + (c2 ^ (p1 & 7))) * 4];
            }
#pragma unroll
            for (int c = 0; c < 4; c++) {
                const s16x8 b0 = fragpack(Ba[c]), b1 = fragpack(Bb[c]);
                const s16x8 ah = fragpack(Hc[c]), al = fragpack(Lc[c]);
                acc0 = __builtin_amdgcn_mfma_f32_32x32x16_bf16(ah, b0, acc0, 0, 0, 0);
                acc1 = __builtin_amdgcn_mfma_f32_32x32x16_bf16(ah, b1, acc1, 0, 0, 0);
                acc0 = __builtin_amdgcn_mfma_f32_32x32x16_bf16(al, b0, acc0, 0, 0, 0);
                acc1 = __builtin_amdgcn_mfma_f32_32x32x16_bf16(al, b1, acc1, 0, 0, 0);
            }
        }
        {   // rows 2,3 of the quad
            uint4 Ba[4], Bb[4];
#pragma unroll
            for (int c = 0; c < 4; c++) {
                const int c2 = c * 2 + half;
                const int p0 = pixb + 68, p1 = pixb + 102;
                Ba[c] = *(const uint4*)&lds[(p0 * 8 + (c2 ^ (p0 & 7))) * 4];
                Bb[c] = *(const uint4*)&lds[(p1 * 8 + (c2 ^ (p1 & 7))) * 4];
            }
#pragma unroll
            for (int c = 0; c < 4; c++) {
                const s16x8 b0 = fragpack(Ba[c]), b1 = fragpack(Bb[c]);
                const s16x8 ah = fragpack(Hc[c]), al = fragpack(Lc[c]);
                acc2 = __builtin_amdgcn_mfma_f32_32x32x16_bf16(ah, b0, acc2, 0, 0, 0);
                acc3 = __builtin_amdgcn_mfma_f32_32x32x16_bf16(ah, b1, acc3, 0, 0, 0);
                acc2 = __builtin_amdgcn_mfma_f32_32x32x16_bf16(al, b0, acc2, 0, 0, 0);
                acc3 = __builtin_amdgcn_mfma_f32_32x32x16_bf16(al, b1, acc3, 0, 0, 0);
            }
        }
    }

    // ---- epilogue. C/D layout (32x32): col=lane&31 (pixel), row=(j&3)+8*(j>>2)+4*half (oc)
    // wave covers ocs mt*32..+31, rows rq*4..+3.
    const int prow = tid >> 5, pcol = tid & 31;
    if constexpr (MODE == 1) {
        __syncthreads();                    // halo reads done; reuse lds for transpose
#define ST1(ACC, RR) { \
        _Pragma("unroll") \
        for (int j = 0; j < 16; j += 2) { \
            const int row = (j & 3) + 8 * (j >> 2) + 4 * half; \
            const int oc = mt * 32 + row; \
            float v0 = ACC[j]     + bias[oc]; \
            float v1 = ACC[j + 1] + bias[oc + 1]; \
            const float a0 = prelu[oc], a1 = prelu[oc + 1]; \
            v0 = fmaxf(v0, 0.f) + a0 * fminf(v0, 0.f); \
            v1 = fmaxf(v1, 0.f) + a1 * fminf(v1, 0.f); \
            const int icp = oc >> 1; \
            lds[((RR) * 32 + icp) * 32 + (colx ^ icp)] = \
                bf16rne(v0) | (bf16rne(v1) << 16); \
        } }
        ST1(acc0, rq * 4)     ST1(acc1, rq * 4 + 1)
        ST1(acc2, rq * 4 + 2) ST1(acc3, rq * 4 + 3)
#undef ST1
        __syncthreads();
        uint d[32];
#pragma unroll
        for (int i = 0; i < 32; i++)
            d[i] = lds[(prow * 32 + i) * 32 + (pcol ^ i)];
        uint* o = op + (size_t)b * PLANE * 32
                     + chunk_addr((y0 + prow) * 256 + x0 + pcol, 0);
#pragma unroll
        for (int k = 0; k < 8; k++)
            *(uint4*)(o + k * 128) = make_uint4(d[4*k], d[4*k+1], d[4*k+2], d[4*k+3]);
    } else {
        // hi pass, then lo pass, reusing the halo LDS
        const size_t pixg = (size_t)(y0 + prow) * 256 + x0 + pcol;
        const size_t cb = (size_t)b * PLANE * 32 + chunk_addr((int)pixg, 0);
        uint d[32], dl[32];
        __syncthreads();
#define STH(ACC, RR) { \
        _Pragma("unroll") \
        for (int j = 0; j < 16; j += 2) { \
            const int row = (j & 3) + 8 * (j >> 2) + 4 * half; \
            const int oc = mt * 32 + row; \
            float v0 = ACC[j]     + bias[oc]; \
            float v1 = ACC[j + 1] + bias[oc + 1]; \
            const int icp = oc >> 1; \
            lds[((RR) * 32 + icp) * 32 + (colx ^ icp)] = \
                bf16rne(v0) | (bf16rne(v1) << 16); \
        } }
        STH(acc0, rq * 4)     STH(acc1, rq * 4 + 1)
        STH(acc2, rq * 4 + 2) STH(acc3, rq * 4 + 3)
#undef STH
        __syncthreads();
#pragma unroll
        for (int i = 0; i < 32; i++)
            d[i] = lds[(prow * 32 + i) * 32 + (pcol ^ i)];
        uint* oh = op + cb;
#pragma unroll
        for (int k = 0; k < 8; k++)
            *(uint4*)(oh + k * 128) = make_uint4(d[4*k], d[4*k+1], d[4*k+2], d[4*k+3]);
        __syncthreads();
#define STL(ACC, RR) { \
        _Pragma("unroll") \
        for (int j = 0; j < 16; j += 2) { \
            const int row = (j & 3) + 8 * (j >> 2) + 4 * half; \
            const int oc = mt * 32 + row; \
            float v0 = ACC[j]     + bias[oc]; \
            float v1 = ACC[j + 1] + bias[oc + 1]; \
            float l0 = v0 - bf16val(bf16rne(v0)); \
            float l1 = v1 - bf16val(bf16rne(v1)); \
            const int icp = oc >> 1; \
            lds[((RR) * 32 + icp) * 32 + (colx ^ icp)] = \
                bf16rne(l0) | (bf16rne(l1) << 16); \
        } }
        STL(acc0, rq * 4)     STL(acc1, rq * 4 + 1)
        STL(acc2, rq * 4 + 2) STL(acc3, rq * 4 + 3)
#undef STL
        __syncthreads();
        float s_ = 0.f, m_ = -INFINITY;
#pragma unroll
        for (int i = 0; i < 32; i++) {
            dl[i] = lds[(prow * 32 + i) * 32 + (pcol ^ i)];
            float ve = bf16val(d[i] & 0xffffu) + bf16val(dl[i] & 0xffffu);
            float vo = bf16val(d[i] >> 16)     + bf16val(dl[i] >> 16);
            s_ += ve + vo;
            m_ = fmaxf(m_, fmaxf(ve, vo));
        }
        uint* ol = op2 + cb;
#pragma unroll
        for (int k = 0; k < 8; k++)
            *(uint4*)(ol + k * 128) = make_uint4(dl[4*k], dl[4*k+1], dl[4*k+2], dl[4*k+3]);
        amx[(size_t)b * 2 * PLANE + pixg] = s_ * (1.f / 64.f);
        amx[(size_t)b * 2 * PLANE + PLANE + pixg] = m_;
    }
}

// ---------------- global average pool from fragment-slot hi: g[b,c] ----------
__global__ __launch_bounds__(256) void gpool_kernel(
    const uint* __restrict__ rph, float* __restrict__ g /*[B*C], pre-zeroed*/)
{
    const int tid = threadIdx.x;
    const int b = blockIdx.y;
    const uint* base = rph + (size_t)b * PLANE * 32;
    float s[8];
#pragma unroll
    for (int i = 0; i < 8; i++) s[i] = 0.f;
    for (int it = 0; it < 32; it++) {
        const size_t a = ((size_t)blockIdx.x * 32 + it) * 1024 + tid * 4;
        const uint4 q = *(const uint4*)(base + a);
        s[0] += bf16val(q.x & 0xffffu); s[1] += bf16val(q.x >> 16);
        s[2] += bf16val(q.y & 0xffffu); s[3] += bf16val(q.y >> 16);
        s[4] += bf16val(q.z & 0xffffu); s[5] += bf16val(q.z >> 16);
        s[6] += bf16val(q.w & 0xffffu); s[7] += bf16val(q.w >> 16);
    }
#pragma unroll
    for (int off = 16; off >= 1; off >>= 1)
#pragma unroll
        for (int i = 0; i < 8; i++) s[i] += __shfl_xor(s[i], off, 64);
    if ((tid & 31) == 0) {
        const int grp = tid >> 5;   // 0..7
#pragma unroll
        for (int i = 0; i < 8; i++)
            atomicAdd(&g[b * 64 + grp * 8 + i], s[i] * (1.f / PLANE));
    }
}

// ---------------- spatial-attention 3x3 conv (2ch -> 1ch) ----------------
__global__ __launch_bounds__(256) void saconv_kernel(
    const float* __restrict__ amx, const float* __restrict__ sa_w,
    const float* __restrict__ sa_b, float* __restrict__ smap)
{
    int pix = blockIdx.x * 256 + threadIdx.x;
    int b = blockIdx.y;
    int x = pix & 255, y = pix >> 8;
    float acc = sa_b[0];
    const float* ab = amx + (size_t)b * 2 * PLANE;
#pragma unroll
    for (int c = 0; c < 2; c++)
#pragma unroll
        for (int dy = -1; dy <= 1; dy++)
#pragma unroll
            for (int dx = -1; dx <= 1; dx++) {
                int gx = x + dx; gx = gx < 0 ? 1 : (gx >= WW ? 2 * WW - 2 - gx : gx);
                int gy = y + dy; gy = gy < 0 ? 1 : (gy >= HH ? 2 * HH - 2 - gy : gy);
                acc += sa_w[c * 9 + (dy + 1) * 3 + (dx + 1)] * ab[(size_t)c * PLANE + gy * WW + gx];
            }
    smap[(size_t)b * PLANE + pix] = acc;
}

// ---------------- tiny MLPs -> hyper kernels, fragment-slot hi/lo --------
__global__ __launch_bounds__(256) void mlp_kernel(
    const float* __restrict__ h, const float* __restrict__ g,
    const float* __restrict__ ca_w1, const float* __restrict__ ca_b1,
    const float* __restrict__ ca_a,
    const float* __restrict__ ca_w2, const float* __restrict__ ca_b2,
    const float* __restrict__ fc_w, const float* __restrict__ fc_b,
    const float* __restrict__ k1_w, const float* __restrict__ k1_b,
    const float* __restrict__ k2_w, const float* __restrict__ k2_b,
    const float* __restrict__ k3_w, const float* __restrict__ k3_b,
    uint* __restrict__ kAhi, uint* __restrict__ kAlo,
    uint* __restrict__ kBhi, uint* __restrict__ kBlo)
{
    int b = blockIdx.x, tid = threadIdx.x;
    __shared__ float gb[64], t16[16], u32[32], v32[32], cg1[32], casig[64];

    if (tid < 64) gb[tid] = g[b * 64 + tid];
    __syncthreads();

    if (tid < 16) {
        float s = fc_b[tid];
        for (int j = 0; j < 16; j++) s += fc_w[tid * 16 + j] * h[b * 16 + j];
        t16[tid] = s >= 0.f ? s : 0.01f * s;
    }
    if (tid < 32) {
        float c1 = ca_b1[tid];
        for (int j = 0; j < 64; j++) c1 += ca_w1[tid * 64 + j] * gb[j];
        cg1[tid] = fmaxf(c1, 0.f) + ca_a[tid] * fminf(c1, 0.f);
    }
    __syncthreads();
    if (tid < 32) {
        float s = k1_b[tid];
        for (int j = 0; j < 16; j++) s += k1_w[tid * 16 + j] * t16[j];
        u32[tid] = s >= 0.f ? s : 0.01f * s;
    }
    if (tid < 64) {
        float c2 = ca_b2[tid];
        for (int j = 0; j < 32; j++) c2 += ca_w2[tid * 32 + j] * cg1[j];
        casig[tid] = 1.f / (1.f + expf(-c2));
    }
    __syncthreads();
    if (tid < 32) {
        float s = k2_b[tid];
        for (int j = 0; j < 32; j++) s += k2_w[tid * 32 + j] * u32[j];
        v32[tid] = s >= 0.f ? s : 0.01f * s;
    }
    __syncthreads();
    // k3: 8192 outputs, adjacent pairs -> one packed dword, fragment-slot store
    for (int o2 = tid; o2 < 4096; o2 += 256) {
        const int o = o2 * 2;
        const int oc = o >> 7;        // /128
        const int i = o & 127;        // even
        float s0 = k3_b[o], s1 = k3_b[o + 1];
        for (int j = 0; j < 32; j++) {
            s0 += k3_w[(size_t)o * 32 + j] * v32[j];
            s1 += k3_w[(size_t)(o + 1) * 32 + j] * v32[j];
        }
        uint *hi, *lo;
        if (i < 64) { hi = kAhi; lo = kAlo; }
        else { s0 *= casig[i - 64]; s1 *= casig[i - 63]; hi = kBhi; lo = kBlo; }
        const int cp = (i & 63) >> 1;
        uint h0 = bf16rne(s0); float l0 = s0 - bf16val(h0);
        uint h1 = bf16rne(s1); float l1 = s1 - bf16val(h1);
        const size_t a = (size_t)b * 2048 + (cp >> 2) * 256 + oc * 4 + (cp & 3);
        hi[a] = h0 | (h1 << 16);
        lo[a] = bf16rne(l0) | (bf16rne(l1) << 16);
    }
}

// ---------------- final via MFMA: out = x + hcb + sig(s)*(A.r) + (B.r) --------
__global__ __launch_bounds__(256, 2) void final_mfma(
    const float* __restrict__ x, const uint* __restrict__ rph,
    const uint* __restrict__ rpl, const float* __restrict__ smap,
    const uint* __restrict__ kAhi, const uint* __restrict__ kAlo,
    const uint* __restrict__ kBhi, const uint* __restrict__ kBlo,
    const float* __restrict__ hcb, float* __restrict__ out)
{
    const int tid = threadIdx.x;
    const int lane = tid & 63;
    const int wid = tid >> 6;
    const int mt = wid & 1;          // oc Mtile
    const int gq = wid >> 1;         // pixel group
    const int b = blockIdx.y;
    const int colx = lane & 31;
    const int half = lane >> 5;
    const int pix = blockIdx.x * 64 + gq * 32 + colx;
    const int pgroup = blockIdx.x * 2 + gq;   // pix >> 5

    // fragment-slot kernel loads (lane-dense)
    const size_t kb = (size_t)b * 2048 + half * 256 + (size_t)(mt * 32 + colx) * 4;
    uint4 KAh[4], KAl[4], KBh[4], KBl[4];
#pragma unroll
    for (int c = 0; c < 4; c++) {
        KAh[c] = *(const uint4*)(kAhi + kb + c * 512);
        KAl[c] = *(const uint4*)(kAlo + kb + c * 512);
        KBh[c] = *(const uint4*)(kBhi + kb + c * 512);
        KBl[c] = *(const uint4*)(kBlo + kb + c * 512);
    }
    // fragment-slot activation loads
    const size_t rb = (size_t)b * PLANE * 32 + (size_t)pgroup * 1024
                    + half * 128 + colx * 4;
    uint4 Bh[4], Bl[4];
#pragma unroll
    for (int c = 0; c < 4; c++) {
        Bh[c] = *(const uint4*)(rph + rb + c * 256);
        Bl[c] = *(const uint4*)(rpl + rb + c * 256);
    }
    f32x16 accA = (f32x16)0.f, accB = (f32x16)0.f;
#pragma unroll
    for (int c = 0; c < 4; c++) {
        const s16x8 bh = fragpack(Bh[c]), bl = fragpack(Bl[c]);
        const s16x8 ah = fragpack(KAh[c]), al = fragpack(KAl[c]);
        const s16x8 ch = fragpack(KBh[c]), cl = fragpack(KBl[c]);
        accA = __builtin_amdgcn_mfma_f32_32x32x16_bf16(ah, bh, accA, 0, 0, 0);
        accA = __builtin_amdgcn_mfma_f32_32x32x16_bf16(ah, bl, accA, 0, 0, 0);
        accA = __builtin_amdgcn_mfma_f32_32x32x16_bf16(al, bh, accA, 0, 0, 0);
        accB = __builtin_amdgcn_mfma_f32_32x32x16_bf16(ch, bh, accB, 0, 0, 0);
        accB = __builtin_amdgcn_mfma_f32_32x32x16_bf16(ch, bl, accB, 0, 0, 0);
        accB = __builtin_amdgcn_mfma_f32_32x32x16_bf16(cl, bh, accB, 0, 0, 0);
    }
    const float sv = smap[(size_t)b * PLANE + pix];
    const float sig = 1.f / (1.f + expf(-sv));
#pragma unroll
    for (int j = 0; j < 16; j++) {
        const int row = (j & 3) + 8 * (j >> 2) + 4 * half;
        const int oc = mt * 32 + row;
        const size_t idx = ((size_t)b * 64 + oc) * PLANE + pix;
        out[idx] = x[idx] + hcb[oc] + sig * accA[j] + accB[j];
    }
}

extern "C" void kernel_launch(void* const* d_in, const int* in_sizes, int n_in,
                              void* d_out, int out_size, void* d_ws, size_t ws_size,
                              hipStream_t stream) {
    const float* x   = (const float*)d_in[0];
    const float* h   = (const float*)d_in[1];
    const float* c1w = (const float*)d_in[2];
    const float* c1b = (const float*)d_in[3];
    const float* pa  = (const float*)d_in[4];
    const float* c2w = (const float*)d_in[5];
    const float* c2b = (const float*)d_in[6];
    const float* saw = (const float*)d_in[7];
    const float* sab = (const float*)d_in[8];
    const float* cw1 = (const float*)d_in[9];
    const float* cb1 = (const float*)d_in[10];
    const float* caa = (const float*)d_in[11];
    const float* cw2 = (const float*)d_in[12];
    const float* cb2 = (const float*)d_in[13];
    const float* fcw = (const float*)d_in[14];
    const float* fcb = (const float*)d_in[15];
    const float* k1w = (const float*)d_in[16];
    const float* k1b = (const float*)d_in[17];
    const float* k2w = (const float*)d_in[18];
    const float* k2b = (const float*)d_in[19];
    const float* k3w = (const float*)d_in[20];
    const float* k3b = (const float*)d_in[21];
    const float* hcb = (const float*)d_in[22];
    float* out = (float*)d_out;

    char* ws = (char*)d_ws;
    const size_t SZ_Q = (size_t)8 * PLANE * 32 * 4;   // 67,108,864 (packed)
    uint*  xp  = (uint*)ws;                           // x repacked
    uint*  r1p = (uint*)(ws + SZ_Q);                  // conv1 out (hi)
    uint*  rph = (uint*)(ws + 2 * SZ_Q);              // conv2 out hi
    uint*  rpl = (uint*)(ws + 3 * SZ_Q);              // conv2 out lo
    float* amx   = (float*)ws;                        // aliases xp (dead after conv1)
    float* smap  = (float*)(ws + (size_t)8 * 2 * PLANE * 4);
    float* g     = (float*)(ws + (size_t)8 * 3 * PLANE * 4);
    uint*  kAhi  = (uint*)(ws + (size_t)8 * 3 * PLANE * 4 + 4096);
    uint*  kAlo  = kAhi + 8 * 2048;
    uint*  kBhi  = kAlo + 8 * 2048;
    uint*  kBlo  = kBhi + 8 * 2048;

    // weight packs live in d_out (dead until final_mfma overwrites it)
    uint* wsp = (uint*)d_out;
    uint* wh1 = wsp;          uint* wl1 = wsp + 18432;
    uint* wh2 = wsp + 36864;  uint* wl2 = wsp + 55296;

    wprep_kernel<<<dim3(72, 2), 256, 0, stream>>>(c1w, c2w, wh1, wl1, wh2, wl2);
    xrepack_kernel<<<dim3(PLANE / 256, 8), 256, 0, stream>>>(x, xp);

    dim3 cgrid(WW / 32, HH / 8, 8);  // (8, 32, 8)
    conv_mfma<1><<<cgrid, 256, 0, stream>>>(xp, wh1, wl1, c1b, pa, r1p, nullptr, nullptr);
    conv_mfma<2><<<cgrid, 256, 0, stream>>>(r1p, wh2, wl2, c2b, nullptr, rph, rpl, amx);

    hipMemsetAsync(g, 0, 512 * sizeof(float), stream);
    gpool_kernel<<<dim3(64, 8), 256, 0, stream>>>(rph, g);
    saconv_kernel<<<dim3(PLANE / 256, 8), 256, 0, stream>>>(amx, saw, sab, smap);
    mlp_kernel<<<8, 256, 0, stream>>>(h, g, cw1, cb1, caa, cw2, cb2,
                                      fcw, fcb, k1w, k1b, k2w, k2b, k3w, k3b,
                                      kAhi, kAlo, kBhi, kBlo);
    final_mfma<<<dim3(PLANE / 64, 8), 256, 0, stream>>>(
        x, rph, rpl, smap, kAhi, kAlo, kBhi, kBlo, hcb, out);
}

// Round 12
// 629.973 us; speedup vs baseline: 1.6886x; 1.0514x over previous
//
#include <hip/hip_runtime.h>
#include <math.h>

#define HH 256
#define WW 256
#define CC 64
#define PLANE (HH*WW)

typedef short s16x8 __attribute__((ext_vector_type(8)));
typedef float f32x16 __attribute__((ext_vector_type(16)));
typedef unsigned int uint;
typedef uint u32x4v __attribute__((ext_vector_type(4)));

__device__ inline uint bf16rne(float f) {
    uint u = __float_as_uint(f);
    return (u + 0x7FFFu + ((u >> 16) & 1u)) >> 16;
}
__device__ inline float bf16val(uint h) { return __uint_as_float(h << 16); }
__device__ inline s16x8 fragpack(uint4 q) {
    u32x4v t = {q.x, q.y, q.z, q.w};
    return __builtin_bit_cast(s16x8, t);
}
__device__ inline void gload_lds16(const uint* g, uint* l) {
    __builtin_amdgcn_global_load_lds(
        (const __attribute__((address_space(1))) uint*)g,
        (__attribute__((address_space(3))) uint*)l, 16, 0, 0);
}
// activation fragment-slot layout: dword (pix, dwi) at
//   (pix>>5)*1024 + (dwi>>2)*128 + (pix&31)*4 + (dwi&3)
__device__ inline size_t chunk_addr(int pix, int c2) {
    return (size_t)(pix >> 5) * 1024 + c2 * 128 + (pix & 31) * 4;
}
// weight fragment-slot layout: dword (tap, oc, dwi) at
//   tap*2048 + (dwi>>2)*256 + oc*4 + (dwi&3)   -> lane-dense dwordx4 loads

// ---------------- weight prep: split fp32 W into bf16 hi/lo ----------------
__global__ __launch_bounds__(256) void wprep_kernel(
    const float* __restrict__ w1, const float* __restrict__ w2,
    uint* __restrict__ wh1, uint* __restrict__ wl1,
    uint* __restrict__ wh2, uint* __restrict__ wl2)
{
    const int idx = blockIdx.x * 256 + threadIdx.x;      // 0..18431
    const float* w = blockIdx.y ? w2 : w1;
    uint* wh = blockIdx.y ? wh2 : wh1;
    uint* wl = blockIdx.y ? wl2 : wl1;
    const int tap = idx >> 11;           // 9
    const int oc  = (idx >> 5) & 63;     // 64
    const int icp = idx & 31;            // 32 ic-pairs (dword index)
    float w0 = w[(oc * 64 + 2 * icp) * 9 + tap];
    float w1v = w[(oc * 64 + 2 * icp + 1) * 9 + tap];
    uint h0 = bf16rne(w0); float l0 = w0 - bf16val(h0);
    uint h1 = bf16rne(w1v); float l1 = w1v - bf16val(h1);
    const int a = tap * 2048 + (icp >> 2) * 256 + oc * 4 + (icp & 3);
    wh[a] = h0 | (h1 << 16);
    wl[a] = bf16rne(l0) | (bf16rne(l1) << 16);
}

// ---------------- x repack: fp32 NCHW -> bf16-pair fragment-slot ----------------
__global__ __launch_bounds__(256) void xrepack_kernel(
    const float* __restrict__ x, uint* __restrict__ xp)
{
    const int tid = threadIdx.x;
    const int px = blockIdx.x * 256 + tid;
    const int b = blockIdx.y;
    const float* xb = x + (size_t)b * CC * PLANE + px;
    uint d[32];
#pragma unroll
    for (int icp = 0; icp < 32; icp++) {
        float v0 = xb[(size_t)(2 * icp) * PLANE];
        float v1 = xb[(size_t)(2 * icp + 1) * PLANE];
        d[icp] = bf16rne(v0) | (bf16rne(v1) << 16);
    }
    uint* o = xp + (size_t)b * PLANE * 32 + chunk_addr(px, 0);
#pragma unroll
    for (int k = 0; k < 8; k++)
        *(uint4*)(o + k * 128) = make_uint4(d[4*k], d[4*k+1], d[4*k+2], d[4*k+3]);
}

// ---------------- conv 3x3 reflect via MFMA, 4-row tile, LDS halo ----------
// wave w: Mtile mt = w&1 (32 oc), row-pair rq = w>>1 (rows rq*2, rq*2+1).
// Per tap: 8 weight dwordx4 + 8 ds_read_b128 + 16 MFMA.
// VGPR ~110 (capped 128 by launch_bounds) -> 4 waves/SIMD residency.
// MODE 1: PReLU + fragment-slot (hi only) out.
// MODE 2: fragment-slot hi/lo out (sequential transposes) + fused chan mean/max.
#define HPIX 204                 // 6*34 halo pixels
#define HCHUNK (HPIX*8)          // 16B chunks = 1632
template<int MODE>
__global__ __launch_bounds__(256, 4) void conv_mfma(
    const uint* __restrict__ xin,   // fragment-slot packed
    const uint* __restrict__ wh, const uint* __restrict__ wl,
    const float* __restrict__ bias, const float* __restrict__ prelu,
    uint* __restrict__ op, uint* __restrict__ op2, float* __restrict__ amx)
{
    __shared__ uint lds[HPIX * 32];          // 26,112 B
    const int tid  = threadIdx.x;
    const int lane = tid & 63;
    const int wid  = tid >> 6;
    const int x0 = blockIdx.x * 32;
    const int y0 = blockIdx.y * 4;
    const int b  = blockIdx.z;
    const int colx = lane & 31;
    const int half = lane >> 5;
    const int mt = wid & 1;          // Mtile (oc group of 32)
    const int rq = wid >> 1;         // row pair: rows rq*2, rq*2+1

    // ---- stage halo: chunk k -> LDS byte k*16 (linear), source pre-swizzled
    {
        const uint* gb = xin + (size_t)b * PLANE * 32;
#pragma unroll
        for (int iter = 0; iter < 7; iter++) {
            const int k = iter * 256 + tid;
            if (iter < 6 || k < HCHUNK) {
                const int pix = k >> 3;
                const int slot = k & 7;
                const int hrow = pix / 34;
                const int hcol = pix - hrow * 34;
                int gy = y0 - 1 + hrow; gy = gy < 0 ? 1 : (gy > 255 ? 254 : gy);
                int gx = x0 - 1 + hcol; gx = gx < 0 ? 1 : (gx > 255 ? 254 : gx);
                const int c2 = slot ^ (pix & 7);    // involution
                gload_lds16(gb + chunk_addr(gy * 256 + gx, c2),
                            &lds[(iter * 256 + wid * 64) * 4]);
            }
        }
    }
    __syncthreads();

    f32x16 acc0 = (f32x16)0.f, acc1 = (f32x16)0.f;   // rows rq*2, rq*2+1

    // lane-dense weight base for this wave's Mtile
    const uint* wbh = wh + half * 256 + (mt * 32 + colx) * 4;
    const uint* wbl = wl + half * 256 + (mt * 32 + colx) * 4;

#pragma unroll
    for (int tap = 0; tap < 9; tap++) {
        const int dy = tap / 3, dx = tap % 3;
        const int pixb = (rq * 2 + dy) * 34 + dx + colx;   // row rq*2

        uint4 Hc[4], Lc[4], Ba[4], Bb[4];
#pragma unroll
        for (int c = 0; c < 4; c++) {
            Hc[c] = *(const uint4*)(wbh + tap * 2048 + c * 512);
            Lc[c] = *(const uint4*)(wbl + tap * 2048 + c * 512);
        }
#pragma unroll
        for (int c = 0; c < 4; c++) {
            const int c2 = c * 2 + half;
            const int p0 = pixb, p1 = pixb + 34;
            Ba[c] = *(const uint4*)&lds[(p0 * 8 + (c2 ^ (p0 & 7))) * 4];
            Bb[c] = *(const uint4*)&lds[(p1 * 8 + (c2 ^ (p1 & 7))) * 4];
        }
#pragma unroll
        for (int c = 0; c < 4; c++) {
            const s16x8 b0 = fragpack(Ba[c]), b1 = fragpack(Bb[c]);
            const s16x8 ah = fragpack(Hc[c]), al = fragpack(Lc[c]);
            acc0 = __builtin_amdgcn_mfma_f32_32x32x16_bf16(ah, b0, acc0, 0, 0, 0);
            acc1 = __builtin_amdgcn_mfma_f32_32x32x16_bf16(ah, b1, acc1, 0, 0, 0);
            acc0 = __builtin_amdgcn_mfma_f32_32x32x16_bf16(al, b0, acc0, 0, 0, 0);
            acc1 = __builtin_amdgcn_mfma_f32_32x32x16_bf16(al, b1, acc1, 0, 0, 0);
        }
    }

    // ---- epilogue. C/D layout (32x32): col=lane&31 (pixel), row=(j&3)+8*(j>>2)+4*half (oc)
    // wave covers ocs mt*32..+31, block rows rq*2, rq*2+1.
    // readback: wave w <-> block row w; lane: pcol=lane&31, seg=lane>>5 (16 dwords each)
    const int pcol = colx, seg = half;
    const int pixg = (y0 + wid) * 256 + x0 + pcol;
    if constexpr (MODE == 1) {
        __syncthreads();                    // halo reads done; reuse lds for transpose
#define ST1(ACC, RR) { \
        _Pragma("unroll") \
        for (int j = 0; j < 16; j += 2) { \
            const int row = (j & 3) + 8 * (j >> 2) + 4 * half; \
            const int oc = mt * 32 + row; \
            float v0 = ACC[j]     + bias[oc]; \
            float v1 = ACC[j + 1] + bias[oc + 1]; \
            const float a0 = prelu[oc], a1 = prelu[oc + 1]; \
            v0 = fmaxf(v0, 0.f) + a0 * fminf(v0, 0.f); \
            v1 = fmaxf(v1, 0.f) + a1 * fminf(v1, 0.f); \
            const int icp = oc >> 1; \
            lds[((RR) * 32 + icp) * 32 + (colx ^ icp)] = \
                bf16rne(v0) | (bf16rne(v1) << 16); \
        } }
        ST1(acc0, rq * 2) ST1(acc1, rq * 2 + 1)
#undef ST1
        __syncthreads();
        uint d[16];
#pragma unroll
        for (int i = 0; i < 16; i++) {
            const int icp = seg * 16 + i;
            d[i] = lds[(wid * 32 + icp) * 32 + (pcol ^ icp)];
        }
        uint* o = op + (size_t)b * PLANE * 32 + chunk_addr(pixg, seg * 4);
#pragma unroll
        for (int k = 0; k < 4; k++)
            *(uint4*)(o + k * 128) = make_uint4(d[4*k], d[4*k+1], d[4*k+2], d[4*k+3]);
    } else {
        // hi pass, then lo pass, reusing the halo LDS (4096 dwords needed)
        const size_t cb = (size_t)b * PLANE * 32 + chunk_addr(pixg, seg * 4);
        uint d[16], dl[16];
        __syncthreads();
#define STH(ACC, RR) { \
        _Pragma("unroll") \
        for (int j = 0; j < 16; j += 2) { \
            const int row = (j & 3) + 8 * (j >> 2) + 4 * half; \
            const int oc = mt * 32 + row; \
            float v0 = ACC[j]     + bias[oc]; \
            float v1 = ACC[j + 1] + bias[oc + 1]; \
            const int icp = oc >> 1; \
            lds[((RR) * 32 + icp) * 32 + (colx ^ icp)] = \
                bf16rne(v0) | (bf16rne(v1) << 16); \
        } }
        STH(acc0, rq * 2) STH(acc1, rq * 2 + 1)
#undef STH
        __syncthreads();
#pragma unroll
        for (int i = 0; i < 16; i++) {
            const int icp = seg * 16 + i;
            d[i] = lds[(wid * 32 + icp) * 32 + (pcol ^ icp)];
        }
        uint* oh = op + cb;
#pragma unroll
        for (int k = 0; k < 4; k++)
            *(uint4*)(oh + k * 128) = make_uint4(d[4*k], d[4*k+1], d[4*k+2], d[4*k+3]);
        __syncthreads();
#define STL(ACC, RR) { \
        _Pragma("unroll") \
        for (int j = 0; j < 16; j += 2) { \
            const int row = (j & 3) + 8 * (j >> 2) + 4 * half; \
            const int oc = mt * 32 + row; \
            float v0 = ACC[j]     + bias[oc]; \
            float v1 = ACC[j + 1] + bias[oc + 1]; \
            float l0 = v0 - bf16val(bf16rne(v0)); \
            float l1 = v1 - bf16val(bf16rne(v1)); \
            const int icp = oc >> 1; \
            lds[((RR) * 32 + icp) * 32 + (colx ^ icp)] = \
                bf16rne(l0) | (bf16rne(l1) << 16); \
        } }
        STL(acc0, rq * 2) STL(acc1, rq * 2 + 1)
#undef STL
        __syncthreads();
        float s_ = 0.f, m_ = -INFINITY;
#pragma unroll
        for (int i = 0; i < 16; i++) {
            const int icp = seg * 16 + i;
            dl[i] = lds[(wid * 32 + icp) * 32 + (pcol ^ icp)];
            float ve = bf16val(d[i] & 0xffffu) + bf16val(dl[i] & 0xffffu);
            float vo = bf16val(d[i] >> 16)     + bf16val(dl[i] >> 16);
            s_ += ve + vo;
            m_ = fmaxf(m_, fmaxf(ve, vo));
        }
        uint* ol = op2 + cb;
#pragma unroll
        for (int k = 0; k < 4; k++)
            *(uint4*)(ol + k * 128) = make_uint4(dl[4*k], dl[4*k+1], dl[4*k+2], dl[4*k+3]);
        // combine the two 16-dword halves (seg 0/1) via lane^32
        s_ += __shfl_xor(s_, 32, 64);
        m_ = fmaxf(m_, __shfl_xor(m_, 32, 64));
        if (seg == 0) {
            amx[(size_t)b * 2 * PLANE + pixg] = s_ * (1.f / 64.f);
            amx[(size_t)b * 2 * PLANE + PLANE + pixg] = m_;
        }
    }
}

// ---------------- global average pool from fragment-slot hi: g[b,c] ----------
__global__ __launch_bounds__(256) void gpool_kernel(
    const uint* __restrict__ rph, float* __restrict__ g /*[B*C], pre-zeroed*/)
{
    const int tid = threadIdx.x;
    const int b = blockIdx.y;
    const uint* base = rph + (size_t)b * PLANE * 32;
    float s[8];
#pragma unroll
    for (int i = 0; i < 8; i++) s[i] = 0.f;
    for (int it = 0; it < 32; it++) {
        const size_t a = ((size_t)blockIdx.x * 32 + it) * 1024 + tid * 4;
        const uint4 q = *(const uint4*)(base + a);
        s[0] += bf16val(q.x & 0xffffu); s[1] += bf16val(q.x >> 16);
        s[2] += bf16val(q.y & 0xffffu); s[3] += bf16val(q.y >> 16);
        s[4] += bf16val(q.z & 0xffffu); s[5] += bf16val(q.z >> 16);
        s[6] += bf16val(q.w & 0xffffu); s[7] += bf16val(q.w >> 16);
    }
#pragma unroll
    for (int off = 16; off >= 1; off >>= 1)
#pragma unroll
        for (int i = 0; i < 8; i++) s[i] += __shfl_xor(s[i], off, 64);
    if ((tid & 31) == 0) {
        const int grp = tid >> 5;   // 0..7
#pragma unroll
        for (int i = 0; i < 8; i++)
            atomicAdd(&g[b * 64 + grp * 8 + i], s[i] * (1.f / PLANE));
    }
}

// ---------------- spatial-attention 3x3 conv (2ch -> 1ch) ----------------
__global__ __launch_bounds__(256) void saconv_kernel(
    const float* __restrict__ amx, const float* __restrict__ sa_w,
    const float* __restrict__ sa_b, float* __restrict__ smap)
{
    int pix = blockIdx.x * 256 + threadIdx.x;
    int b = blockIdx.y;
    int x = pix & 255, y = pix >> 8;
    float acc = sa_b[0];
    const float* ab = amx + (size_t)b * 2 * PLANE;
#pragma unroll
    for (int c = 0; c < 2; c++)
#pragma unroll
        for (int dy = -1; dy <= 1; dy++)
#pragma unroll
            for (int dx = -1; dx <= 1; dx++) {
                int gx = x + dx; gx = gx < 0 ? 1 : (gx >= WW ? 2 * WW - 2 - gx : gx);
                int gy = y + dy; gy = gy < 0 ? 1 : (gy >= HH ? 2 * HH - 2 - gy : gy);
                acc += sa_w[c * 9 + (dy + 1) * 3 + (dx + 1)] * ab[(size_t)c * PLANE + gy * WW + gx];
            }
    smap[(size_t)b * PLANE + pix] = acc;
}

// ---------------- tiny MLPs -> hyper kernels, fragment-slot hi/lo --------
__global__ __launch_bounds__(256) void mlp_kernel(
    const float* __restrict__ h, const float* __restrict__ g,
    const float* __restrict__ ca_w1, const float* __restrict__ ca_b1,
    const float* __restrict__ ca_a,
    const float* __restrict__ ca_w2, const float* __restrict__ ca_b2,
    const float* __restrict__ fc_w, const float* __restrict__ fc_b,
    const float* __restrict__ k1_w, const float* __restrict__ k1_b,
    const float* __restrict__ k2_w, const float* __restrict__ k2_b,
    const float* __restrict__ k3_w, const float* __restrict__ k3_b,
    uint* __restrict__ kAhi, uint* __restrict__ kAlo,
    uint* __restrict__ kBhi, uint* __restrict__ kBlo)
{
    int b = blockIdx.x, tid = threadIdx.x;
    __shared__ float gb[64], t16[16], u32[32], v32[32], cg1[32], casig[64];

    if (tid < 64) gb[tid] = g[b * 64 + tid];
    __syncthreads();

    if (tid < 16) {
        float s = fc_b[tid];
        for (int j = 0; j < 16; j++) s += fc_w[tid * 16 + j] * h[b * 16 + j];
        t16[tid] = s >= 0.f ? s : 0.01f * s;
    }
    if (tid < 32) {
        float c1 = ca_b1[tid];
        for (int j = 0; j < 64; j++) c1 += ca_w1[tid * 64 + j] * gb[j];
        cg1[tid] = fmaxf(c1, 0.f) + ca_a[tid] * fminf(c1, 0.f);
    }
    __syncthreads();
    if (tid < 32) {
        float s = k1_b[tid];
        for (int j = 0; j < 16; j++) s += k1_w[tid * 16 + j] * t16[j];
        u32[tid] = s >= 0.f ? s : 0.01f * s;
    }
    if (tid < 64) {
        float c2 = ca_b2[tid];
        for (int j = 0; j < 32; j++) c2 += ca_w2[tid * 32 + j] * cg1[j];
        casig[tid] = 1.f / (1.f + expf(-c2));
    }
    __syncthreads();
    if (tid < 32) {
        float s = k2_b[tid];
        for (int j = 0; j < 32; j++) s += k2_w[tid * 32 + j] * u32[j];
        v32[tid] = s >= 0.f ? s : 0.01f * s;
    }
    __syncthreads();
    // k3: 8192 outputs, adjacent pairs -> one packed dword, fragment-slot store
    for (int o2 = tid; o2 < 4096; o2 += 256) {
        const int o = o2 * 2;
        const int oc = o >> 7;        // /128
        const int i = o & 127;        // even
        float s0 = k3_b[o], s1 = k3_b[o + 1];
        for (int j = 0; j < 32; j++) {
            s0 += k3_w[(size_t)o * 32 + j] * v32[j];
            s1 += k3_w[(size_t)(o + 1) * 32 + j] * v32[j];
        }
        uint *hi, *lo;
        if (i < 64) { hi = kAhi; lo = kAlo; }
        else { s0 *= casig[i - 64]; s1 *= casig[i - 63]; hi = kBhi; lo = kBlo; }
        const int cp = (i & 63) >> 1;
        uint h0 = bf16rne(s0); float l0 = s0 - bf16val(h0);
        uint h1 = bf16rne(s1); float l1 = s1 - bf16val(h1);
        const size_t a = (size_t)b * 2048 + (cp >> 2) * 256 + oc * 4 + (cp & 3);
        hi[a] = h0 | (h1 << 16);
        lo[a] = bf16rne(l0) | (bf16rne(l1) << 16);
    }
}

// ---------------- final via MFMA: out = x + hcb + sig(s)*(A.r) + (B.r) --------
__global__ __launch_bounds__(256, 2) void final_mfma(
    const float* __restrict__ x, const uint* __restrict__ rph,
    const uint* __restrict__ rpl, const float* __restrict__ smap,
    const uint* __restrict__ kAhi, const uint* __restrict__ kAlo,
    const uint* __restrict__ kBhi, const uint* __restrict__ kBlo,
    const float* __restrict__ hcb, float* __restrict__ out)
{
    const int tid = threadIdx.x;
    const int lane = tid & 63;
    const int wid = tid >> 6;
    const int mt = wid & 1;          // oc Mtile
    const int gq = wid >> 1;         // pixel group
    const int b = blockIdx.y;
    const int colx = lane & 31;
    const int half = lane >> 5;
    const int pix = blockIdx.x * 64 + gq * 32 + colx;
    const int pgroup = blockIdx.x * 2 + gq;   // pix >> 5

    // fragment-slot kernel loads (lane-dense)
    const size_t kb = (size_t)b * 2048 + half * 256 + (size_t)(mt * 32 + colx) * 4;
    uint4 KAh[4], KAl[4], KBh[4], KBl[4];
#pragma unroll
    for (int c = 0; c < 4; c++) {
        KAh[c] = *(const uint4*)(kAhi + kb + c * 512);
        KAl[c] = *(const uint4*)(kAlo + kb + c * 512);
        KBh[c] = *(const uint4*)(kBhi + kb + c * 512);
        KBl[c] = *(const uint4*)(kBlo + kb + c * 512);
    }
    // fragment-slot activation loads
    const size_t rb = (size_t)b * PLANE * 32 + (size_t)pgroup * 1024
                    + half * 128 + colx * 4;
    uint4 Bh[4], Bl[4];
#pragma unroll
    for (int c = 0; c < 4; c++) {
        Bh[c] = *(const uint4*)(rph + rb + c * 256);
        Bl[c] = *(const uint4*)(rpl + rb + c * 256);
    }
    f32x16 accA = (f32x16)0.f, accB = (f32x16)0.f;
#pragma unroll
    for (int c = 0; c < 4; c++) {
        const s16x8 bh = fragpack(Bh[c]), bl = fragpack(Bl[c]);
        const s16x8 ah = fragpack(KAh[c]), al = fragpack(KAl[c]);
        const s16x8 ch = fragpack(KBh[c]), cl = fragpack(KBl[c]);
        accA = __builtin_amdgcn_mfma_f32_32x32x16_bf16(ah, bh, accA, 0, 0, 0);
        accA = __builtin_amdgcn_mfma_f32_32x32x16_bf16(ah, bl, accA, 0, 0, 0);
        accA = __builtin_amdgcn_mfma_f32_32x32x16_bf16(al, bh, accA, 0, 0, 0);
        accB = __builtin_amdgcn_mfma_f32_32x32x16_bf16(ch, bh, accB, 0, 0, 0);
        accB = __builtin_amdgcn_mfma_f32_32x32x16_bf16(ch, bl, accB, 0, 0, 0);
        accB = __builtin_amdgcn_mfma_f32_32x32x16_bf16(cl, bh, accB, 0, 0, 0);
    }
    const float sv = smap[(size_t)b * PLANE + pix];
    const float sig = 1.f / (1.f + expf(-sv));
#pragma unroll
    for (int j = 0; j < 16; j++) {
        const int row = (j & 3) + 8 * (j >> 2) + 4 * half;
        const int oc = mt * 32 + row;
        const size_t idx = ((size_t)b * 64 + oc) * PLANE + pix;
        out[idx] = x[idx] + hcb[oc] + sig * accA[j] + accB[j];
    }
}

extern "C" void kernel_launch(void* const* d_in, const int* in_sizes, int n_in,
                              void* d_out, int out_size, void* d_ws, size_t ws_size,
                              hipStream_t stream) {
    const float* x   = (const float*)d_in[0];
    const float* h   = (const float*)d_in[1];
    const float* c1w = (const float*)d_in[2];
    const float* c1b = (const float*)d_in[3];
    const float* pa  = (const float*)d_in[4];
    const float* c2w = (const float*)d_in[5];
    const float* c2b = (const float*)d_in[6];
    const float* saw = (const float*)d_in[7];
    const float* sab = (const float*)d_in[8];
    const float* cw1 = (const float*)d_in[9];
    const float* cb1 = (const float*)d_in[10];
    const float* caa = (const float*)d_in[11];
    const float* cw2 = (const float*)d_in[12];
    const float* cb2 = (const float*)d_in[13];
    const float* fcw = (const float*)d_in[14];
    const float* fcb = (const float*)d_in[15];
    const float* k1w = (const float*)d_in[16];
    const float* k1b = (const float*)d_in[17];
    const float* k2w = (const float*)d_in[18];
    const float* k2b = (const float*)d_in[19];
    const float* k3w = (const float*)d_in[20];
    const float* k3b = (const float*)d_in[21];
    const float* hcb = (const float*)d_in[22];
    float* out = (float*)d_out;

    char* ws = (char*)d_ws;
    const size_t SZ_Q = (size_t)8 * PLANE * 32 * 4;   // 67,108,864 (packed)
    uint*  xp  = (uint*)ws;                           // x repacked
    uint*  r1p = (uint*)(ws + SZ_Q);                  // conv1 out (hi)
    uint*  rph = (uint*)(ws + 2 * SZ_Q);              // conv2 out hi
    uint*  rpl = (uint*)(ws + 3 * SZ_Q);              // conv2 out lo
    float* amx   = (float*)ws;                        // aliases xp (dead after conv1)
    float* smap  = (float*)(ws + (size_t)8 * 2 * PLANE * 4);
    float* g     = (float*)(ws + (size_t)8 * 3 * PLANE * 4);
    uint*  kAhi  = (uint*)(ws + (size_t)8 * 3 * PLANE * 4 + 4096);
    uint*  kAlo  = kAhi + 8 * 2048;
    uint*  kBhi  = kAlo + 8 * 2048;
    uint*  kBlo  = kBhi + 8 * 2048;

    // weight packs live in d_out (dead until final_mfma overwrites it)
    uint* wsp = (uint*)d_out;
    uint* wh1 = wsp;          uint* wl1 = wsp + 18432;
    uint* wh2 = wsp + 36864;  uint* wl2 = wsp + 55296;

    wprep_kernel<<<dim3(72, 2), 256, 0, stream>>>(c1w, c2w, wh1, wl1, wh2, wl2);
    xrepack_kernel<<<dim3(PLANE / 256, 8), 256, 0, stream>>>(x, xp);

    dim3 cgrid(WW / 32, HH / 4, 8);  // (8, 64, 8)
    conv_mfma<1><<<cgrid, 256, 0, stream>>>(xp, wh1, wl1, c1b, pa, r1p, nullptr, nullptr);
    conv_mfma<2><<<cgrid, 256, 0, stream>>>(r1p, wh2, wl2, c2b, nullptr, rph, rpl, amx);

    hipMemsetAsync(g, 0, 512 * sizeof(float), stream);
    gpool_kernel<<<dim3(64, 8), 256, 0, stream>>>(rph, g);
    saconv_kernel<<<dim3(PLANE / 256, 8), 256, 0, stream>>>(amx, saw, sab, smap);
    mlp_kernel<<<8, 256, 0, stream>>>(h, g, cw1, cb1, caa, cw2, cb2,
                                      fcw, fcb, k1w, k1b, k2w, k2b, k3w, k3b,
                                      kAhi, kAlo, kBhi, kBlo);
    final_mfma<<<dim3(PLANE / 64, 8), 256, 0, stream>>>(
        x, rph, rpl, smap, kAhi, kAlo, kBhi, kBlo, hcb, out);
}

// Round 13
// 625.452 us; speedup vs baseline: 1.7008x; 1.0072x over previous
//
#include <hip/hip_runtime.h>
#include <math.h>

#define HH 256
#define WW 256
#define CC 64
#define PLANE (HH*WW)

typedef short s16x8 __attribute__((ext_vector_type(8)));
typedef float f32x16 __attribute__((ext_vector_type(16)));
typedef unsigned int uint;
typedef uint u32x4v __attribute__((ext_vector_type(4)));

__device__ inline uint bf16rne(float f) {
    uint u = __float_as_uint(f);
    return (u + 0x7FFFu + ((u >> 16) & 1u)) >> 16;
}
__device__ inline float bf16val(uint h) { return __uint_as_float(h << 16); }
__device__ inline s16x8 fragpack(uint4 q) {
    u32x4v t = {q.x, q.y, q.z, q.w};
    return __builtin_bit_cast(s16x8, t);
}
__device__ inline void gload_lds16(const uint* g, uint* l) {
    __builtin_amdgcn_global_load_lds(
        (const __attribute__((address_space(1))) uint*)g,
        (__attribute__((address_space(3))) uint*)l, 16, 0, 0);
}
// activation fragment-slot layout: dword (pix, dwi) at
//   (pix>>5)*1024 + (dwi>>2)*128 + (pix&31)*4 + (dwi&3)
__device__ inline size_t chunk_addr(int pix, int c2) {
    return (size_t)(pix >> 5) * 1024 + c2 * 128 + (pix & 31) * 4;
}
// weight fragment-slot layout: dword (tap, oc, dwi) at
//   tap*2048 + (dwi>>2)*256 + oc*4 + (dwi&3)   -> lane-dense dwordx4 loads

// ---------------- weight prep: split fp32 W into bf16 hi/lo ----------------
__global__ __launch_bounds__(256) void wprep_kernel(
    const float* __restrict__ w1, const float* __restrict__ w2,
    uint* __restrict__ wh1, uint* __restrict__ wl1,
    uint* __restrict__ wh2, uint* __restrict__ wl2)
{
    const int idx = blockIdx.x * 256 + threadIdx.x;      // 0..18431
    const float* w = blockIdx.y ? w2 : w1;
    uint* wh = blockIdx.y ? wh2 : wh1;
    uint* wl = blockIdx.y ? wl2 : wl1;
    const int tap = idx >> 11;           // 9
    const int oc  = (idx >> 5) & 63;     // 64
    const int icp = idx & 31;            // 32 ic-pairs (dword index)
    float w0 = w[(oc * 64 + 2 * icp) * 9 + tap];
    float w1v = w[(oc * 64 + 2 * icp + 1) * 9 + tap];
    uint h0 = bf16rne(w0); float l0 = w0 - bf16val(h0);
    uint h1 = bf16rne(w1v); float l1 = w1v - bf16val(h1);
    const int a = tap * 2048 + (icp >> 2) * 256 + oc * 4 + (icp & 3);
    wh[a] = h0 | (h1 << 16);
    wl[a] = bf16rne(l0) | (bf16rne(l1) << 16);
}

// ---------------- x repack: fp32 NCHW -> bf16-pair fragment-slot ----------------
__global__ __launch_bounds__(256) void xrepack_kernel(
    const float* __restrict__ x, uint* __restrict__ xp)
{
    const int tid = threadIdx.x;
    const int px = blockIdx.x * 256 + tid;
    const int b = blockIdx.y;
    const float* xb = x + (size_t)b * CC * PLANE + px;
    uint d[32];
#pragma unroll
    for (int icp = 0; icp < 32; icp++) {
        float v0 = xb[(size_t)(2 * icp) * PLANE];
        float v1 = xb[(size_t)(2 * icp + 1) * PLANE];
        d[icp] = bf16rne(v0) | (bf16rne(v1) << 16);
    }
    uint* o = xp + (size_t)b * PLANE * 32 + chunk_addr(px, 0);
#pragma unroll
    for (int k = 0; k < 8; k++)
        *(uint4*)(o + k * 128) = make_uint4(d[4*k], d[4*k+1], d[4*k+2], d[4*k+3]);
}

// ---------------- conv 3x3 reflect via MFMA, 4-row tile, LDS halo ----------
// wave w: Mtile mt = w&1 (32 oc), row-pair rq = w>>1 (rows rq*2, rq*2+1).
// Per tap: 8 ds_read_b128 + 16 MFMA; NEXT tap's 8 weight dwordx4 are issued
// BEFORE the MFMA block (full-unroll SSA double-buffer) to hide L2 latency.
// MODE 1: PReLU + fragment-slot (hi only) out.
// MODE 2: fragment-slot hi/lo out (sequential transposes) + fused chan mean/max.
#define HPIX 204                 // 6*34 halo pixels
#define HCHUNK (HPIX*8)          // 16B chunks = 1632
template<int MODE>
__global__ __launch_bounds__(256, 4) void conv_mfma(
    const uint* __restrict__ xin,   // fragment-slot packed
    const uint* __restrict__ wh, const uint* __restrict__ wl,
    const float* __restrict__ bias, const float* __restrict__ prelu,
    uint* __restrict__ op, uint* __restrict__ op2, float* __restrict__ amx)
{
    __shared__ uint lds[HPIX * 32];          // 26,112 B
    const int tid  = threadIdx.x;
    const int lane = tid & 63;
    const int wid  = tid >> 6;
    const int x0 = blockIdx.x * 32;
    const int y0 = blockIdx.y * 4;
    const int b  = blockIdx.z;
    const int colx = lane & 31;
    const int half = lane >> 5;
    const int mt = wid & 1;          // Mtile (oc group of 32)
    const int rq = wid >> 1;         // row pair: rows rq*2, rq*2+1

    // ---- stage halo: chunk k -> LDS byte k*16 (linear), source pre-swizzled
    {
        const uint* gb = xin + (size_t)b * PLANE * 32;
#pragma unroll
        for (int iter = 0; iter < 7; iter++) {
            const int k = iter * 256 + tid;
            if (iter < 6 || k < HCHUNK) {
                const int pix = k >> 3;
                const int slot = k & 7;
                const int hrow = pix / 34;
                const int hcol = pix - hrow * 34;
                int gy = y0 - 1 + hrow; gy = gy < 0 ? 1 : (gy > 255 ? 254 : gy);
                int gx = x0 - 1 + hcol; gx = gx < 0 ? 1 : (gx > 255 ? 254 : gx);
                const int c2 = slot ^ (pix & 7);    // involution
                gload_lds16(gb + chunk_addr(gy * 256 + gx, c2),
                            &lds[(iter * 256 + wid * 64) * 4]);
            }
        }
    }

    // lane-dense weight base for this wave's Mtile; preload tap 0
    const uint* wbh = wh + half * 256 + (mt * 32 + colx) * 4;
    const uint* wbl = wl + half * 256 + (mt * 32 + colx) * 4;
    uint4 Hc[4], Lc[4];
#pragma unroll
    for (int c = 0; c < 4; c++) {
        Hc[c] = *(const uint4*)(wbh + c * 512);
        Lc[c] = *(const uint4*)(wbl + c * 512);
    }
    __syncthreads();

    f32x16 acc0 = (f32x16)0.f, acc1 = (f32x16)0.f;   // rows rq*2, rq*2+1

#pragma unroll
    for (int tap = 0; tap < 9; tap++) {
        const int dy = tap / 3, dx = tap % 3;
        const int pixb = (rq * 2 + dy) * 34 + dx + colx;   // row rq*2

        uint4 Ba[4], Bb[4];
#pragma unroll
        for (int c = 0; c < 4; c++) {
            const int c2 = c * 2 + half;
            const int p0 = pixb, p1 = pixb + 34;
            Ba[c] = *(const uint4*)&lds[(p0 * 8 + (c2 ^ (p0 & 7))) * 4];
            Bb[c] = *(const uint4*)&lds[(p1 * 8 + (c2 ^ (p1 & 7))) * 4];
        }
        // prefetch NEXT tap's weights before this tap's MFMA block
        uint4 Hn[4], Ln[4];
        if (tap < 8) {
#pragma unroll
            for (int c = 0; c < 4; c++) {
                Hn[c] = *(const uint4*)(wbh + (tap + 1) * 2048 + c * 512);
                Ln[c] = *(const uint4*)(wbl + (tap + 1) * 2048 + c * 512);
            }
        }
#pragma unroll
        for (int c = 0; c < 4; c++) {
            const s16x8 b0 = fragpack(Ba[c]), b1 = fragpack(Bb[c]);
            const s16x8 ah = fragpack(Hc[c]), al = fragpack(Lc[c]);
            acc0 = __builtin_amdgcn_mfma_f32_32x32x16_bf16(ah, b0, acc0, 0, 0, 0);
            acc1 = __builtin_amdgcn_mfma_f32_32x32x16_bf16(ah, b1, acc1, 0, 0, 0);
            acc0 = __builtin_amdgcn_mfma_f32_32x32x16_bf16(al, b0, acc0, 0, 0, 0);
            acc1 = __builtin_amdgcn_mfma_f32_32x32x16_bf16(al, b1, acc1, 0, 0, 0);
        }
        if (tap < 8) {
#pragma unroll
            for (int c = 0; c < 4; c++) { Hc[c] = Hn[c]; Lc[c] = Ln[c]; }
        }
    }

    // ---- epilogue. C/D layout (32x32): col=lane&31 (pixel), row=(j&3)+8*(j>>2)+4*half (oc)
    // wave covers ocs mt*32..+31, block rows rq*2, rq*2+1.
    // readback: wave w <-> block row w; lane: pcol=lane&31, seg=lane>>5 (16 dwords each)
    const int pcol = colx, seg = half;
    const int pixg = (y0 + wid) * 256 + x0 + pcol;
    if constexpr (MODE == 1) {
        __syncthreads();                    // halo reads done; reuse lds for transpose
#define ST1(ACC, RR) { \
        _Pragma("unroll") \
        for (int j = 0; j < 16; j += 2) { \
            const int row = (j & 3) + 8 * (j >> 2) + 4 * half; \
            const int oc = mt * 32 + row; \
            float v0 = ACC[j]     + bias[oc]; \
            float v1 = ACC[j + 1] + bias[oc + 1]; \
            const float a0 = prelu[oc], a1 = prelu[oc + 1]; \
            v0 = fmaxf(v0, 0.f) + a0 * fminf(v0, 0.f); \
            v1 = fmaxf(v1, 0.f) + a1 * fminf(v1, 0.f); \
            const int icp = oc >> 1; \
            lds[((RR) * 32 + icp) * 32 + (colx ^ icp)] = \
                bf16rne(v0) | (bf16rne(v1) << 16); \
        } }
        ST1(acc0, rq * 2) ST1(acc1, rq * 2 + 1)
#undef ST1
        __syncthreads();
        uint d[16];
#pragma unroll
        for (int i = 0; i < 16; i++) {
            const int icp = seg * 16 + i;
            d[i] = lds[(wid * 32 + icp) * 32 + (pcol ^ icp)];
        }
        uint* o = op + (size_t)b * PLANE * 32 + chunk_addr(pixg, seg * 4);
#pragma unroll
        for (int k = 0; k < 4; k++)
            *(uint4*)(o + k * 128) = make_uint4(d[4*k], d[4*k+1], d[4*k+2], d[4*k+3]);
    } else {
        // hi pass, then lo pass, reusing the halo LDS (4096 dwords needed)
        const size_t cb = (size_t)b * PLANE * 32 + chunk_addr(pixg, seg * 4);
        uint d[16], dl[16];
        __syncthreads();
#define STH(ACC, RR) { \
        _Pragma("unroll") \
        for (int j = 0; j < 16; j += 2) { \
            const int row = (j & 3) + 8 * (j >> 2) + 4 * half; \
            const int oc = mt * 32 + row; \
            float v0 = ACC[j]     + bias[oc]; \
            float v1 = ACC[j + 1] + bias[oc + 1]; \
            const int icp = oc >> 1; \
            lds[((RR) * 32 + icp) * 32 + (colx ^ icp)] = \
                bf16rne(v0) | (bf16rne(v1) << 16); \
        } }
        STH(acc0, rq * 2) STH(acc1, rq * 2 + 1)
#undef STH
        __syncthreads();
#pragma unroll
        for (int i = 0; i < 16; i++) {
            const int icp = seg * 16 + i;
            d[i] = lds[(wid * 32 + icp) * 32 + (pcol ^ icp)];
        }
        uint* oh = op + cb;
#pragma unroll
        for (int k = 0; k < 4; k++)
            *(uint4*)(oh + k * 128) = make_uint4(d[4*k], d[4*k+1], d[4*k+2], d[4*k+3]);
        __syncthreads();
#define STL(ACC, RR) { \
        _Pragma("unroll") \
        for (int j = 0; j < 16; j += 2) { \
            const int row = (j & 3) + 8 * (j >> 2) + 4 * half; \
            const int oc = mt * 32 + row; \
            float v0 = ACC[j]     + bias[oc]; \
            float v1 = ACC[j + 1] + bias[oc + 1]; \
            float l0 = v0 - bf16val(bf16rne(v0)); \
            float l1 = v1 - bf16val(bf16rne(v1)); \
            const int icp = oc >> 1; \
            lds[((RR) * 32 + icp) * 32 + (colx ^ icp)] = \
                bf16rne(l0) | (bf16rne(l1) << 16); \
        } }
        STL(acc0, rq * 2) STL(acc1, rq * 2 + 1)
#undef STL
        __syncthreads();
        float s_ = 0.f, m_ = -INFINITY;
#pragma unroll
        for (int i = 0; i < 16; i++) {
            const int icp = seg * 16 + i;
            dl[i] = lds[(wid * 32 + icp) * 32 + (pcol ^ icp)];
            float ve = bf16val(d[i] & 0xffffu) + bf16val(dl[i] & 0xffffu);
            float vo = bf16val(d[i] >> 16)     + bf16val(dl[i] >> 16);
            s_ += ve + vo;
            m_ = fmaxf(m_, fmaxf(ve, vo));
        }
        uint* ol = op2 + cb;
#pragma unroll
        for (int k = 0; k < 4; k++)
            *(uint4*)(ol + k * 128) = make_uint4(dl[4*k], dl[4*k+1], dl[4*k+2], dl[4*k+3]);
        // combine the two 16-dword halves (seg 0/1) via lane^32
        s_ += __shfl_xor(s_, 32, 64);
        m_ = fmaxf(m_, __shfl_xor(m_, 32, 64));
        if (seg == 0) {
            amx[(size_t)b * 2 * PLANE + pixg] = s_ * (1.f / 64.f);
            amx[(size_t)b * 2 * PLANE + PLANE + pixg] = m_;
        }
    }
}

// ---------------- global average pool from fragment-slot hi: g[b,c] ----------
__global__ __launch_bounds__(256) void gpool_kernel(
    const uint* __restrict__ rph, float* __restrict__ g /*[B*C], pre-zeroed*/)
{
    const int tid = threadIdx.x;
    const int b = blockIdx.y;
    const uint* base = rph + (size_t)b * PLANE * 32;
    float s[8];
#pragma unroll
    for (int i = 0; i < 8; i++) s[i] = 0.f;
    for (int it = 0; it < 32; it++) {
        const size_t a = ((size_t)blockIdx.x * 32 + it) * 1024 + tid * 4;
        const uint4 q = *(const uint4*)(base + a);
        s[0] += bf16val(q.x & 0xffffu); s[1] += bf16val(q.x >> 16);
        s[2] += bf16val(q.y & 0xffffu); s[3] += bf16val(q.y >> 16);
        s[4] += bf16val(q.z & 0xffffu); s[5] += bf16val(q.z >> 16);
        s[6] += bf16val(q.w & 0xffffu); s[7] += bf16val(q.w >> 16);
    }
#pragma unroll
    for (int off = 16; off >= 1; off >>= 1)
#pragma unroll
        for (int i = 0; i < 8; i++) s[i] += __shfl_xor(s[i], off, 64);
    if ((tid & 31) == 0) {
        const int grp = tid >> 5;   // 0..7
#pragma unroll
        for (int i = 0; i < 8; i++)
            atomicAdd(&g[b * 64 + grp * 8 + i], s[i] * (1.f / PLANE));
    }
}

// ---------------- tiny MLPs -> hyper kernels, fragment-slot hi/lo --------
__global__ __launch_bounds__(256) void mlp_kernel(
    const float* __restrict__ h, const float* __restrict__ g,
    const float* __restrict__ ca_w1, const float* __restrict__ ca_b1,
    const float* __restrict__ ca_a,
    const float* __restrict__ ca_w2, const float* __restrict__ ca_b2,
    const float* __restrict__ fc_w, const float* __restrict__ fc_b,
    const float* __restrict__ k1_w, const float* __restrict__ k1_b,
    const float* __restrict__ k2_w, const float* __restrict__ k2_b,
    const float* __restrict__ k3_w, const float* __restrict__ k3_b,
    uint* __restrict__ kAhi, uint* __restrict__ kAlo,
    uint* __restrict__ kBhi, uint* __restrict__ kBlo)
{
    int b = blockIdx.x, tid = threadIdx.x;
    __shared__ float gb[64], t16[16], u32[32], v32[32], cg1[32], casig[64];

    if (tid < 64) gb[tid] = g[b * 64 + tid];
    __syncthreads();

    if (tid < 16) {
        float s = fc_b[tid];
        for (int j = 0; j < 16; j++) s += fc_w[tid * 16 + j] * h[b * 16 + j];
        t16[tid] = s >= 0.f ? s : 0.01f * s;
    }
    if (tid < 32) {
        float c1 = ca_b1[tid];
        for (int j = 0; j < 64; j++) c1 += ca_w1[tid * 64 + j] * gb[j];
        cg1[tid] = fmaxf(c1, 0.f) + ca_a[tid] * fminf(c1, 0.f);
    }
    __syncthreads();
    if (tid < 32) {
        float s = k1_b[tid];
        for (int j = 0; j < 16; j++) s += k1_w[tid * 16 + j] * t16[j];
        u32[tid] = s >= 0.f ? s : 0.01f * s;
    }
    if (tid < 64) {
        float c2 = ca_b2[tid];
        for (int j = 0; j < 32; j++) c2 += ca_w2[tid * 32 + j] * cg1[j];
        casig[tid] = 1.f / (1.f + expf(-c2));
    }
    __syncthreads();
    if (tid < 32) {
        float s = k2_b[tid];
        for (int j = 0; j < 32; j++) s += k2_w[tid * 32 + j] * u32[j];
        v32[tid] = s >= 0.f ? s : 0.01f * s;
    }
    __syncthreads();
    // k3: 8192 outputs, adjacent pairs -> one packed dword, fragment-slot store
    for (int o2 = tid; o2 < 4096; o2 += 256) {
        const int o = o2 * 2;
        const int oc = o >> 7;        // /128
        const int i = o & 127;        // even
        float s0 = k3_b[o], s1 = k3_b[o + 1];
        for (int j = 0; j < 32; j++) {
            s0 += k3_w[(size_t)o * 32 + j] * v32[j];
            s1 += k3_w[(size_t)(o + 1) * 32 + j] * v32[j];
        }
        uint *hi, *lo;
        if (i < 64) { hi = kAhi; lo = kAlo; }
        else { s0 *= casig[i - 64]; s1 *= casig[i - 63]; hi = kBhi; lo = kBlo; }
        const int cp = (i & 63) >> 1;
        uint h0 = bf16rne(s0); float l0 = s0 - bf16val(h0);
        uint h1 = bf16rne(s1); float l1 = s1 - bf16val(h1);
        const size_t a = (size_t)b * 2048 + (cp >> 2) * 256 + oc * 4 + (cp & 3);
        hi[a] = h0 | (h1 << 16);
        lo[a] = bf16rne(l0) | (bf16rne(l1) << 16);
    }
}

// ---------------- final via MFMA + inlined spatial-attention conv -----------
// out = x + hcb + sig(sa3x3(amx))*(A.r) + (B.r)
__global__ __launch_bounds__(256, 2) void final_mfma(
    const float* __restrict__ x, const uint* __restrict__ rph,
    const uint* __restrict__ rpl, const float* __restrict__ amx,
    const uint* __restrict__ kAhi, const uint* __restrict__ kAlo,
    const uint* __restrict__ kBhi, const uint* __restrict__ kBlo,
    const float* __restrict__ sa_w, const float* __restrict__ sa_b,
    const float* __restrict__ hcb, float* __restrict__ out)
{
    const int tid = threadIdx.x;
    const int lane = tid & 63;
    const int wid = tid >> 6;
    const int mt = wid & 1;          // oc Mtile
    const int gq = wid >> 1;         // pixel group
    const int b = blockIdx.y;
    const int colx = lane & 31;
    const int half = lane >> 5;
    const int pix = blockIdx.x * 64 + gq * 32 + colx;
    const int pgroup = blockIdx.x * 2 + gq;   // pix >> 5

    // fragment-slot kernel loads (lane-dense)
    const size_t kb = (size_t)b * 2048 + half * 256 + (size_t)(mt * 32 + colx) * 4;
    uint4 KAh[4], KAl[4], KBh[4], KBl[4];
#pragma unroll
    for (int c = 0; c < 4; c++) {
        KAh[c] = *(const uint4*)(kAhi + kb + c * 512);
        KAl[c] = *(const uint4*)(kAlo + kb + c * 512);
        KBh[c] = *(const uint4*)(kBhi + kb + c * 512);
        KBl[c] = *(const uint4*)(kBlo + kb + c * 512);
    }
    // fragment-slot activation loads
    const size_t rb = (size_t)b * PLANE * 32 + (size_t)pgroup * 1024
                    + half * 128 + colx * 4;
    uint4 Bh[4], Bl[4];
#pragma unroll
    for (int c = 0; c < 4; c++) {
        Bh[c] = *(const uint4*)(rph + rb + c * 256);
        Bl[c] = *(const uint4*)(rpl + rb + c * 256);
    }

    // inlined spatial attention: 3x3 reflect conv over amx (2ch -> 1)
    const int xx = pix & 255, yy = pix >> 8;
    float sacc = sa_b[0];
    const float* ab = amx + (size_t)b * 2 * PLANE;
#pragma unroll
    for (int cc = 0; cc < 2; cc++)
#pragma unroll
        for (int dy2 = -1; dy2 <= 1; dy2++)
#pragma unroll
            for (int dx2 = -1; dx2 <= 1; dx2++) {
                int gx = xx + dx2; gx = gx < 0 ? 1 : (gx >= WW ? 2 * WW - 2 - gx : gx);
                int gy = yy + dy2; gy = gy < 0 ? 1 : (gy >= HH ? 2 * HH - 2 - gy : gy);
                sacc += sa_w[cc * 9 + (dy2 + 1) * 3 + (dx2 + 1)]
                      * ab[(size_t)cc * PLANE + gy * WW + gx];
            }
    const float sig = 1.f / (1.f + expf(-sacc));

    f32x16 accA = (f32x16)0.f, accB = (f32x16)0.f;
#pragma unroll
    for (int c = 0; c < 4; c++) {
        const s16x8 bh = fragpack(Bh[c]), bl = fragpack(Bl[c]);
        const s16x8 ah = fragpack(KAh[c]), al = fragpack(KAl[c]);
        const s16x8 ch = fragpack(KBh[c]), cl = fragpack(KBl[c]);
        accA = __builtin_amdgcn_mfma_f32_32x32x16_bf16(ah, bh, accA, 0, 0, 0);
        accA = __builtin_amdgcn_mfma_f32_32x32x16_bf16(ah, bl, accA, 0, 0, 0);
        accA = __builtin_amdgcn_mfma_f32_32x32x16_bf16(al, bh, accA, 0, 0, 0);
        accB = __builtin_amdgcn_mfma_f32_32x32x16_bf16(ch, bh, accB, 0, 0, 0);
        accB = __builtin_amdgcn_mfma_f32_32x32x16_bf16(ch, bl, accB, 0, 0, 0);
        accB = __builtin_amdgcn_mfma_f32_32x32x16_bf16(cl, bh, accB, 0, 0, 0);
    }
#pragma unroll
    for (int j = 0; j < 16; j++) {
        const int row = (j & 3) + 8 * (j >> 2) + 4 * half;
        const int oc = mt * 32 + row;
        const size_t idx = ((size_t)b * 64 + oc) * PLANE + pix;
        out[idx] = x[idx] + hcb[oc] + sig * accA[j] + accB[j];
    }
}

extern "C" void kernel_launch(void* const* d_in, const int* in_sizes, int n_in,
                              void* d_out, int out_size, void* d_ws, size_t ws_size,
                              hipStream_t stream) {
    const float* x   = (const float*)d_in[0];
    const float* h   = (const float*)d_in[1];
    const float* c1w = (const float*)d_in[2];
    const float* c1b = (const float*)d_in[3];
    const float* pa  = (const float*)d_in[4];
    const float* c2w = (const float*)d_in[5];
    const float* c2b = (const float*)d_in[6];
    const float* saw = (const float*)d_in[7];
    const float* sab = (const float*)d_in[8];
    const float* cw1 = (const float*)d_in[9];
    const float* cb1 = (const float*)d_in[10];
    const float* caa = (const float*)d_in[11];
    const float* cw2 = (const float*)d_in[12];
    const float* cb2 = (const float*)d_in[13];
    const float* fcw = (const float*)d_in[14];
    const float* fcb = (const float*)d_in[15];
    const float* k1w = (const float*)d_in[16];
    const float* k1b = (const float*)d_in[17];
    const float* k2w = (const float*)d_in[18];
    const float* k2b = (const float*)d_in[19];
    const float* k3w = (const float*)d_in[20];
    const float* k3b = (const float*)d_in[21];
    const float* hcb = (const float*)d_in[22];
    float* out = (float*)d_out;

    char* ws = (char*)d_ws;
    const size_t SZ_Q = (size_t)8 * PLANE * 32 * 4;   // 67,108,864 (packed)
    uint*  xp  = (uint*)ws;                           // x repacked
    uint*  r1p = (uint*)(ws + SZ_Q);                  // conv1 out (hi)
    uint*  rph = (uint*)(ws + 2 * SZ_Q);              // conv2 out hi
    uint*  rpl = (uint*)(ws + 3 * SZ_Q);              // conv2 out lo
    float* amx   = (float*)ws;                        // aliases xp (dead after conv1)
    float* g     = (float*)(ws + (size_t)8 * 3 * PLANE * 4);
    uint*  kAhi  = (uint*)(ws + (size_t)8 * 3 * PLANE * 4 + 4096);
    uint*  kAlo  = kAhi + 8 * 2048;
    uint*  kBhi  = kAlo + 8 * 2048;
    uint*  kBlo  = kBhi + 8 * 2048;

    // weight packs live in d_out (dead until final_mfma overwrites it)
    uint* wsp = (uint*)d_out;
    uint* wh1 = wsp;          uint* wl1 = wsp + 18432;
    uint* wh2 = wsp + 36864;  uint* wl2 = wsp + 55296;

    wprep_kernel<<<dim3(72, 2), 256, 0, stream>>>(c1w, c2w, wh1, wl1, wh2, wl2);
    xrepack_kernel<<<dim3(PLANE / 256, 8), 256, 0, stream>>>(x, xp);

    dim3 cgrid(WW / 32, HH / 4, 8);  // (8, 64, 8)
    conv_mfma<1><<<cgrid, 256, 0, stream>>>(xp, wh1, wl1, c1b, pa, r1p, nullptr, nullptr);
    conv_mfma<2><<<cgrid, 256, 0, stream>>>(r1p, wh2, wl2, c2b, nullptr, rph, rpl, amx);

    hipMemsetAsync(g, 0, 512 * sizeof(float), stream);
    gpool_kernel<<<dim3(64, 8), 256, 0, stream>>>(rph, g);
    mlp_kernel<<<8, 256, 0, stream>>>(h, g, cw1, cb1, caa, cw2, cb2,
                                      fcw, fcb, k1w, k1b, k2w, k2b, k3w, k3b,
                                      kAhi, kAlo, kBhi, kBlo);
    final_mfma<<<dim3(PLANE / 64, 8), 256, 0, stream>>>(
        x, rph, rpl, amx, kAhi, kAlo, kBhi, kBlo, saw, sab, hcb, out);
}

// Round 15
// 596.048 us; speedup vs baseline: 1.7847x; 1.0493x over previous
//
#include <hip/hip_runtime.h>
#include <math.h>

#define HH 256
#define WW 256
#define CC 64
#define PLANE (HH*WW)

typedef short s16x8 __attribute__((ext_vector_type(8)));
typedef float f32x16 __attribute__((ext_vector_type(16)));
typedef unsigned int uint;
typedef uint u32x4v __attribute__((ext_vector_type(4)));

__device__ inline uint bf16rne(float f) {
    uint u = __float_as_uint(f);
    return (u + 0x7FFFu + ((u >> 16) & 1u)) >> 16;
}
__device__ inline float bf16val(uint h) { return __uint_as_float(h << 16); }
__device__ inline s16x8 fragpack(uint4 q) {
    u32x4v t = {q.x, q.y, q.z, q.w};
    return __builtin_bit_cast(s16x8, t);
}
__device__ inline void gload_lds16(const uint* g, uint* l) {
    __builtin_amdgcn_global_load_lds(
        (const __attribute__((address_space(1))) uint*)g,
        (__attribute__((address_space(3))) uint*)l, 16, 0, 0);
}
// activation fragment-slot layout: dword (pix, dwi) at
//   (pix>>5)*1024 + (dwi>>2)*128 + (pix&31)*4 + (dwi&3)
__device__ inline size_t chunk_addr(int pix, int c2) {
    return (size_t)(pix >> 5) * 1024 + c2 * 128 + (pix & 31) * 4;
}
// weight fragment-slot layout: dword (tap, oc, dwi) at
//   tap*2048 + (dwi>>2)*256 + oc*4 + (dwi&3)   -> lane-dense dwordx4 loads

// ---------------- weight prep: split fp32 W into bf16 hi/lo ----------------
__global__ __launch_bounds__(256) void wprep_kernel(
    const float* __restrict__ w1, const float* __restrict__ w2,
    uint* __restrict__ wh1, uint* __restrict__ wl1,
    uint* __restrict__ wh2, uint* __restrict__ wl2)
{
    const int idx = blockIdx.x * 256 + threadIdx.x;      // 0..18431
    const float* w = blockIdx.y ? w2 : w1;
    uint* wh = blockIdx.y ? wh2 : wh1;
    uint* wl = blockIdx.y ? wl2 : wl1;
    const int tap = idx >> 11;           // 9
    const int oc  = (idx >> 5) & 63;     // 64
    const int icp = idx & 31;            // 32 ic-pairs (dword index)
    float w0 = w[(oc * 64 + 2 * icp) * 9 + tap];
    float w1v = w[(oc * 64 + 2 * icp + 1) * 9 + tap];
    uint h0 = bf16rne(w0); float l0 = w0 - bf16val(h0);
    uint h1 = bf16rne(w1v); float l1 = w1v - bf16val(h1);
    const int a = tap * 2048 + (icp >> 2) * 256 + oc * 4 + (icp & 3);
    wh[a] = h0 | (h1 << 16);
    wl[a] = bf16rne(l0) | (bf16rne(l1) << 16);
}

// ---------------- x repack: fp32 NCHW -> bf16-pair fragment-slot ----------------
__global__ __launch_bounds__(256) void xrepack_kernel(
    const float* __restrict__ x, uint* __restrict__ xp)
{
    const int tid = threadIdx.x;
    const int px = blockIdx.x * 256 + tid;
    const int b = blockIdx.y;
    const float* xb = x + (size_t)b * CC * PLANE + px;
    uint d[32];
#pragma unroll
    for (int icp = 0; icp < 32; icp++) {
        float v0 = xb[(size_t)(2 * icp) * PLANE];
        float v1 = xb[(size_t)(2 * icp + 1) * PLANE];
        d[icp] = bf16rne(v0) | (bf16rne(v1) << 16);
    }
    uint* o = xp + (size_t)b * PLANE * 32 + chunk_addr(px, 0);
#pragma unroll
    for (int k = 0; k < 8; k++)
        *(uint4*)(o + k * 128) = make_uint4(d[4*k], d[4*k+1], d[4*k+2], d[4*k+3]);
}

// ---------------- conv 3x3 reflect via MFMA, 4-row tile, LDS halo ----------
// wave w: Mtile mt = w&1 (32 oc), row-pair rq = w>>1 (rows rq*2, rq*2+1).
// Per tap: {8 ds_read_b128 + NEXT tap's 8 weight dwordx4} -> sched_barrier(0)
// -> 16 MFMA. The barrier pins the load batch above the MFMAs (rule 18 /
// T19) so each tap pays ONE wait, and weights were issued a full tap early.
// MODE 1: PReLU + fragment-slot (hi only) out.
// MODE 2: fragment-slot hi/lo out + fused chan mean/max + fused gpool partials.
#define HPIX 204                 // 6*34 halo pixels
#define HCHUNK (HPIX*8)          // 16B chunks = 1632
template<int MODE>
__global__ __launch_bounds__(256, 3) void conv_mfma(
    const uint* __restrict__ xin,   // fragment-slot packed
    const uint* __restrict__ wh, const uint* __restrict__ wl,
    const float* __restrict__ bias, const float* __restrict__ prelu,
    uint* __restrict__ op, uint* __restrict__ op2, float* __restrict__ amx,
    float* __restrict__ gsum)
{
    __shared__ uint lds[HPIX * 32];          // 26,112 B
    const int tid  = threadIdx.x;
    const int lane = tid & 63;
    const int wid  = tid >> 6;
    const int x0 = blockIdx.x * 32;
    const int y0 = blockIdx.y * 4;
    const int b  = blockIdx.z;
    const int colx = lane & 31;
    const int half = lane >> 5;
    const int mt = wid & 1;          // Mtile (oc group of 32)
    const int rq = wid >> 1;         // row pair: rows rq*2, rq*2+1

    // ---- stage halo: chunk k -> LDS byte k*16 (linear), source pre-swizzled
    {
        const uint* gb = xin + (size_t)b * PLANE * 32;
#pragma unroll
        for (int iter = 0; iter < 7; iter++) {
            const int k = iter * 256 + tid;
            if (iter < 6 || k < HCHUNK) {
                const int pix = k >> 3;
                const int slot = k & 7;
                const int hrow = pix / 34;
                const int hcol = pix - hrow * 34;
                int gy = y0 - 1 + hrow; gy = gy < 0 ? 1 : (gy > 255 ? 254 : gy);
                int gx = x0 - 1 + hcol; gx = gx < 0 ? 1 : (gx > 255 ? 254 : gx);
                const int c2 = slot ^ (pix & 7);    // involution
                gload_lds16(gb + chunk_addr(gy * 256 + gx, c2),
                            &lds[(iter * 256 + wid * 64) * 4]);
            }
        }
    }

    // lane-dense weight base for this wave's Mtile; preload tap 0
    const uint* wbh = wh + half * 256 + (mt * 32 + colx) * 4;
    const uint* wbl = wl + half * 256 + (mt * 32 + colx) * 4;
    uint4 Hc[4], Lc[4];
#pragma unroll
    for (int c = 0; c < 4; c++) {
        Hc[c] = *(const uint4*)(wbh + c * 512);
        Lc[c] = *(const uint4*)(wbl + c * 512);
    }
    __syncthreads();

    f32x16 acc0 = (f32x16)0.f, acc1 = (f32x16)0.f;   // rows rq*2, rq*2+1

#pragma unroll
    for (int tap = 0; tap < 9; tap++) {
        const int dy = tap / 3, dx = tap % 3;
        const int pixb = (rq * 2 + dy) * 34 + dx + colx;   // row rq*2

        uint4 Ba[4], Bb[4];
#pragma unroll
        for (int c = 0; c < 4; c++) {
            const int c2 = c * 2 + half;
            const int p0 = pixb, p1 = pixb + 34;
            Ba[c] = *(const uint4*)&lds[(p0 * 8 + (c2 ^ (p0 & 7))) * 4];
            Bb[c] = *(const uint4*)&lds[(p1 * 8 + (c2 ^ (p1 & 7))) * 4];
        }
        uint4 Hn[4], Ln[4];
        if (tap < 8) {
#pragma unroll
            for (int c = 0; c < 4; c++) {
                Hn[c] = *(const uint4*)(wbh + (tap + 1) * 2048 + c * 512);
                Ln[c] = *(const uint4*)(wbl + (tap + 1) * 2048 + c * 512);
            }
        }
        // pin: all loads above stay above; MFMAs below stay below
        __builtin_amdgcn_sched_barrier(0);
#pragma unroll
        for (int c = 0; c < 4; c++) {
            const s16x8 b0 = fragpack(Ba[c]), b1 = fragpack(Bb[c]);
            const s16x8 ah = fragpack(Hc[c]), al = fragpack(Lc[c]);
            acc0 = __builtin_amdgcn_mfma_f32_32x32x16_bf16(ah, b0, acc0, 0, 0, 0);
            acc1 = __builtin_amdgcn_mfma_f32_32x32x16_bf16(ah, b1, acc1, 0, 0, 0);
            acc0 = __builtin_amdgcn_mfma_f32_32x32x16_bf16(al, b0, acc0, 0, 0, 0);
            acc1 = __builtin_amdgcn_mfma_f32_32x32x16_bf16(al, b1, acc1, 0, 0, 0);
        }
        if (tap < 8) {
#pragma unroll
            for (int c = 0; c < 4; c++) { Hc[c] = Hn[c]; Lc[c] = Ln[c]; }
        }
    }

    // ---- epilogue. C/D layout (32x32): col=lane&31 (pixel), row=(j&3)+8*(j>>2)+4*half (oc)
    const int pcol = colx, seg = half;
    const int pixg = (y0 + wid) * 256 + x0 + pcol;
    if constexpr (MODE == 1) {
        __syncthreads();                    // halo reads done; reuse lds for transpose
#define ST1(ACC, RR) { \
        _Pragma("unroll") \
        for (int j = 0; j < 16; j += 2) { \
            const int row = (j & 3) + 8 * (j >> 2) + 4 * half; \
            const int oc = mt * 32 + row; \
            float v0 = ACC[j]     + bias[oc]; \
            float v1 = ACC[j + 1] + bias[oc + 1]; \
            const float a0 = prelu[oc], a1 = prelu[oc + 1]; \
            v0 = fmaxf(v0, 0.f) + a0 * fminf(v0, 0.f); \
            v1 = fmaxf(v1, 0.f) + a1 * fminf(v1, 0.f); \
            const int icp = oc >> 1; \
            lds[((RR) * 32 + icp) * 32 + (colx ^ icp)] = \
                bf16rne(v0) | (bf16rne(v1) << 16); \
        } }
        ST1(acc0, rq * 2) ST1(acc1, rq * 2 + 1)
#undef ST1
        __syncthreads();
        uint d[16];
#pragma unroll
        for (int i = 0; i < 16; i++) {
            const int icp = seg * 16 + i;
            d[i] = lds[(wid * 32 + icp) * 32 + (pcol ^ icp)];
        }
        uint* o = op + (size_t)b * PLANE * 32 + chunk_addr(pixg, seg * 4);
#pragma unroll
        for (int k = 0; k < 4; k++)
            *(uint4*)(o + k * 128) = make_uint4(d[4*k], d[4*k+1], d[4*k+2], d[4*k+3]);
    } else {
        // hi pass, then lo pass, reusing the halo LDS (4096 dwords needed)
        const size_t cb = (size_t)b * PLANE * 32 + chunk_addr(pixg, seg * 4);
        uint d[16], dl[16];
        __syncthreads();
#define STH(ACC, RR) { \
        _Pragma("unroll") \
        for (int j = 0; j < 16; j += 2) { \
            const int row = (j & 3) + 8 * (j >> 2) + 4 * half; \
            const int oc = mt * 32 + row; \
            float v0 = ACC[j]     + bias[oc]; \
            float v1 = ACC[j + 1] + bias[oc + 1]; \
            const int icp = oc >> 1; \
            lds[((RR) * 32 + icp) * 32 + (colx ^ icp)] = \
                bf16rne(v0) | (bf16rne(v1) << 16); \
        } }
        STH(acc0, rq * 2) STH(acc1, rq * 2 + 1)
#undef STH
        __syncthreads();
#pragma unroll
        for (int i = 0; i < 16; i++) {
            const int icp = seg * 16 + i;
            d[i] = lds[(wid * 32 + icp) * 32 + (pcol ^ icp)];
        }
        // fused gpool: channel-major partial sums from the hi transpose.
        // thread t: channel-pair cp=t&31, pixel subset hr=t>>5 (16 pixels).
        // bank = (pc ^ cp) & 31 is a lane-permutation -> conflict-free.
        const int cp_g = tid & 31;
        const int hr_g = tid >> 5;
        const int row_g = hr_g >> 1;
        const int pc0_g = (hr_g & 1) * 16;
        float gs0 = 0.f, gs1 = 0.f;
#pragma unroll
        for (int p = 0; p < 16; p++) {
            const int pc = pc0_g + p;
            const uint v = lds[(row_g * 32 + cp_g) * 32 + (pc ^ cp_g)];
            gs0 += bf16val(v & 0xffffu);
            gs1 += bf16val(v >> 16);
        }
        uint* oh = op + cb;
#pragma unroll
        for (int k = 0; k < 4; k++)
            *(uint4*)(oh + k * 128) = make_uint4(d[4*k], d[4*k+1], d[4*k+2], d[4*k+3]);
        __syncthreads();
#define STL(ACC, RR) { \
        _Pragma("unroll") \
        for (int j = 0; j < 16; j += 2) { \
            const int row = (j & 3) + 8 * (j >> 2) + 4 * half; \
            const int oc = mt * 32 + row; \
            float v0 = ACC[j]     + bias[oc]; \
            float v1 = ACC[j + 1] + bias[oc + 1]; \
            float l0 = v0 - bf16val(bf16rne(v0)); \
            float l1 = v1 - bf16val(bf16rne(v1)); \
            const int icp = oc >> 1; \
            lds[((RR) * 32 + icp) * 32 + (colx ^ icp)] = \
                bf16rne(l0) | (bf16rne(l1) << 16); \
        } }
        STL(acc0, rq * 2) STL(acc1, rq * 2 + 1)
#undef STL
        __syncthreads();
        float s_ = 0.f, m_ = -INFINITY;
#pragma unroll
        for (int i = 0; i < 16; i++) {
            const int icp = seg * 16 + i;
            dl[i] = lds[(wid * 32 + icp) * 32 + (pcol ^ icp)];
            float ve = bf16val(d[i] & 0xffffu) + bf16val(dl[i] & 0xffffu);
            float vo = bf16val(d[i] >> 16)     + bf16val(dl[i] >> 16);
            s_ += ve + vo;
            m_ = fmaxf(m_, fmaxf(ve, vo));
        }
        uint* ol = op2 + cb;
#pragma unroll
        for (int k = 0; k < 4; k++)
            *(uint4*)(ol + k * 128) = make_uint4(dl[4*k], dl[4*k+1], dl[4*k+2], dl[4*k+3]);
        // gpool partials: region [4096, 4608) of lds is free (lo transpose uses <4096)
        lds[4096 + hr_g * 64 + 2 * cp_g]     = __float_as_uint(gs0);
        lds[4096 + hr_g * 64 + 2 * cp_g + 1] = __float_as_uint(gs1);
        // combine the two 16-dword halves (seg 0/1) via lane^32
        s_ += __shfl_xor(s_, 32, 64);
        m_ = fmaxf(m_, __shfl_xor(m_, 32, 64));
        if (seg == 0) {
            amx[(size_t)b * 2 * PLANE + pixg] = s_ * (1.f / 64.f);
            amx[(size_t)b * 2 * PLANE + PLANE + pixg] = m_;
        }
        __syncthreads();
        if (tid < 64) {
            float t = 0.f;
#pragma unroll
            for (int h8 = 0; h8 < 8; h8++)
                t += __uint_as_float(lds[4096 + h8 * 64 + tid]);
            atomicAdd(&gsum[b * 64 + tid], t * (1.f / PLANE));
        }
    }
}

// ---------------- tiny MLPs -> hyper kernels, fragment-slot hi/lo --------
__global__ __launch_bounds__(256) void mlp_kernel(
    const float* __restrict__ h, const float* __restrict__ g,
    const float* __restrict__ ca_w1, const float* __restrict__ ca_b1,
    const float* __restrict__ ca_a,
    const float* __restrict__ ca_w2, const float* __restrict__ ca_b2,
    const float* __restrict__ fc_w, const float* __restrict__ fc_b,
    const float* __restrict__ k1_w, const float* __restrict__ k1_b,
    const float* __restrict__ k2_w, const float* __restrict__ k2_b,
    const float* __restrict__ k3_w, const float* __restrict__ k3_b,
    uint* __restrict__ kAhi, uint* __restrict__ kAlo,
    uint* __restrict__ kBhi, uint* __restrict__ kBlo)
{
    int b = blockIdx.x, tid = threadIdx.x;
    __shared__ float gb[64], t16[16], u32[32], v32[32], cg1[32], casig[64];

    if (tid < 64) gb[tid] = g[b * 64 + tid];
    __syncthreads();

    if (tid < 16) {
        float s = fc_b[tid];
        for (int j = 0; j < 16; j++) s += fc_w[tid * 16 + j] * h[b * 16 + j];
        t16[tid] = s >= 0.f ? s : 0.01f * s;
    }
    if (tid < 32) {
        float c1 = ca_b1[tid];
        for (int j = 0; j < 64; j++) c1 += ca_w1[tid * 64 + j] * gb[j];
        cg1[tid] = fmaxf(c1, 0.f) + ca_a[tid] * fminf(c1, 0.f);
    }
    __syncthreads();
    if (tid < 32) {
        float s = k1_b[tid];
        for (int j = 0; j < 16; j++) s += k1_w[tid * 16 + j] * t16[j];
        u32[tid] = s >= 0.f ? s : 0.01f * s;
    }
    if (tid < 64) {
        float c2 = ca_b2[tid];
        for (int j = 0; j < 32; j++) c2 += ca_w2[tid * 32 + j] * cg1[j];
        casig[tid] = 1.f / (1.f + expf(-c2));
    }
    __syncthreads();
    if (tid < 32) {
        float s = k2_b[tid];
        for (int j = 0; j < 32; j++) s += k2_w[tid * 32 + j] * u32[j];
        v32[tid] = s >= 0.f ? s : 0.01f * s;
    }
    __syncthreads();
    // k3: 8192 outputs, adjacent pairs -> one packed dword, fragment-slot store
    for (int o2 = tid; o2 < 4096; o2 += 256) {
        const int o = o2 * 2;
        const int oc = o >> 7;        // /128
        const int i = o & 127;        // even
        float s0 = k3_b[o], s1 = k3_b[o + 1];
        for (int j = 0; j < 32; j++) {
            s0 += k3_w[(size_t)o * 32 + j] * v32[j];
            s1 += k3_w[(size_t)(o + 1) * 32 + j] * v32[j];
        }
        uint *hi, *lo;
        if (i < 64) { hi = kAhi; lo = kAlo; }
        else { s0 *= casig[i - 64]; s1 *= casig[i - 63]; hi = kBhi; lo = kBlo; }
        const int cp = (i & 63) >> 1;
        uint h0 = bf16rne(s0); float l0 = s0 - bf16val(h0);
        uint h1 = bf16rne(s1); float l1 = s1 - bf16val(h1);
        const size_t a = (size_t)b * 2048 + (cp >> 2) * 256 + oc * 4 + (cp & 3);
        hi[a] = h0 | (h1 << 16);
        lo[a] = bf16rne(l0) | (bf16rne(l1) << 16);
    }
}

// ---------------- final via MFMA + inlined spatial-attention conv -----------
// out = x + hcb + sig(sa3x3(amx))*(A.r) + (B.r)
__global__ __launch_bounds__(256, 2) void final_mfma(
    const float* __restrict__ x, const uint* __restrict__ rph,
    const uint* __restrict__ rpl, const float* __restrict__ amx,
    const uint* __restrict__ kAhi, const uint* __restrict__ kAlo,
    const uint* __restrict__ kBhi, const uint* __restrict__ kBlo,
    const float* __restrict__ sa_w, const float* __restrict__ sa_b,
    const float* __restrict__ hcb, float* __restrict__ out)
{
    const int tid = threadIdx.x;
    const int lane = tid & 63;
    const int wid = tid >> 6;
    const int mt = wid & 1;          // oc Mtile
    const int gq = wid >> 1;         // pixel group
    const int b = blockIdx.y;
    const int colx = lane & 31;
    const int half = lane >> 5;
    const int pix = blockIdx.x * 64 + gq * 32 + colx;
    const int pgroup = blockIdx.x * 2 + gq;   // pix >> 5

    // fragment-slot kernel loads (lane-dense)
    const size_t kb = (size_t)b * 2048 + half * 256 + (size_t)(mt * 32 + colx) * 4;
    uint4 KAh[4], KAl[4], KBh[4], KBl[4];
#pragma unroll
    for (int c = 0; c < 4; c++) {
        KAh[c] = *(const uint4*)(kAhi + kb + c * 512);
        KAl[c] = *(const uint4*)(kAlo + kb + c * 512);
        KBh[c] = *(const uint4*)(kBhi + kb + c * 512);
        KBl[c] = *(const uint4*)(kBlo + kb + c * 512);
    }
    // fragment-slot activation loads
    const size_t rb = (size_t)b * PLANE * 32 + (size_t)pgroup * 1024
                    + half * 128 + colx * 4;
    uint4 Bh[4], Bl[4];
#pragma unroll
    for (int c = 0; c < 4; c++) {
        Bh[c] = *(const uint4*)(rph + rb + c * 256);
        Bl[c] = *(const uint4*)(rpl + rb + c * 256);
    }

    // inlined spatial attention: 3x3 reflect conv over amx (2ch -> 1)
    const int xx = pix & 255, yy = pix >> 8;
    float sacc = sa_b[0];
    const float* ab = amx + (size_t)b * 2 * PLANE;
#pragma unroll
    for (int cc = 0; cc < 2; cc++)
#pragma unroll
        for (int dy2 = -1; dy2 <= 1; dy2++)
#pragma unroll
            for (int dx2 = -1; dx2 <= 1; dx2++) {
                int gx = xx + dx2; gx = gx < 0 ? 1 : (gx >= WW ? 2 * WW - 2 - gx : gx);
                int gy = yy + dy2; gy = gy < 0 ? 1 : (gy >= HH ? 2 * HH - 2 - gy : gy);
                sacc += sa_w[cc * 9 + (dy2 + 1) * 3 + (dx2 + 1)]
                      * ab[(size_t)cc * PLANE + gy * WW + gx];
            }
    const float sig = 1.f / (1.f + expf(-sacc));

    f32x16 accA = (f32x16)0.f, accB = (f32x16)0.f;
#pragma unroll
    for (int c = 0; c < 4; c++) {
        const s16x8 bh = fragpack(Bh[c]), bl = fragpack(Bl[c]);
        const s16x8 ah = fragpack(KAh[c]), al = fragpack(KAl[c]);
        const s16x8 ch = fragpack(KBh[c]), cl = fragpack(KBl[c]);
        accA = __builtin_amdgcn_mfma_f32_32x32x16_bf16(ah, bh, accA, 0, 0, 0);
        accA = __builtin_amdgcn_mfma_f32_32x32x16_bf16(ah, bl, accA, 0, 0, 0);
        accA = __builtin_amdgcn_mfma_f32_32x32x16_bf16(al, bh, accA, 0, 0, 0);
        accB = __builtin_amdgcn_mfma_f32_32x32x16_bf16(ch, bh, accB, 0, 0, 0);
        accB = __builtin_amdgcn_mfma_f32_32x32x16_bf16(ch, bl, accB, 0, 0, 0);
        accB = __builtin_amdgcn_mfma_f32_32x32x16_bf16(cl, bh, accB, 0, 0, 0);
    }
#pragma unroll
    for (int j = 0; j < 16; j++) {
        const int row = (j & 3) + 8 * (j >> 2) + 4 * half;
        const int oc = mt * 32 + row;
        const size_t idx = ((size_t)b * 64 + oc) * PLANE + pix;
        out[idx] = x[idx] + hcb[oc] + sig * accA[j] + accB[j];
    }
}

extern "C" void kernel_launch(void* const* d_in, const int* in_sizes, int n_in,
                              void* d_out, int out_size, void* d_ws, size_t ws_size,
                              hipStream_t stream) {
    const float* x   = (const float*)d_in[0];
    const float* h   = (const float*)d_in[1];
    const float* c1w = (const float*)d_in[2];
    const float* c1b = (const float*)d_in[3];
    const float* pa  = (const float*)d_in[4];
    const float* c2w = (const float*)d_in[5];
    const float* c2b = (const float*)d_in[6];
    const float* saw = (const float*)d_in[7];
    const float* sab = (const float*)d_in[8];
    const float* cw1 = (const float*)d_in[9];
    const float* cb1 = (const float*)d_in[10];
    const float* caa = (const float*)d_in[11];
    const float* cw2 = (const float*)d_in[12];
    const float* cb2 = (const float*)d_in[13];
    const float* fcw = (const float*)d_in[14];
    const float* fcb = (const float*)d_in[15];
    const float* k1w = (const float*)d_in[16];
    const float* k1b = (const float*)d_in[17];
    const float* k2w = (const float*)d_in[18];
    const float* k2b = (const float*)d_in[19];
    const float* k3w = (const float*)d_in[20];
    const float* k3b = (const float*)d_in[21];
    const float* hcb = (const float*)d_in[22];
    float* out = (float*)d_out;

    char* ws = (char*)d_ws;
    const size_t SZ_Q = (size_t)8 * PLANE * 32 * 4;   // 67,108,864 (packed)
    uint*  xp  = (uint*)ws;                           // x repacked
    uint*  r1p = (uint*)(ws + SZ_Q);                  // conv1 out (hi)
    uint*  rph = (uint*)(ws + 2 * SZ_Q);              // conv2 out hi
    uint*  rpl = (uint*)(ws + 3 * SZ_Q);              // conv2 out lo
    float* amx   = (float*)ws;                        // aliases xp (xp dead after conv1)
    uint*  kAhi  = (uint*)(ws + (size_t)8 * 3 * PLANE * 4 + 4096);
    uint*  kAlo  = kAhi + 8 * 2048;
    uint*  kBhi  = kAlo + 8 * 2048;
    uint*  kBlo  = kBhi + 8 * 2048;

    // weight packs + g live in d_out (dead until final_mfma overwrites it).
    // g must NOT alias xp: it is memset BEFORE conv1 (xp still live there).
    uint* wsp = (uint*)d_out;
    uint* wh1 = wsp;          uint* wl1 = wsp + 18432;
    uint* wh2 = wsp + 36864;  uint* wl2 = wsp + 55296;
    float* g  = (float*)(wsp + 73728);                // 512 floats in d_out

    wprep_kernel<<<dim3(72, 2), 256, 0, stream>>>(c1w, c2w, wh1, wl1, wh2, wl2);
    xrepack_kernel<<<dim3(PLANE / 256, 8), 256, 0, stream>>>(x, xp);
    hipMemsetAsync(g, 0, 512 * sizeof(float), stream);

    dim3 cgrid(WW / 32, HH / 4, 8);  // (8, 64, 8)
    conv_mfma<1><<<cgrid, 256, 0, stream>>>(xp, wh1, wl1, c1b, pa, r1p, nullptr,
                                            nullptr, nullptr);
    conv_mfma<2><<<cgrid, 256, 0, stream>>>(r1p, wh2, wl2, c2b, nullptr, rph, rpl,
                                            amx, g);

    mlp_kernel<<<8, 256, 0, stream>>>(h, g, cw1, cb1, caa, cw2, cb2,
                                      fcw, fcb, k1w, k1b, k2w, k2b, k3w, k3b,
                                      kAhi, kAlo, kBhi, kBlo);
    final_mfma<<<dim3(PLANE / 64, 8), 256, 0, stream>>>(
        x, rph, rpl, amx, kAhi, kAlo, kBhi, kBlo, saw, sab, hcb, out);
}

// Round 16
// 564.169 us; speedup vs baseline: 1.8855x; 1.0565x over previous
//
#include <hip/hip_runtime.h>
#include <math.h>

#define HH 256
#define WW 256
#define CC 64
#define PLANE (HH*WW)

typedef short s16x8 __attribute__((ext_vector_type(8)));
typedef float f32x16 __attribute__((ext_vector_type(16)));
typedef unsigned int uint;
typedef uint u32x4v __attribute__((ext_vector_type(4)));

__device__ inline uint bf16rne(float f) {
    uint u = __float_as_uint(f);
    return (u + 0x7FFFu + ((u >> 16) & 1u)) >> 16;
}
__device__ inline float bf16val(uint h) { return __uint_as_float(h << 16); }
__device__ inline s16x8 fragpack(uint4 q) {
    u32x4v t = {q.x, q.y, q.z, q.w};
    return __builtin_bit_cast(s16x8, t);
}
__device__ inline void gload_lds16(const uint* g, uint* l) {
    __builtin_amdgcn_global_load_lds(
        (const __attribute__((address_space(1))) uint*)g,
        (__attribute__((address_space(3))) uint*)l, 16, 0, 0);
}
// activation fragment-slot layout: dword (pix, dwi) at
//   (pix>>5)*1024 + (dwi>>2)*128 + (pix&31)*4 + (dwi&3)
__device__ inline size_t chunk_addr(int pix, int c2) {
    return (size_t)(pix >> 5) * 1024 + c2 * 128 + (pix & 31) * 4;
}
// weight fragment-slot layout: dword (tap, oc, dwi) at
//   tap*2048 + (dwi>>2)*256 + oc*4 + (dwi&3)   -> lane-dense dwordx4 loads

// ---------------- weight prep: split fp32 W into bf16 hi/lo ----------------
__global__ __launch_bounds__(256) void wprep_kernel(
    const float* __restrict__ w1, const float* __restrict__ w2,
    uint* __restrict__ wh1, uint* __restrict__ wl1,
    uint* __restrict__ wh2, uint* __restrict__ wl2)
{
    const int idx = blockIdx.x * 256 + threadIdx.x;      // 0..18431
    const float* w = blockIdx.y ? w2 : w1;
    uint* wh = blockIdx.y ? wh2 : wh1;
    uint* wl = blockIdx.y ? wl2 : wl1;
    const int tap = idx >> 11;           // 9
    const int oc  = (idx >> 5) & 63;     // 64
    const int icp = idx & 31;            // 32 ic-pairs (dword index)
    float w0 = w[(oc * 64 + 2 * icp) * 9 + tap];
    float w1v = w[(oc * 64 + 2 * icp + 1) * 9 + tap];
    uint h0 = bf16rne(w0); float l0 = w0 - bf16val(h0);
    uint h1 = bf16rne(w1v); float l1 = w1v - bf16val(h1);
    const int a = tap * 2048 + (icp >> 2) * 256 + oc * 4 + (icp & 3);
    wh[a] = h0 | (h1 << 16);
    wl[a] = bf16rne(l0) | (bf16rne(l1) << 16);
}

// ---------------- x repack: fp32 NCHW -> bf16-pair fragment-slot ----------------
__global__ __launch_bounds__(256) void xrepack_kernel(
    const float* __restrict__ x, uint* __restrict__ xp)
{
    const int tid = threadIdx.x;
    const int px = blockIdx.x * 256 + tid;
    const int b = blockIdx.y;
    const float* xb = x + (size_t)b * CC * PLANE + px;
    uint d[32];
#pragma unroll
    for (int icp = 0; icp < 32; icp++) {
        float v0 = xb[(size_t)(2 * icp) * PLANE];
        float v1 = xb[(size_t)(2 * icp + 1) * PLANE];
        d[icp] = bf16rne(v0) | (bf16rne(v1) << 16);
    }
    uint* o = xp + (size_t)b * PLANE * 32 + chunk_addr(px, 0);
#pragma unroll
    for (int k = 0; k < 8; k++)
        *(uint4*)(o + k * 128) = make_uint4(d[4*k], d[4*k+1], d[4*k+2], d[4*k+3]);
}

// ---------------- conv 3x3 reflect via MFMA, 4-row tile, LDS halo ----------
// wave w: Mtile mt = w&1 (32 oc), row-pair rq = w>>1 (rows rq*2, rq*2+1).
// Per tap: {8 ds_read_b128 + NEXT tap's 8 weight dwordx4} -> sched_barrier(0)
// -> 16 MFMA.
// MODE 1: PReLU + fragment-slot (hi only) out.
// MODE 2: fragment-slot hi out + fused chan mean/max + fused gpool partials.
//         (lo residual dropped: r already carries O(2^-9) upstream rounding)
#define HPIX 204                 // 6*34 halo pixels
#define HCHUNK (HPIX*8)          // 16B chunks = 1632
template<int MODE>
__global__ __launch_bounds__(256, 3) void conv_mfma(
    const uint* __restrict__ xin,   // fragment-slot packed
    const uint* __restrict__ wh, const uint* __restrict__ wl,
    const float* __restrict__ bias, const float* __restrict__ prelu,
    uint* __restrict__ op, float* __restrict__ amx, float* __restrict__ gsum)
{
    __shared__ uint lds[HPIX * 32];          // 26,112 B
    const int tid  = threadIdx.x;
    const int lane = tid & 63;
    const int wid  = tid >> 6;
    const int x0 = blockIdx.x * 32;
    const int y0 = blockIdx.y * 4;
    const int b  = blockIdx.z;
    const int colx = lane & 31;
    const int half = lane >> 5;
    const int mt = wid & 1;          // Mtile (oc group of 32)
    const int rq = wid >> 1;         // row pair: rows rq*2, rq*2+1

    // ---- stage halo: chunk k -> LDS byte k*16 (linear), source pre-swizzled
    {
        const uint* gb = xin + (size_t)b * PLANE * 32;
#pragma unroll
        for (int iter = 0; iter < 7; iter++) {
            const int k = iter * 256 + tid;
            if (iter < 6 || k < HCHUNK) {
                const int pix = k >> 3;
                const int slot = k & 7;
                const int hrow = pix / 34;
                const int hcol = pix - hrow * 34;
                int gy = y0 - 1 + hrow; gy = gy < 0 ? 1 : (gy > 255 ? 254 : gy);
                int gx = x0 - 1 + hcol; gx = gx < 0 ? 1 : (gx > 255 ? 254 : gx);
                const int c2 = slot ^ (pix & 7);    // involution
                gload_lds16(gb + chunk_addr(gy * 256 + gx, c2),
                            &lds[(iter * 256 + wid * 64) * 4]);
            }
        }
    }

    // lane-dense weight base for this wave's Mtile; preload tap 0
    const uint* wbh = wh + half * 256 + (mt * 32 + colx) * 4;
    const uint* wbl = wl + half * 256 + (mt * 32 + colx) * 4;
    uint4 Hc[4], Lc[4];
#pragma unroll
    for (int c = 0; c < 4; c++) {
        Hc[c] = *(const uint4*)(wbh + c * 512);
        Lc[c] = *(const uint4*)(wbl + c * 512);
    }
    __syncthreads();

    f32x16 acc0 = (f32x16)0.f, acc1 = (f32x16)0.f;   // rows rq*2, rq*2+1

#pragma unroll
    for (int tap = 0; tap < 9; tap++) {
        const int dy = tap / 3, dx = tap % 3;
        const int pixb = (rq * 2 + dy) * 34 + dx + colx;   // row rq*2

        uint4 Ba[4], Bb[4];
#pragma unroll
        for (int c = 0; c < 4; c++) {
            const int c2 = c * 2 + half;
            const int p0 = pixb, p1 = pixb + 34;
            Ba[c] = *(const uint4*)&lds[(p0 * 8 + (c2 ^ (p0 & 7))) * 4];
            Bb[c] = *(const uint4*)&lds[(p1 * 8 + (c2 ^ (p1 & 7))) * 4];
        }
        uint4 Hn[4], Ln[4];
        if (tap < 8) {
#pragma unroll
            for (int c = 0; c < 4; c++) {
                Hn[c] = *(const uint4*)(wbh + (tap + 1) * 2048 + c * 512);
                Ln[c] = *(const uint4*)(wbl + (tap + 1) * 2048 + c * 512);
            }
        }
        // pin: all loads above stay above; MFMAs below stay below
        __builtin_amdgcn_sched_barrier(0);
#pragma unroll
        for (int c = 0; c < 4; c++) {
            const s16x8 b0 = fragpack(Ba[c]), b1 = fragpack(Bb[c]);
            const s16x8 ah = fragpack(Hc[c]), al = fragpack(Lc[c]);
            acc0 = __builtin_amdgcn_mfma_f32_32x32x16_bf16(ah, b0, acc0, 0, 0, 0);
            acc1 = __builtin_amdgcn_mfma_f32_32x32x16_bf16(ah, b1, acc1, 0, 0, 0);
            acc0 = __builtin_amdgcn_mfma_f32_32x32x16_bf16(al, b0, acc0, 0, 0, 0);
            acc1 = __builtin_amdgcn_mfma_f32_32x32x16_bf16(al, b1, acc1, 0, 0, 0);
        }
        if (tap < 8) {
#pragma unroll
            for (int c = 0; c < 4; c++) { Hc[c] = Hn[c]; Lc[c] = Ln[c]; }
        }
    }

    // ---- epilogue. C/D layout (32x32): col=lane&31 (pixel), row=(j&3)+8*(j>>2)+4*half (oc)
    const int pcol = colx, seg = half;
    const int pixg = (y0 + wid) * 256 + x0 + pcol;
    __syncthreads();                    // halo reads done; reuse lds for transpose
#define STH(ACC, RR, DOPRELU) { \
    _Pragma("unroll") \
    for (int j = 0; j < 16; j += 2) { \
        const int row = (j & 3) + 8 * (j >> 2) + 4 * half; \
        const int oc = mt * 32 + row; \
        float v0 = ACC[j]     + bias[oc]; \
        float v1 = ACC[j + 1] + bias[oc + 1]; \
        if (DOPRELU) { \
            const float a0 = prelu[oc], a1 = prelu[oc + 1]; \
            v0 = fmaxf(v0, 0.f) + a0 * fminf(v0, 0.f); \
            v1 = fmaxf(v1, 0.f) + a1 * fminf(v1, 0.f); \
        } \
        const int icp = oc >> 1; \
        lds[((RR) * 32 + icp) * 32 + (colx ^ icp)] = \
            bf16rne(v0) | (bf16rne(v1) << 16); \
    } }
    STH(acc0, rq * 2, (MODE == 1)) STH(acc1, rq * 2 + 1, (MODE == 1))
#undef STH
    __syncthreads();
    uint d[16];
#pragma unroll
    for (int i = 0; i < 16; i++) {
        const int icp = seg * 16 + i;
        d[i] = lds[(wid * 32 + icp) * 32 + (pcol ^ icp)];
    }
    uint* o = op + (size_t)b * PLANE * 32 + chunk_addr(pixg, seg * 4);
#pragma unroll
    for (int k = 0; k < 4; k++)
        *(uint4*)(o + k * 128) = make_uint4(d[4*k], d[4*k+1], d[4*k+2], d[4*k+3]);

    if constexpr (MODE == 2) {
        // fused per-pixel channel mean/max (from hi; 2^-9 relative, fine)
        float s_ = 0.f, m_ = -INFINITY;
#pragma unroll
        for (int i = 0; i < 16; i++) {
            float ve = bf16val(d[i] & 0xffffu);
            float vo = bf16val(d[i] >> 16);
            s_ += ve + vo;
            m_ = fmaxf(m_, fmaxf(ve, vo));
        }
        // fused gpool: channel-major partial sums from the hi transpose.
        const int cp_g = tid & 31;
        const int hr_g = tid >> 5;
        const int row_g = hr_g >> 1;
        const int pc0_g = (hr_g & 1) * 16;
        float gs0 = 0.f, gs1 = 0.f;
#pragma unroll
        for (int p = 0; p < 16; p++) {
            const int pc = pc0_g + p;
            const uint v = lds[(row_g * 32 + cp_g) * 32 + (pc ^ cp_g)];
            gs0 += bf16val(v & 0xffffu);
            gs1 += bf16val(v >> 16);
        }
        s_ += __shfl_xor(s_, 32, 64);
        m_ = fmaxf(m_, __shfl_xor(m_, 32, 64));
        if (seg == 0) {
            amx[(size_t)b * 2 * PLANE + pixg] = s_ * (1.f / 64.f);
            amx[(size_t)b * 2 * PLANE + PLANE + pixg] = m_;
        }
        __syncthreads();
        lds[4096 + hr_g * 64 + 2 * cp_g]     = __float_as_uint(gs0);
        lds[4096 + hr_g * 64 + 2 * cp_g + 1] = __float_as_uint(gs1);
        __syncthreads();
        if (tid < 64) {
            float t = 0.f;
#pragma unroll
            for (int h8 = 0; h8 < 8; h8++)
                t += __uint_as_float(lds[4096 + h8 * 64 + tid]);
            atomicAdd(&gsum[b * 64 + tid], t * (1.f / PLANE));
        }
    }
}

// ---------------- tiny MLPs -> hyper kernels, fragment-slot hi/lo --------
__global__ __launch_bounds__(256) void mlp_kernel(
    const float* __restrict__ h, const float* __restrict__ g,
    const float* __restrict__ ca_w1, const float* __restrict__ ca_b1,
    const float* __restrict__ ca_a,
    const float* __restrict__ ca_w2, const float* __restrict__ ca_b2,
    const float* __restrict__ fc_w, const float* __restrict__ fc_b,
    const float* __restrict__ k1_w, const float* __restrict__ k1_b,
    const float* __restrict__ k2_w, const float* __restrict__ k2_b,
    const float* __restrict__ k3_w, const float* __restrict__ k3_b,
    uint* __restrict__ kAhi, uint* __restrict__ kAlo,
    uint* __restrict__ kBhi, uint* __restrict__ kBlo)
{
    int b = blockIdx.x, tid = threadIdx.x;
    __shared__ float gb[64], t16[16], u32[32], v32[32], cg1[32], casig[64];

    if (tid < 64) gb[tid] = g[b * 64 + tid];
    __syncthreads();

    if (tid < 16) {
        float s = fc_b[tid];
        for (int j = 0; j < 16; j++) s += fc_w[tid * 16 + j] * h[b * 16 + j];
        t16[tid] = s >= 0.f ? s : 0.01f * s;
    }
    if (tid < 32) {
        float c1 = ca_b1[tid];
        for (int j = 0; j < 64; j++) c1 += ca_w1[tid * 64 + j] * gb[j];
        cg1[tid] = fmaxf(c1, 0.f) + ca_a[tid] * fminf(c1, 0.f);
    }
    __syncthreads();
    if (tid < 32) {
        float s = k1_b[tid];
        for (int j = 0; j < 16; j++) s += k1_w[tid * 16 + j] * t16[j];
        u32[tid] = s >= 0.f ? s : 0.01f * s;
    }
    if (tid < 64) {
        float c2 = ca_b2[tid];
        for (int j = 0; j < 32; j++) c2 += ca_w2[tid * 32 + j] * cg1[j];
        casig[tid] = 1.f / (1.f + expf(-c2));
    }
    __syncthreads();
    if (tid < 32) {
        float s = k2_b[tid];
        for (int j = 0; j < 32; j++) s += k2_w[tid * 32 + j] * u32[j];
        v32[tid] = s >= 0.f ? s : 0.01f * s;
    }
    __syncthreads();
    // k3: 8192 outputs, adjacent pairs -> one packed dword, fragment-slot store
    for (int o2 = tid; o2 < 4096; o2 += 256) {
        const int o = o2 * 2;
        const int oc = o >> 7;        // /128
        const int i = o & 127;        // even
        float s0 = k3_b[o], s1 = k3_b[o + 1];
        for (int j = 0; j < 32; j++) {
            s0 += k3_w[(size_t)o * 32 + j] * v32[j];
            s1 += k3_w[(size_t)(o + 1) * 32 + j] * v32[j];
        }
        uint *hi, *lo;
        if (i < 64) { hi = kAhi; lo = kAlo; }
        else { s0 *= casig[i - 64]; s1 *= casig[i - 63]; hi = kBhi; lo = kBlo; }
        const int cp = (i & 63) >> 1;
        uint h0 = bf16rne(s0); float l0 = s0 - bf16val(h0);
        uint h1 = bf16rne(s1); float l1 = s1 - bf16val(h1);
        const size_t a = (size_t)b * 2048 + (cp >> 2) * 256 + oc * 4 + (cp & 3);
        hi[a] = h0 | (h1 << 16);
        lo[a] = bf16rne(l0) | (bf16rne(l1) << 16);
    }
}

// ---------------- final via MFMA + inlined spatial-attention conv -----------
// out = x + hcb + sig(sa3x3(amx))*(A.r) + (B.r);  r = hi only (see note)
__global__ __launch_bounds__(256, 8) void final_mfma(
    const float* __restrict__ x, const uint* __restrict__ rph,
    const float* __restrict__ amx,
    const uint* __restrict__ kAhi, const uint* __restrict__ kAlo,
    const uint* __restrict__ kBhi, const uint* __restrict__ kBlo,
    const float* __restrict__ sa_w, const float* __restrict__ sa_b,
    const float* __restrict__ hcb, float* __restrict__ out)
{
    const int tid = threadIdx.x;
    const int lane = tid & 63;
    const int wid = tid >> 6;
    const int mt = wid & 1;          // oc Mtile
    const int gq = wid >> 1;         // pixel group
    const int b = blockIdx.y;
    const int colx = lane & 31;
    const int half = lane >> 5;
    const int pix = blockIdx.x * 64 + gq * 32 + colx;
    const int pgroup = blockIdx.x * 2 + gq;   // pix >> 5

    // fragment-slot kernel loads (lane-dense)
    const size_t kb = (size_t)b * 2048 + half * 256 + (size_t)(mt * 32 + colx) * 4;
    uint4 KAh[4], KAl[4], KBh[4], KBl[4];
#pragma unroll
    for (int c = 0; c < 4; c++) {
        KAh[c] = *(const uint4*)(kAhi + kb + c * 512);
        KAl[c] = *(const uint4*)(kAlo + kb + c * 512);
        KBh[c] = *(const uint4*)(kBhi + kb + c * 512);
        KBl[c] = *(const uint4*)(kBlo + kb + c * 512);
    }
    // fragment-slot activation loads (hi only)
    const size_t rb = (size_t)b * PLANE * 32 + (size_t)pgroup * 1024
                    + half * 128 + colx * 4;
    uint4 Bh[4];
#pragma unroll
    for (int c = 0; c < 4; c++)
        Bh[c] = *(const uint4*)(rph + rb + c * 256);

    // inlined spatial attention: 3x3 reflect conv over amx (2ch -> 1)
    const int xx = pix & 255, yy = pix >> 8;
    float sacc = sa_b[0];
    const float* ab = amx + (size_t)b * 2 * PLANE;
#pragma unroll
    for (int cc = 0; cc < 2; cc++)
#pragma unroll
        for (int dy2 = -1; dy2 <= 1; dy2++)
#pragma unroll
            for (int dx2 = -1; dx2 <= 1; dx2++) {
                int gx = xx + dx2; gx = gx < 0 ? 1 : (gx >= WW ? 2 * WW - 2 - gx : gx);
                int gy = yy + dy2; gy = gy < 0 ? 1 : (gy >= HH ? 2 * HH - 2 - gy : gy);
                sacc += sa_w[cc * 9 + (dy2 + 1) * 3 + (dx2 + 1)]
                      * ab[(size_t)cc * PLANE + gy * WW + gx];
            }
    const float sig = 1.f / (1.f + expf(-sacc));

    f32x16 accA = (f32x16)0.f, accB = (f32x16)0.f;
#pragma unroll
    for (int c = 0; c < 4; c++) {
        const s16x8 bh = fragpack(Bh[c]);
        const s16x8 ah = fragpack(KAh[c]), al = fragpack(KAl[c]);
        const s16x8 ch = fragpack(KBh[c]), cl = fragpack(KBl[c]);
        accA = __builtin_amdgcn_mfma_f32_32x32x16_bf16(ah, bh, accA, 0, 0, 0);
        accA = __builtin_amdgcn_mfma_f32_32x32x16_bf16(al, bh, accA, 0, 0, 0);
        accB = __builtin_amdgcn_mfma_f32_32x32x16_bf16(ch, bh, accB, 0, 0, 0);
        accB = __builtin_amdgcn_mfma_f32_32x32x16_bf16(cl, bh, accB, 0, 0, 0);
    }
#pragma unroll
    for (int j = 0; j < 16; j++) {
        const int row = (j & 3) + 8 * (j >> 2) + 4 * half;
        const int oc = mt * 32 + row;
        const size_t idx = ((size_t)b * 64 + oc) * PLANE + pix;
        out[idx] = x[idx] + hcb[oc] + sig * accA[j] + accB[j];
    }
}

extern "C" void kernel_launch(void* const* d_in, const int* in_sizes, int n_in,
                              void* d_out, int out_size, void* d_ws, size_t ws_size,
                              hipStream_t stream) {
    const float* x   = (const float*)d_in[0];
    const float* h   = (const float*)d_in[1];
    const float* c1w = (const float*)d_in[2];
    const float* c1b = (const float*)d_in[3];
    const float* pa  = (const float*)d_in[4];
    const float* c2w = (const float*)d_in[5];
    const float* c2b = (const float*)d_in[6];
    const float* saw = (const float*)d_in[7];
    const float* sab = (const float*)d_in[8];
    const float* cw1 = (const float*)d_in[9];
    const float* cb1 = (const float*)d_in[10];
    const float* caa = (const float*)d_in[11];
    const float* cw2 = (const float*)d_in[12];
    const float* cb2 = (const float*)d_in[13];
    const float* fcw = (const float*)d_in[14];
    const float* fcb = (const float*)d_in[15];
    const float* k1w = (const float*)d_in[16];
    const float* k1b = (const float*)d_in[17];
    const float* k2w = (const float*)d_in[18];
    const float* k2b = (const float*)d_in[19];
    const float* k3w = (const float*)d_in[20];
    const float* k3b = (const float*)d_in[21];
    const float* hcb = (const float*)d_in[22];
    float* out = (float*)d_out;

    char* ws = (char*)d_ws;
    const size_t SZ_Q = (size_t)8 * PLANE * 32 * 4;   // 67,108,864 (packed)
    uint*  xp  = (uint*)ws;                           // x repacked
    uint*  r1p = (uint*)(ws + SZ_Q);                  // conv1 out (hi)
    uint*  rph = (uint*)(ws + 2 * SZ_Q);              // conv2 out hi
    float* amx   = (float*)ws;                        // aliases xp (xp dead after conv1)
    uint*  kAhi  = (uint*)(ws + (size_t)8 * 3 * PLANE * 4 + 4096);
    uint*  kAlo  = kAhi + 8 * 2048;
    uint*  kBhi  = kAlo + 8 * 2048;
    uint*  kBlo  = kBhi + 8 * 2048;

    // weight packs + g live in d_out (dead until final_mfma overwrites it).
    // g must NOT alias xp: it is memset BEFORE conv1 (xp still live there).
    uint* wsp = (uint*)d_out;
    uint* wh1 = wsp;          uint* wl1 = wsp + 18432;
    uint* wh2 = wsp + 36864;  uint* wl2 = wsp + 55296;
    float* g  = (float*)(wsp + 73728);                // 512 floats in d_out

    wprep_kernel<<<dim3(72, 2), 256, 0, stream>>>(c1w, c2w, wh1, wl1, wh2, wl2);
    xrepack_kernel<<<dim3(PLANE / 256, 8), 256, 0, stream>>>(x, xp);
    hipMemsetAsync(g, 0, 512 * sizeof(float), stream);

    dim3 cgrid(WW / 32, HH / 4, 8);  // (8, 64, 8)
    conv_mfma<1><<<cgrid, 256, 0, stream>>>(xp, wh1, wl1, c1b, pa, r1p,
                                            nullptr, nullptr);
    conv_mfma<2><<<cgrid, 256, 0, stream>>>(r1p, wh2, wl2, c2b, nullptr, rph,
                                            amx, g);

    mlp_kernel<<<8, 256, 0, stream>>>(h, g, cw1, cb1, caa, cw2, cb2,
                                      fcw, fcb, k1w, k1b, k2w, k2b, k3w, k3b,
                                      kAhi, kAlo, kBhi, kBlo);
    final_mfma<<<dim3(PLANE / 64, 8), 256, 0, stream>>>(
        x, rph, amx, kAhi, kAlo, kBhi, kBlo, saw, sab, hcb, out);
}